// Round 1
// baseline (445.149 us; speedup 1.0000x reference)
//
#include <hip/hip_runtime.h>
#include <stdint.h>

#define B 4
#define HW 128
#define C 256
#define NTOK 16384
#define MALL 65536
#define HEADS 8
#define DH 32

typedef float f32x4 __attribute__((ext_vector_type(4)));
typedef short s16x8 __attribute__((ext_vector_type(8)));
typedef short s16x4 __attribute__((ext_vector_type(4)));
typedef __bf16 bf16x8 __attribute__((ext_vector_type(8)));

__device__ __forceinline__ float bf2f(unsigned short u) {
  union { unsigned int i; float f; } x;
  x.i = ((unsigned int)u) << 16;
  return x.f;
}
__device__ __forceinline__ unsigned short f2bf(float f) {
  union { float f; unsigned int i; } x;
  x.f = f;
  unsigned int lsb = (x.i >> 16) & 1u;
  unsigned int r = x.i + 0x7fffu + lsb;
  return (unsigned short)(r >> 16);
}

__device__ __forceinline__ void gload_lds16(const void* g, void* l) {
  auto gp = reinterpret_cast<const __attribute__((address_space(1))) unsigned int*>(
      reinterpret_cast<uintptr_t>(g));
  auto lp = reinterpret_cast<__attribute__((address_space(3))) unsigned int*>(
      reinterpret_cast<uintptr_t>(l));
  __builtin_amdgcn_global_load_lds(gp, lp, 16, 0, 0);
}

// ---------------- cast x to bf16 ----------------
__global__ __launch_bounds__(256) void cast_x_kernel(const float* __restrict__ x,
                                                     unsigned short* __restrict__ xb) {
  const size_t stride = (size_t)gridDim.x * blockDim.x * 4;
  for (size_t i = ((size_t)blockIdx.x * blockDim.x + threadIdx.x) * 4; i < (size_t)MALL * C;
       i += stride) {
    const float4 v = *(const float4*)&x[i];
    s16x4 o;
    o[0] = (short)f2bf(v.x);
    o[1] = (short)f2bf(v.y);
    o[2] = (short)f2bf(v.z);
    o[3] = (short)f2bf(v.w);
    *(s16x4*)&xb[i] = o;
  }
}

// ---------------- weight prep: transpose+cast ----------------
__global__ __launch_bounds__(256) void prep_w_kernel(
    const float* __restrict__ wq, const float* __restrict__ wk, const float* __restrict__ wv,
    const float* __restrict__ wproj, const float* __restrict__ w1, const float* __restrict__ w2,
    unsigned short* __restrict__ wqkvT, unsigned short* __restrict__ wprojT,
    unsigned short* __restrict__ w1b, unsigned short* __restrict__ w2b) {
  const int idx = blockIdx.x * 256 + threadIdx.x;  // 0..65535
  const int mat = blockIdx.y;
  const int n = idx >> 8, k = idx & 255;
  switch (mat) {
    case 0: wqkvT[idx] = f2bf(wq[k * 256 + n]); break;
    case 1: wqkvT[65536 + idx] = f2bf(wk[k * 256 + n]); break;
    case 2: wqkvT[131072 + idx] = f2bf(wv[k * 256 + n]); break;
    case 3: wprojT[idx] = f2bf(wproj[k * 256 + n]); break;
    case 4: w1b[idx] = f2bf(w1[idx]); break;   // [co][ci] already K-contig
    case 5: w2b[idx] = f2bf(w2[idx]); break;
  }
}

// ---------------- transpose mask [C][N] -> [N][C] bf16 ----------------
__global__ __launch_bounds__(1024) void tmask_kernel(const float* __restrict__ mask,
                                                     unsigned short* __restrict__ mT) {
  __shared__ float tile[32][33];
  const int p0 = blockIdx.x * 32, c0 = blockIdx.y * 32;
  const int tx = threadIdx.x & 31, ty = threadIdx.x >> 5;
  tile[ty][tx] = mask[(size_t)(c0 + ty) * NTOK + p0 + tx];
  __syncthreads();
  mT[(size_t)(p0 + ty) * C + c0 + tx] = f2bf(tile[tx][ty]);
}

// ---------------- main bf16 MFMA GEMM: C[M,N] = A[M,K] * Bt[N,K]^T ----------------
// mode 0: split into 3 bf16 outputs by col/256 (qkv). mode 1: +bias, bf16 out.
// mode 2: +bias, accumulate into existing f32 out.
__global__ __launch_bounds__(256) void gemm_bt_kernel(
    const unsigned short* __restrict__ A, const unsigned short* __restrict__ Bt, const int K,
    const int mode, unsigned short* __restrict__ ob0, unsigned short* __restrict__ ob1,
    unsigned short* __restrict__ ob2, const float* __restrict__ bias,
    float* __restrict__ of32) {
  __shared__ unsigned short lA[128 * 64];
  __shared__ unsigned short lB[128 * 64];
  const int m0 = blockIdx.x * 128;
  const int n0 = blockIdx.y * 128;
  const int t = threadIdx.x;
  const int w = t >> 6, l = t & 63;
  const int wr = w >> 1, wc = w & 1;
  const int lr = l & 15, lg = l >> 4;

  f32x4 acc[4][4];
#pragma unroll
  for (int i = 0; i < 4; ++i)
#pragma unroll
    for (int j = 0; j < 4; ++j) acc[i][j] = f32x4{0.f, 0.f, 0.f, 0.f};

  for (int k0 = 0; k0 < K; k0 += 64) {
    __syncthreads();
#pragma unroll
    for (int s = 0; s < 4; ++s) {
      const int seg = w * 4 + s;
      const int bo = seg * 1024 + l * 16;  // byte offset within 16KB tile
      const int row = bo >> 7;             // 128B per row (64 bf16)
      const int colb = bo & 127;
      gload_lds16((const char*)A + ((size_t)(m0 + row) * K + k0) * 2 + colb,
                  (char*)lA + seg * 1024);
      gload_lds16((const char*)Bt + ((size_t)(n0 + row) * K + k0) * 2 + colb,
                  (char*)lB + seg * 1024);
    }
    __syncthreads();
#pragma unroll
    for (int kk = 0; kk < 64; kk += 32) {
      bf16x8 af[4], bfr[4];
#pragma unroll
      for (int i = 0; i < 4; ++i)
        af[i] = *(const bf16x8*)&lA[(wr * 64 + i * 16 + lr) * 64 + kk + lg * 8];
#pragma unroll
      for (int j = 0; j < 4; ++j)
        bfr[j] = *(const bf16x8*)&lB[(wc * 64 + j * 16 + lr) * 64 + kk + lg * 8];
#pragma unroll
      for (int i = 0; i < 4; ++i)
#pragma unroll
        for (int j = 0; j < 4; ++j)
          acc[i][j] = __builtin_amdgcn_mfma_f32_16x16x32_bf16(af[i], bfr[j], acc[i][j], 0, 0, 0);
    }
  }
#pragma unroll
  for (int i = 0; i < 4; ++i) {
    const int grow = m0 + wr * 64 + i * 16 + lg * 4;
#pragma unroll
    for (int j = 0; j < 4; ++j) {
      const int gcol = n0 + wc * 64 + j * 16 + lr;
#pragma unroll
      for (int r = 0; r < 4; ++r) {
        const float v = acc[i][j][r];
        const size_t row = (size_t)(grow + r);
        if (mode == 0) {
          unsigned short* dst = (gcol < 256) ? ob0 : (gcol < 512 ? ob1 : ob2);
          dst[row * C + (gcol & 255)] = f2bf(v);
        } else if (mode == 1) {
          ob0[row * C + gcol] = f2bf(v + bias[gcol]);
        } else {
          const size_t idx = row * C + gcol;
          of32[idx] += v + bias[gcol];
        }
      }
    }
  }
}

// ---------------- depthwise 5x5 + sigmoid + mask_emb = m1*(1+a) ----------------
__global__ __launch_bounds__(256) void mask_dw5_kernel(
    const unsigned short* __restrict__ m2, const unsigned short* __restrict__ m1,
    const float* __restrict__ dw, const float* __restrict__ db,
    unsigned short* __restrict__ memb) {
  const int x0 = blockIdx.x * 32;
  const int y = blockIdx.y;
  const int c = threadIdx.x;
  float w[25];
#pragma unroll
  for (int e = 0; e < 25; ++e) w[e] = dw[c * 25 + e];
  const float bias = db[c];
  float col[5][5];  // col[k][dy]: column x-2+k
#pragma unroll
  for (int k = 0; k < 5; ++k) {
    const int xx = x0 - 2 + k;
#pragma unroll
    for (int dy = 0; dy < 5; ++dy) {
      const int yy = y + dy - 2;
      col[k][dy] = (xx >= 0 && xx < HW && yy >= 0 && yy < HW)
                       ? bf2f(m2[((size_t)yy * HW + xx) * C + c])
                       : 0.f;
    }
  }
  for (int xi = 0; xi < 32; ++xi) {
    const int x = x0 + xi;
    float s = bias;
#pragma unroll
    for (int kx = 0; kx < 5; ++kx)
#pragma unroll
      for (int ky = 0; ky < 5; ++ky) s += w[ky * 5 + kx] * col[kx][ky];
    const float a = 1.f / (1.f + expf(-s));
    const size_t oi = ((size_t)y * HW + x) * C + c;
    memb[oi] = f2bf(bf2f(m1[oi]) * (1.f + a));
#pragma unroll
    for (int k = 0; k < 4; ++k)
#pragma unroll
      for (int dy = 0; dy < 5; ++dy) col[k][dy] = col[k + 1][dy];
    const int xn = x + 3;
#pragma unroll
    for (int dy = 0; dy < 5; ++dy) {
      const int yy = y + dy - 2;
      col[4][dy] =
          (xn < HW && yy >= 0 && yy < HW) ? bf2f(m2[((size_t)yy * HW + xn) * C + c]) : 0.f;
    }
  }
}

// ---------------- sumsq over tokens per (b,c) : partials ----------------
__global__ __launch_bounds__(256) void sumsq_kernel(const unsigned short* __restrict__ qb,
                                                    const unsigned short* __restrict__ kb,
                                                    float* __restrict__ ssq,
                                                    float* __restrict__ ssk) {
  const int chunk = blockIdx.x;  // 64
  const int b = blockIdx.y;      // 4
  const int t = threadIdx.x;
  const int c0 = (t & 63) * 4;
  const int rw = t >> 6;
  float aq[4] = {0.f, 0.f, 0.f, 0.f}, ak[4] = {0.f, 0.f, 0.f, 0.f};
  for (int r = rw; r < 256; r += 4) {
    const size_t n = (size_t)b * NTOK + chunk * 256 + r;
    s16x4 qv = *(const s16x4*)&qb[n * C + c0];
    s16x4 kv = *(const s16x4*)&kb[n * C + c0];
#pragma unroll
    for (int e = 0; e < 4; ++e) {
      const float f = bf2f((unsigned short)qv[e]);
      aq[e] += f * f;
      const float g = bf2f((unsigned short)kv[e]);
      ak[e] += g * g;
    }
  }
  __shared__ float redq[4][256], redk[4][256];
#pragma unroll
  for (int e = 0; e < 4; ++e) {
    redq[rw][c0 + e] = aq[e];
    redk[rw][c0 + e] = ak[e];
  }
  __syncthreads();
  const float s1 = redq[0][t] + redq[1][t] + redq[2][t] + redq[3][t];
  const float s2 = redk[0][t] + redk[1][t] + redk[2][t] + redk[3][t];
  ssq[((size_t)b * 64 + chunk) * C + t] = s1;
  ssk[((size_t)b * 64 + chunk) * C + t] = s2;
}

// ---------------- Gram partials G[i][j] = sum_n k[n,i]*q[n,j] per (b,h) ----------------
__global__ __launch_bounds__(256) void gram_kernel(const unsigned short* __restrict__ qb,
                                                   const unsigned short* __restrict__ kb,
                                                   float* __restrict__ Gpart) {
  const int chunk = blockIdx.x;  // 16
  const int h = blockIdx.y;      // 8
  const int b = blockIdx.z;      // 4
  __shared__ unsigned short lk[128 * 32], lq[128 * 32];
  const int t = threadIdx.x;
  const int wv = t >> 6;
  const int i0 = (t & 7) * 4, j0 = ((t >> 3) & 7) * 4;
  float acc[4][4] = {};
  for (int sub = 0; sub < 8; ++sub) {
    const size_t nbase = (size_t)b * NTOK + chunk * 1024 + sub * 128;
    __syncthreads();
#pragma unroll
    for (int it = 0; it < 2; ++it) {
      const int row = it * 64 + (t >> 2);
      const int cb = (t & 3) * 8;
      *(s16x8*)&lk[row * 32 + cb] = *(const s16x8*)&kb[(nbase + row) * C + h * 32 + cb];
      *(s16x8*)&lq[row * 32 + cb] = *(const s16x8*)&qb[(nbase + row) * C + h * 32 + cb];
    }
    __syncthreads();
    for (int n = wv; n < 128; n += 4) {
      s16x4 kv = *(const s16x4*)&lk[n * 32 + i0];
      s16x4 qv = *(const s16x4*)&lq[n * 32 + j0];
      float kf[4], qf[4];
#pragma unroll
      for (int e = 0; e < 4; ++e) {
        kf[e] = bf2f((unsigned short)kv[e]);
        qf[e] = bf2f((unsigned short)qv[e]);
      }
#pragma unroll
      for (int a = 0; a < 4; ++a)
#pragma unroll
        for (int bb = 0; bb < 4; ++bb) acc[a][bb] += kf[a] * qf[bb];
    }
  }
  const int pc = chunk * 4 + wv;
  float* dst = Gpart + (((size_t)pc * B + b) * HEADS + h) * 1024;
#pragma unroll
  for (int a = 0; a < 4; ++a)
#pragma unroll
    for (int bb = 0; bb < 4; ++bb) dst[(i0 + a) * 32 + (j0 + bb)] = acc[a][bb];
}

// ---------------- reduce + normalize + softmax -> attn bf16 ----------------
__global__ __launch_bounds__(256) void softmax_kernel(
    const float* __restrict__ Gpart, const float* __restrict__ ssq,
    const float* __restrict__ ssk, const float* __restrict__ rescale,
    unsigned short* __restrict__ attnb) {
  const int h = blockIdx.x, b = blockIdx.y;
  const int t = threadIdx.x;
  __shared__ float G[1024];
  __shared__ float nq[32], nk[32];
#pragma unroll
  for (int e = 0; e < 4; ++e) {
    const int cell = e * 256 + t;
    float s = 0.f;
    for (int pc = 0; pc < 64; ++pc)
      s += Gpart[(((size_t)pc * B + b) * HEADS + h) * 1024 + cell];
    G[cell] = s;
  }
  if (t < 64) {
    const int d = t & 31;
    const float* ss = (t < 32) ? ssq : ssk;
    float s = 0.f;
    for (int ch = 0; ch < 64; ++ch) s += ss[((size_t)b * 64 + ch) * C + h * 32 + d];
    const float nn = fmaxf(sqrtf(s), 1e-12f);
    if (t < 32) nq[d] = nn;
    else nk[d] = nn;
  }
  __syncthreads();
  if (t < 32) {
    const int i = t;
    const float rs = rescale[h];
    float row[32];
    float mx = -1e30f;
#pragma unroll
    for (int j = 0; j < 32; ++j) {
      const float v = G[i * 32 + j] / (nk[i] * nq[j]) * rs;
      row[j] = v;
      mx = fmaxf(mx, v);
    }
    float sum = 0.f;
#pragma unroll
    for (int j = 0; j < 32; ++j) {
      const float e = expf(row[j] - mx);
      row[j] = e;
      sum += e;
    }
    const float inv = 1.f / sum;
#pragma unroll
    for (int j = 0; j < 32; ++j)
      attnb[(((size_t)b * HEADS + h) * 32 + i) * 32 + j] = f2bf(row[j] * inv);
  }
}

// ---------------- PV: out_pre[n, 32h+i] = sum_j attn[h,i,j] * (v*ma)[n, 32h+j] ----------------
#define PVP 264
#define ATP 40
__global__ __launch_bounds__(256) void pv_kernel(const unsigned short* __restrict__ vb,
                                                 const unsigned short* __restrict__ memb,
                                                 const unsigned short* __restrict__ attnb,
                                                 unsigned short* __restrict__ outp) {
  const int n0 = blockIdx.x * 64;
  const int b = blockIdx.y;
  __shared__ unsigned short vma[64 * PVP];
  __shared__ unsigned short at[HEADS * 32 * ATP];
  const int t = threadIdx.x, w = t >> 6, l = t & 63;
  const int lr = l & 15, lg = l >> 4;
  for (int e = t; e < 8192; e += 256) {
    const int h = e >> 10, ij = e & 1023;
    at[(h * 32 + (ij >> 5)) * ATP + (ij & 31)] = attnb[(size_t)b * 8192 + e];
  }
  {
    const int row = t >> 2, cs = (t & 3) * 64;
#pragma unroll
    for (int i2 = 0; i2 < 8; ++i2) {
      const int c = cs + i2 * 8;
      s16x8 vv = *(const s16x8*)&vb[((size_t)b * NTOK + n0 + row) * C + c];
      s16x8 mm = *(const s16x8*)&memb[(size_t)(n0 + row) * C + c];
      s16x8 o;
#pragma unroll
      for (int e = 0; e < 8; ++e)
        o[e] = (short)f2bf(bf2f((unsigned short)vv[e]) * bf2f((unsigned short)mm[e]));
      *(s16x8*)&vma[row * PVP + c] = o;
    }
  }
  __syncthreads();
  f32x4 acc[4][4];
#pragma unroll
  for (int i = 0; i < 4; ++i)
#pragma unroll
    for (int j = 0; j < 4; ++j) acc[i][j] = f32x4{0.f, 0.f, 0.f, 0.f};
#pragma unroll
  for (int j = 0; j < 4; ++j) {
    const int head = w * 2 + (j >> 1);
    const int colh = (j & 1) * 16 + lr;
    const bf16x8 bfr = *(const bf16x8*)&at[(head * 32 + colh) * ATP + lg * 8];
#pragma unroll
    for (int i = 0; i < 4; ++i) {
      const bf16x8 af = *(const bf16x8*)&vma[(i * 16 + lr) * PVP + head * 32 + lg * 8];
      acc[i][j] = __builtin_amdgcn_mfma_f32_16x16x32_bf16(af, bfr, acc[i][j], 0, 0, 0);
    }
  }
#pragma unroll
  for (int i = 0; i < 4; ++i) {
#pragma unroll
    for (int j = 0; j < 4; ++j) {
      const int head = w * 2 + (j >> 1);
      const int gcol = head * 32 + (j & 1) * 16 + lr;
      const int grow = n0 + i * 16 + lg * 4;
#pragma unroll
      for (int r = 0; r < 4; ++r)
        outp[((size_t)b * NTOK + grow + r) * C + gcol] = f2bf(acc[i][j][r]);
    }
  }
}

// ---------------- depthwise 3x3 (optional GELU; bf16 or f32 out) ----------------
__global__ __launch_bounds__(256) void dw3_kernel(const unsigned short* __restrict__ in,
                                                  const float* __restrict__ wgt,
                                                  unsigned short* __restrict__ out_bf,
                                                  float* __restrict__ out_f32,
                                                  const int do_gelu, const int write_f32) {
  const int y = blockIdx.x;
  const int b = blockIdx.y;
  const int x0 = blockIdx.z * 64;
  const int c = threadIdx.x;
  float w[9];
#pragma unroll
  for (int e = 0; e < 9; ++e) w[e] = wgt[c * 9 + e];
  const size_t base = (size_t)b * NTOK * C + c;
  const int ym = y - 1, yp = y + 1;
  const bool hm = (ym >= 0), hp = (yp < HW);
  auto ld = [&](int yy, int xx) -> float { return bf2f(in[base + ((size_t)yy * HW + xx) * C]); };
  float c0, c1, c2, d0, d1, d2;
  if (x0 > 0) {
    c0 = hm ? ld(ym, x0 - 1) : 0.f;
    c1 = ld(y, x0 - 1);
    c2 = hp ? ld(yp, x0 - 1) : 0.f;
  } else {
    c0 = c1 = c2 = 0.f;
  }
  d0 = hm ? ld(ym, x0) : 0.f;
  d1 = ld(y, x0);
  d2 = hp ? ld(yp, x0) : 0.f;
#pragma unroll 4
  for (int xi = 0; xi < 64; ++xi) {
    const int x = x0 + xi;
    float e0 = 0.f, e1 = 0.f, e2 = 0.f;
    if (x + 1 < HW) {
      e0 = hm ? ld(ym, x + 1) : 0.f;
      e1 = ld(y, x + 1);
      e2 = hp ? ld(yp, x + 1) : 0.f;
    }
    float r = w[0] * c0 + w[1] * d0 + w[2] * e0 + w[3] * c1 + w[4] * d1 + w[5] * e1 +
              w[6] * c2 + w[7] * d2 + w[8] * e2;
    if (do_gelu) r = 0.5f * r * (1.f + erff(r * 0.70710678118654752f));
    const size_t oi = base + ((size_t)y * HW + x) * C;
    if (write_f32) out_f32[oi] = r;
    else out_bf[oi] = f2bf(r);
    c0 = d0; c1 = d1; c2 = d2;
    d0 = e0; d1 = e1; d2 = e2;
  }
}

extern "C" void kernel_launch(void* const* d_in, const int* in_sizes, int n_in, void* d_out,
                              int out_size, void* d_ws, size_t ws_size, hipStream_t stream) {
  (void)in_sizes; (void)n_in; (void)out_size; (void)ws_size;
  const float* x = (const float*)d_in[0];
  const float* maskp = (const float*)d_in[1];
  const float* wq = (const float*)d_in[2];
  const float* wk = (const float*)d_in[3];
  const float* wv = (const float*)d_in[4];
  const float* rescale = (const float*)d_in[5];
  const float* wproj = (const float*)d_in[6];
  const float* bproj = (const float*)d_in[7];
  const float* mg_w1 = (const float*)d_in[8];
  const float* mg_b1 = (const float*)d_in[9];
  const float* mg_w2 = (const float*)d_in[10];
  const float* mg_b2 = (const float*)d_in[11];
  const float* mg_dw = (const float*)d_in[12];
  const float* mg_db = (const float*)d_in[13];
  const float* be_w1 = (const float*)d_in[14];
  const float* be_w2 = (const float*)d_in[15];
  float* out = (float*)d_out;
  char* ws = (char*)d_ws;

  unsigned short* xb = (unsigned short*)(ws + 0ull);            // 32MB, later out_pre
  unsigned short* qb = (unsigned short*)(ws + 33554432ull);     // 32MB, later y1
  unsigned short* kb = (unsigned short*)(ws + 67108864ull);     // 32MB
  unsigned short* vb = (unsigned short*)(ws + 100663296ull);    // 32MB
  unsigned short* mT = (unsigned short*)(ws + 134217728ull);    // 8MB, later mask_emb
  unsigned short* m1b = (unsigned short*)(ws + 142606336ull);   // 8MB
  unsigned short* m2b = (unsigned short*)(ws + 150994944ull);   // 8MB, later Gpart
  unsigned short* wqkvT = (unsigned short*)(ws + 159383552ull); // 384KB
  unsigned short* wprojT = (unsigned short*)(ws + 159776768ull);// 128KB
  unsigned short* w1b = (unsigned short*)(ws + 159907840ull);   // 128KB
  unsigned short* w2b = (unsigned short*)(ws + 160038912ull);   // 128KB
  float* ssq = (float*)(ws + 160169984ull);                     // 256KB
  float* ssk = (float*)(ws + 160432128ull);                     // 256KB
  unsigned short* attnb = (unsigned short*)(ws + 160694272ull); // 64KB
  float* Gpart = (float*)m2b;
  unsigned short* memb = mT;
  unsigned short* outpre = xb;
  unsigned short* y1 = qb;

  cast_x_kernel<<<2048, 256, 0, stream>>>(x, xb);
  prep_w_kernel<<<dim3(256, 6), 256, 0, stream>>>(wq, wk, wv, wproj, mg_w1, mg_w2, wqkvT,
                                                  wprojT, w1b, w2b);
  tmask_kernel<<<dim3(512, 8), 1024, 0, stream>>>(maskp, mT);
  // mask branch: m1 = maskT*W1^T+b1 ; m2 = m1*W2^T+b2 ; memb = m1*(1+sigmoid(dw5(m2)+db))
  gemm_bt_kernel<<<dim3(128, 2), 256, 0, stream>>>(mT, w1b, 256, 1, m1b, nullptr, nullptr,
                                                   mg_b1, nullptr);
  gemm_bt_kernel<<<dim3(128, 2), 256, 0, stream>>>(m1b, w2b, 256, 1, m2b, nullptr, nullptr,
                                                   mg_b2, nullptr);
  mask_dw5_kernel<<<dim3(4, 128), 256, 0, stream>>>(m2b, m1b, mg_dw, mg_db, memb);
  // q,k,v
  gemm_bt_kernel<<<dim3(512, 6), 256, 0, stream>>>(xb, wqkvT, 256, 0, qb, kb, vb, nullptr,
                                                   nullptr);
  sumsq_kernel<<<dim3(64, 4), 256, 0, stream>>>(qb, kb, ssq, ssk);
  gram_kernel<<<dim3(16, 8, 4), 256, 0, stream>>>(qb, kb, Gpart);
  softmax_kernel<<<dim3(8, 4), 256, 0, stream>>>(Gpart, ssq, ssk, rescale, attnb);
  pv_kernel<<<dim3(256, 4), 256, 0, stream>>>(vb, memb, attnb, outpre);
  // band branch -> writes d_out; proj GEMM accumulates on top
  dw3_kernel<<<dim3(128, 4, 2), 256, 0, stream>>>(vb, be_w1, y1, nullptr, 1, 0);
  dw3_kernel<<<dim3(128, 4, 2), 256, 0, stream>>>(y1, be_w2, nullptr, out, 0, 1);
  gemm_bt_kernel<<<dim3(512, 2), 256, 0, stream>>>(outpre, wprojT, 256, 2, nullptr, nullptr,
                                                   nullptr, bproj, out);
}

// Round 2
// 385.643 us; speedup vs baseline: 1.1543x; 1.1543x over previous
//
#include <hip/hip_runtime.h>
#include <stdint.h>

#define B 4
#define HW 128
#define C 256
#define NTOK 16384
#define MALL 65536
#define HEADS 8
#define DH 32

typedef float f32x4 __attribute__((ext_vector_type(4)));
typedef short s16x8 __attribute__((ext_vector_type(8)));
typedef short s16x4 __attribute__((ext_vector_type(4)));
typedef __bf16 bf16x8 __attribute__((ext_vector_type(8)));

__device__ __forceinline__ float bf2f(unsigned short u) {
  union { unsigned int i; float f; } x;
  x.i = ((unsigned int)u) << 16;
  return x.f;
}
__device__ __forceinline__ unsigned short f2bf(float f) {
  union { float f; unsigned int i; } x;
  x.f = f;
  unsigned int lsb = (x.i >> 16) & 1u;
  unsigned int r = x.i + 0x7fffu + lsb;
  return (unsigned short)(r >> 16);
}

__device__ __forceinline__ void gload_lds16(const void* g, void* l) {
  auto gp = reinterpret_cast<const __attribute__((address_space(1))) unsigned int*>(
      reinterpret_cast<uintptr_t>(g));
  auto lp = reinterpret_cast<__attribute__((address_space(3))) unsigned int*>(
      reinterpret_cast<uintptr_t>(l));
  __builtin_amdgcn_global_load_lds(gp, lp, 16, 0, 0);
}

// ---------------- cast x to bf16 ----------------
__global__ __launch_bounds__(256) void cast_x_kernel(const float* __restrict__ x,
                                                     unsigned short* __restrict__ xb) {
  const size_t stride = (size_t)gridDim.x * blockDim.x * 4;
  for (size_t i = ((size_t)blockIdx.x * blockDim.x + threadIdx.x) * 4; i < (size_t)MALL * C;
       i += stride) {
    const float4 v = *(const float4*)&x[i];
    s16x4 o;
    o[0] = (short)f2bf(v.x);
    o[1] = (short)f2bf(v.y);
    o[2] = (short)f2bf(v.z);
    o[3] = (short)f2bf(v.w);
    *(s16x4*)&xb[i] = o;
  }
}

// ---------------- weight prep: transpose+cast ----------------
__global__ __launch_bounds__(256) void prep_w_kernel(
    const float* __restrict__ wq, const float* __restrict__ wk, const float* __restrict__ wv,
    const float* __restrict__ wproj, const float* __restrict__ w1, const float* __restrict__ w2,
    unsigned short* __restrict__ wqkvT, unsigned short* __restrict__ wprojT,
    unsigned short* __restrict__ w1b, unsigned short* __restrict__ w2b) {
  const int idx = blockIdx.x * 256 + threadIdx.x;  // 0..65535
  const int mat = blockIdx.y;
  const int n = idx >> 8, k = idx & 255;
  switch (mat) {
    case 0: wqkvT[idx] = f2bf(wq[k * 256 + n]); break;
    case 1: wqkvT[65536 + idx] = f2bf(wk[k * 256 + n]); break;
    case 2: wqkvT[131072 + idx] = f2bf(wv[k * 256 + n]); break;
    case 3: wprojT[idx] = f2bf(wproj[k * 256 + n]); break;
    case 4: w1b[idx] = f2bf(w1[idx]); break;   // [co][ci] already K-contig
    case 5: w2b[idx] = f2bf(w2[idx]); break;
  }
}

// ---------------- transpose mask [C][N] -> [N][C] bf16 ----------------
__global__ __launch_bounds__(1024) void tmask_kernel(const float* __restrict__ mask,
                                                     unsigned short* __restrict__ mT) {
  __shared__ float tile[32][33];
  const int p0 = blockIdx.x * 32, c0 = blockIdx.y * 32;
  const int tx = threadIdx.x & 31, ty = threadIdx.x >> 5;
  tile[ty][tx] = mask[(size_t)(c0 + ty) * NTOK + p0 + tx];
  __syncthreads();
  mT[(size_t)(p0 + ty) * C + c0 + tx] = f2bf(tile[tx][ty]);
}

// ---------------- main bf16 MFMA GEMM: C[M,N] = A[M,K] * Bt[N,K]^T ----------------
// 1D grid, XCD-swizzled, N-fast ordering (consecutive blocks share the A panel).
// mode 0: split into 3 bf16 outputs by col/256 (qkv). mode 1: +bias, bf16 out.
// mode 2: +bias, accumulate into existing f32 out.
__global__ __launch_bounds__(256) void gemm_bt_kernel(
    const unsigned short* __restrict__ A, const unsigned short* __restrict__ Bt, const int K,
    const int nbn, const int mode, unsigned short* __restrict__ ob0,
    unsigned short* __restrict__ ob1, unsigned short* __restrict__ ob2,
    const float* __restrict__ bias, float* __restrict__ of32) {
  __shared__ unsigned short lA[128 * 64];
  __shared__ unsigned short lB[128 * 64];
  // bijective XCD swizzle (m204), then N-fast decomposition
  const int nwg = gridDim.x;
  const int bid = blockIdx.x;
  const int qd = nwg >> 3, rr = nwg & 7;
  const int xcd = bid & 7, sidx = bid >> 3;
  const int swz = (xcd < rr ? xcd * (qd + 1) : rr * (qd + 1) + (xcd - rr) * qd) + sidx;
  const int m0 = (swz / nbn) * 128;
  const int n0 = (swz % nbn) * 128;
  const int t = threadIdx.x;
  const int w = t >> 6, l = t & 63;
  const int wr = w >> 1, wc = w & 1;
  const int lr = l & 15, lg = l >> 4;

  f32x4 acc[4][4];
#pragma unroll
  for (int i = 0; i < 4; ++i)
#pragma unroll
    for (int j = 0; j < 4; ++j) acc[i][j] = f32x4{0.f, 0.f, 0.f, 0.f};

  for (int k0 = 0; k0 < K; k0 += 64) {
    __syncthreads();
#pragma unroll
    for (int s = 0; s < 4; ++s) {
      const int seg = w * 4 + s;
      const int bo = seg * 1024 + l * 16;  // byte offset within 16KB tile
      const int row = bo >> 7;             // 128B per row (64 bf16)
      const int colb = bo & 127;
      gload_lds16((const char*)A + ((size_t)(m0 + row) * K + k0) * 2 + colb,
                  (char*)lA + seg * 1024);
      gload_lds16((const char*)Bt + ((size_t)(n0 + row) * K + k0) * 2 + colb,
                  (char*)lB + seg * 1024);
    }
    __syncthreads();
#pragma unroll
    for (int kk = 0; kk < 64; kk += 32) {
      bf16x8 af[4], bfr[4];
#pragma unroll
      for (int i = 0; i < 4; ++i)
        af[i] = *(const bf16x8*)&lA[(wr * 64 + i * 16 + lr) * 64 + kk + lg * 8];
#pragma unroll
      for (int j = 0; j < 4; ++j)
        bfr[j] = *(const bf16x8*)&lB[(wc * 64 + j * 16 + lr) * 64 + kk + lg * 8];
#pragma unroll
      for (int i = 0; i < 4; ++i)
#pragma unroll
        for (int j = 0; j < 4; ++j)
          acc[i][j] = __builtin_amdgcn_mfma_f32_16x16x32_bf16(af[i], bfr[j], acc[i][j], 0, 0, 0);
    }
  }
#pragma unroll
  for (int i = 0; i < 4; ++i) {
    const int grow = m0 + wr * 64 + i * 16 + lg * 4;
#pragma unroll
    for (int j = 0; j < 4; ++j) {
      const int gcol = n0 + wc * 64 + j * 16 + lr;
#pragma unroll
      for (int r = 0; r < 4; ++r) {
        const float v = acc[i][j][r];
        const size_t row = (size_t)(grow + r);
        if (mode == 0) {
          unsigned short* dst = (gcol < 256) ? ob0 : (gcol < 512 ? ob1 : ob2);
          dst[row * C + (gcol & 255)] = f2bf(v);
        } else if (mode == 1) {
          ob0[row * C + gcol] = f2bf(v + bias[gcol]);
        } else {
          const size_t idx = row * C + gcol;
          of32[idx] += v + bias[gcol];
        }
      }
    }
  }
}

// ---------------- depthwise 5x5 + sigmoid + mask_emb = m1*(1+a) ----------------
__global__ __launch_bounds__(256) void mask_dw5_kernel(
    const unsigned short* __restrict__ m2, const unsigned short* __restrict__ m1,
    const float* __restrict__ dw, const float* __restrict__ db,
    unsigned short* __restrict__ memb) {
  const int x0 = blockIdx.x * 32;
  const int y = blockIdx.y;
  const int c = threadIdx.x;
  float w[25];
#pragma unroll
  for (int e = 0; e < 25; ++e) w[e] = dw[c * 25 + e];
  const float bias = db[c];
  float col[5][5];  // col[k][dy]: column x-2+k
#pragma unroll
  for (int k = 0; k < 5; ++k) {
    const int xx = x0 - 2 + k;
#pragma unroll
    for (int dy = 0; dy < 5; ++dy) {
      const int yy = y + dy - 2;
      col[k][dy] = (xx >= 0 && xx < HW && yy >= 0 && yy < HW)
                       ? bf2f(m2[((size_t)yy * HW + xx) * C + c])
                       : 0.f;
    }
  }
  for (int xi = 0; xi < 32; ++xi) {
    const int x = x0 + xi;
    float s = bias;
#pragma unroll
    for (int kx = 0; kx < 5; ++kx)
#pragma unroll
      for (int ky = 0; ky < 5; ++ky) s += w[ky * 5 + kx] * col[kx][ky];
    const float a = 1.f / (1.f + expf(-s));
    const size_t oi = ((size_t)y * HW + x) * C + c;
    memb[oi] = f2bf(bf2f(m1[oi]) * (1.f + a));
#pragma unroll
    for (int k = 0; k < 4; ++k)
#pragma unroll
      for (int dy = 0; dy < 5; ++dy) col[k][dy] = col[k + 1][dy];
    const int xn = x + 3;
#pragma unroll
    for (int dy = 0; dy < 5; ++dy) {
      const int yy = y + dy - 2;
      col[4][dy] =
          (xn < HW && yy >= 0 && yy < HW) ? bf2f(m2[((size_t)yy * HW + xn) * C + c]) : 0.f;
    }
  }
}

// ---------------- Gram partials + fused sumsq ----------------
// G[i][j] = sum_n k[n,i]*q[n,j] per (b,h); sumsq of q,k per channel folded into staging.
__global__ __launch_bounds__(256) void gram_kernel(const unsigned short* __restrict__ qb,
                                                   const unsigned short* __restrict__ kb,
                                                   float* __restrict__ Gpart,
                                                   float* __restrict__ ssq,
                                                   float* __restrict__ ssk) {
  const int chunk = blockIdx.x;  // 16
  const int h = blockIdx.y;      // 8
  const int b = blockIdx.z;      // 4
  __shared__ unsigned short lk[128 * 32], lq[128 * 32];
  const int t = threadIdx.x;
  const int wv = t >> 6;
  const int i0 = (t & 7) * 4, j0 = ((t >> 3) & 7) * 4;
  const int lrow = t >> 2, lcb = (t & 3) * 8;
  float acc[4][4] = {};
  float sq[8] = {}, sk[8] = {};
  for (int sub = 0; sub < 8; ++sub) {
    const size_t nbase = (size_t)b * NTOK + chunk * 1024 + sub * 128;
    __syncthreads();
#pragma unroll
    for (int it = 0; it < 2; ++it) {
      const int row = it * 64 + lrow;
      const s16x8 kv8 = *(const s16x8*)&kb[(nbase + row) * C + h * 32 + lcb];
      const s16x8 qv8 = *(const s16x8*)&qb[(nbase + row) * C + h * 32 + lcb];
      *(s16x8*)&lk[row * 32 + lcb] = kv8;
      *(s16x8*)&lq[row * 32 + lcb] = qv8;
#pragma unroll
      for (int e = 0; e < 8; ++e) {
        const float kf = bf2f((unsigned short)kv8[e]);
        sk[e] += kf * kf;
        const float qf = bf2f((unsigned short)qv8[e]);
        sq[e] += qf * qf;
      }
    }
    __syncthreads();
    for (int n = wv; n < 128; n += 4) {
      s16x4 kv = *(const s16x4*)&lk[n * 32 + i0];
      s16x4 qv = *(const s16x4*)&lq[n * 32 + j0];
      float kf[4], qf[4];
#pragma unroll
      for (int e = 0; e < 4; ++e) {
        kf[e] = bf2f((unsigned short)kv[e]);
        qf[e] = bf2f((unsigned short)qv[e]);
      }
#pragma unroll
      for (int a = 0; a < 4; ++a)
#pragma unroll
        for (int bb = 0; bb < 4; ++bb) acc[a][bb] += kf[a] * qf[bb];
    }
  }
  const int pc = chunk * 4 + wv;
  float* dst = Gpart + (((size_t)pc * B + b) * HEADS + h) * 1024;
#pragma unroll
  for (int a = 0; a < 4; ++a)
#pragma unroll
    for (int bb = 0; bb < 4; ++bb) dst[(i0 + a) * 32 + (j0 + bb)] = acc[a][bb];
  // block-wide sumsq reduce (reuse LDS as float buffers)
  __syncthreads();
  float* fq = (float*)lq;
  float* fk = (float*)lk;
#pragma unroll
  for (int e = 0; e < 8; ++e) {
    fq[t * 8 + e] = sq[e];
    fk[t * 8 + e] = sk[e];
  }
  __syncthreads();
  if (t < 32) {
    const int tm = t >> 3, e = t & 7;
    float s1 = 0.f, s2 = 0.f;
    for (int k2 = 0; k2 < 64; ++k2) {
      const int tt = tm + k2 * 4;
      s1 += fq[tt * 8 + e];
      s2 += fk[tt * 8 + e];
    }
    ssq[((size_t)b * 16 + chunk) * C + h * 32 + t] = s1;
    ssk[((size_t)b * 16 + chunk) * C + h * 32 + t] = s2;
  }
}

// ---------------- reduce + normalize + softmax -> attn bf16 ----------------
__global__ __launch_bounds__(256) void softmax_kernel(
    const float* __restrict__ Gpart, const float* __restrict__ ssq,
    const float* __restrict__ ssk, const float* __restrict__ rescale,
    unsigned short* __restrict__ attnb) {
  const int h = blockIdx.x, b = blockIdx.y;
  const int t = threadIdx.x;
  __shared__ float G[1024];
  __shared__ float nq[32], nk[32];
#pragma unroll
  for (int e = 0; e < 4; ++e) {
    const int cell = e * 256 + t;
    float s = 0.f;
    for (int pc = 0; pc < 64; ++pc)
      s += Gpart[(((size_t)pc * B + b) * HEADS + h) * 1024 + cell];
    G[cell] = s;
  }
  if (t < 64) {
    const int d = t & 31;
    const float* ss = (t < 32) ? ssq : ssk;
    float s = 0.f;
    for (int ch = 0; ch < 16; ++ch) s += ss[((size_t)b * 16 + ch) * C + h * 32 + d];
    const float nn = fmaxf(sqrtf(s), 1e-12f);
    if (t < 32) nq[d] = nn;
    else nk[d] = nn;
  }
  __syncthreads();
  if (t < 32) {
    const int i = t;
    const float rs = rescale[h];
    float row[32];
    float mx = -1e30f;
#pragma unroll
    for (int j = 0; j < 32; ++j) {
      const float v = G[i * 32 + j] / (nk[i] * nq[j]) * rs;
      row[j] = v;
      mx = fmaxf(mx, v);
    }
    float sum = 0.f;
#pragma unroll
    for (int j = 0; j < 32; ++j) {
      const float e = expf(row[j] - mx);
      row[j] = e;
      sum += e;
    }
    const float inv = 1.f / sum;
#pragma unroll
    for (int j = 0; j < 32; ++j)
      attnb[(((size_t)b * HEADS + h) * 32 + i) * 32 + j] = f2bf(row[j] * inv);
  }
}

// ---------------- PV: out_pre[n, 32h+i] = sum_j attn[h,i,j] * (v*ma)[n, 32h+j] ----------------
#define PVP 264
#define ATP 40
__global__ __launch_bounds__(256) void pv_kernel(const unsigned short* __restrict__ vb,
                                                 const unsigned short* __restrict__ memb,
                                                 const unsigned short* __restrict__ attnb,
                                                 unsigned short* __restrict__ outp) {
  const int n0 = blockIdx.x * 64;
  const int b = blockIdx.y;
  __shared__ unsigned short vma[64 * PVP];
  __shared__ unsigned short at[HEADS * 32 * ATP];
  const int t = threadIdx.x, w = t >> 6, l = t & 63;
  const int lr = l & 15, lg = l >> 4;
  for (int e = t; e < 8192; e += 256) {
    const int h = e >> 10, ij = e & 1023;
    at[(h * 32 + (ij >> 5)) * ATP + (ij & 31)] = attnb[(size_t)b * 8192 + e];
  }
  {
    const int row = t >> 2, cs = (t & 3) * 64;
#pragma unroll
    for (int i2 = 0; i2 < 8; ++i2) {
      const int c = cs + i2 * 8;
      s16x8 vv = *(const s16x8*)&vb[((size_t)b * NTOK + n0 + row) * C + c];
      s16x8 mm = *(const s16x8*)&memb[(size_t)(n0 + row) * C + c];
      s16x8 o;
#pragma unroll
      for (int e = 0; e < 8; ++e)
        o[e] = (short)f2bf(bf2f((unsigned short)vv[e]) * bf2f((unsigned short)mm[e]));
      *(s16x8*)&vma[row * PVP + c] = o;
    }
  }
  __syncthreads();
  f32x4 acc[4][4];
#pragma unroll
  for (int i = 0; i < 4; ++i)
#pragma unroll
    for (int j = 0; j < 4; ++j) acc[i][j] = f32x4{0.f, 0.f, 0.f, 0.f};
#pragma unroll
  for (int j = 0; j < 4; ++j) {
    const int head = w * 2 + (j >> 1);
    const int colh = (j & 1) * 16 + lr;
    const bf16x8 bfr = *(const bf16x8*)&at[(head * 32 + colh) * ATP + lg * 8];
#pragma unroll
    for (int i = 0; i < 4; ++i) {
      const bf16x8 af = *(const bf16x8*)&vma[(i * 16 + lr) * PVP + head * 32 + lg * 8];
      acc[i][j] = __builtin_amdgcn_mfma_f32_16x16x32_bf16(af, bfr, acc[i][j], 0, 0, 0);
    }
  }
#pragma unroll
  for (int i = 0; i < 4; ++i) {
#pragma unroll
    for (int j = 0; j < 4; ++j) {
      const int head = w * 2 + (j >> 1);
      const int gcol = head * 32 + (j & 1) * 16 + lr;
      const int grow = n0 + i * 16 + lg * 4;
#pragma unroll
      for (int r = 0; r < 4; ++r)
        outp[((size_t)b * NTOK + grow + r) * C + gcol] = f2bf(acc[i][j][r]);
    }
  }
}

// ---------------- depthwise 3x3, 4 channels/thread (optional GELU; bf16 or f32 out) ------
__global__ __launch_bounds__(512) void dw3_kernel(const unsigned short* __restrict__ in,
                                                  const float* __restrict__ wgt,
                                                  unsigned short* __restrict__ out_bf,
                                                  float* __restrict__ out_f32,
                                                  const int do_gelu, const int write_f32) {
  const int y = blockIdx.x;
  const int b = blockIdx.y;
  const int t = threadIdx.x;
  const int cg = (t & 63) * 4;
  const int x0 = (t >> 6) * 16;
  float w[9][4];
#pragma unroll
  for (int e = 0; e < 9; ++e)
#pragma unroll
    for (int ch = 0; ch < 4; ++ch) w[e][ch] = wgt[(cg + ch) * 9 + e];
  const int ym = y - 1, yp = y + 1;
  const bool hm = (ym >= 0), hp = (yp < HW);
  const size_t base = (size_t)b * NTOK * C + cg;
  auto ld4 = [&](int yy, int xx) -> f32x4 {
    const s16x4 v = *(const s16x4*)&in[base + ((size_t)yy * HW + xx) * C];
    f32x4 f;
    f[0] = bf2f((unsigned short)v[0]);
    f[1] = bf2f((unsigned short)v[1]);
    f[2] = bf2f((unsigned short)v[2]);
    f[3] = bf2f((unsigned short)v[3]);
    return f;
  };
  const f32x4 zero = {0.f, 0.f, 0.f, 0.f};
  f32x4 a0, a1, a2, b0, b1, b2;
  if (x0 > 0) {
    a0 = hm ? ld4(ym, x0 - 1) : zero;
    a1 = ld4(y, x0 - 1);
    a2 = hp ? ld4(yp, x0 - 1) : zero;
  } else {
    a0 = a1 = a2 = zero;
  }
  b0 = hm ? ld4(ym, x0) : zero;
  b1 = ld4(y, x0);
  b2 = hp ? ld4(yp, x0) : zero;
  for (int xi = 0; xi < 16; ++xi) {
    const int x = x0 + xi;
    f32x4 c0, c1, c2;
    if (x + 1 < HW) {
      c0 = hm ? ld4(ym, x + 1) : zero;
      c1 = ld4(y, x + 1);
      c2 = hp ? ld4(yp, x + 1) : zero;
    } else {
      c0 = c1 = c2 = zero;
    }
    float res[4];
#pragma unroll
    for (int ch = 0; ch < 4; ++ch) {
      float r = w[0][ch] * a0[ch] + w[1][ch] * b0[ch] + w[2][ch] * c0[ch] +
                w[3][ch] * a1[ch] + w[4][ch] * b1[ch] + w[5][ch] * c1[ch] +
                w[6][ch] * a2[ch] + w[7][ch] * b2[ch] + w[8][ch] * c2[ch];
      if (do_gelu) r = 0.5f * r * (1.f + erff(r * 0.70710678118654752f));
      res[ch] = r;
    }
    const size_t oi = base + ((size_t)y * HW + x) * C;
    if (write_f32) {
      const f32x4 o = {res[0], res[1], res[2], res[3]};
      *(f32x4*)&out_f32[oi] = o;
    } else {
      s16x4 o;
      o[0] = (short)f2bf(res[0]);
      o[1] = (short)f2bf(res[1]);
      o[2] = (short)f2bf(res[2]);
      o[3] = (short)f2bf(res[3]);
      *(s16x4*)&out_bf[oi] = o;
    }
    a0 = b0; a1 = b1; a2 = b2;
    b0 = c0; b1 = c1; b2 = c2;
  }
}

extern "C" void kernel_launch(void* const* d_in, const int* in_sizes, int n_in, void* d_out,
                              int out_size, void* d_ws, size_t ws_size, hipStream_t stream) {
  (void)in_sizes; (void)n_in; (void)out_size; (void)ws_size;
  const float* x = (const float*)d_in[0];
  const float* maskp = (const float*)d_in[1];
  const float* wq = (const float*)d_in[2];
  const float* wk = (const float*)d_in[3];
  const float* wv = (const float*)d_in[4];
  const float* rescale = (const float*)d_in[5];
  const float* wproj = (const float*)d_in[6];
  const float* bproj = (const float*)d_in[7];
  const float* mg_w1 = (const float*)d_in[8];
  const float* mg_b1 = (const float*)d_in[9];
  const float* mg_w2 = (const float*)d_in[10];
  const float* mg_b2 = (const float*)d_in[11];
  const float* mg_dw = (const float*)d_in[12];
  const float* mg_db = (const float*)d_in[13];
  const float* be_w1 = (const float*)d_in[14];
  const float* be_w2 = (const float*)d_in[15];
  float* out = (float*)d_out;
  char* ws = (char*)d_ws;

  unsigned short* xb = (unsigned short*)(ws + 0ull);            // 32MB, later out_pre
  unsigned short* qb = (unsigned short*)(ws + 33554432ull);     // 32MB, later y1
  unsigned short* kb = (unsigned short*)(ws + 67108864ull);     // 32MB
  unsigned short* vb = (unsigned short*)(ws + 100663296ull);    // 32MB
  unsigned short* mT = (unsigned short*)(ws + 134217728ull);    // 8MB, later mask_emb
  unsigned short* m1b = (unsigned short*)(ws + 142606336ull);   // 8MB
  unsigned short* m2b = (unsigned short*)(ws + 150994944ull);   // 8MB, later Gpart
  unsigned short* wqkvT = (unsigned short*)(ws + 159383552ull); // 384KB
  unsigned short* wprojT = (unsigned short*)(ws + 159776768ull);// 128KB
  unsigned short* w1b = (unsigned short*)(ws + 159907840ull);   // 128KB
  unsigned short* w2b = (unsigned short*)(ws + 160038912ull);   // 128KB
  float* ssq = (float*)(ws + 160169984ull);                     // 64KB (16 partials)
  float* ssk = (float*)(ws + 160432128ull);                     // 64KB
  unsigned short* attnb = (unsigned short*)(ws + 160694272ull); // 64KB
  float* Gpart = (float*)m2b;
  unsigned short* memb = mT;
  unsigned short* outpre = xb;
  unsigned short* y1 = qb;

  cast_x_kernel<<<2048, 256, 0, stream>>>(x, xb);
  prep_w_kernel<<<dim3(256, 6), 256, 0, stream>>>(wq, wk, wv, wproj, mg_w1, mg_w2, wqkvT,
                                                  wprojT, w1b, w2b);
  tmask_kernel<<<dim3(512, 8), 1024, 0, stream>>>(maskp, mT);
  // mask branch: m1 = maskT*W1^T+b1 ; m2 = m1*W2^T+b2 ; memb = m1*(1+sigmoid(dw5(m2)+db))
  gemm_bt_kernel<<<256, 256, 0, stream>>>(mT, w1b, 256, 2, 1, m1b, nullptr, nullptr, mg_b1,
                                          nullptr);
  gemm_bt_kernel<<<256, 256, 0, stream>>>(m1b, w2b, 256, 2, 1, m2b, nullptr, nullptr, mg_b2,
                                          nullptr);
  mask_dw5_kernel<<<dim3(4, 128), 256, 0, stream>>>(m2b, m1b, mg_dw, mg_db, memb);
  // q,k,v
  gemm_bt_kernel<<<3072, 256, 0, stream>>>(xb, wqkvT, 256, 6, 0, qb, kb, vb, nullptr, nullptr);
  gram_kernel<<<dim3(16, 8, 4), 256, 0, stream>>>(qb, kb, Gpart, ssq, ssk);
  softmax_kernel<<<dim3(8, 4), 256, 0, stream>>>(Gpart, ssq, ssk, rescale, attnb);
  pv_kernel<<<dim3(256, 4), 256, 0, stream>>>(vb, memb, attnb, outpre);
  // band branch -> writes d_out; proj GEMM accumulates on top
  dw3_kernel<<<dim3(128, 4), 512, 0, stream>>>(vb, be_w1, y1, nullptr, 1, 0);
  dw3_kernel<<<dim3(128, 4), 512, 0, stream>>>(y1, be_w2, nullptr, out, 0, 1);
  gemm_bt_kernel<<<1024, 256, 0, stream>>>(outpre, wprojT, 256, 2, 2, nullptr, nullptr,
                                           nullptr, bproj, out);
}

// Round 3
// 373.079 us; speedup vs baseline: 1.1932x; 1.0337x over previous
//
#include <hip/hip_runtime.h>
#include <stdint.h>

#define B 4
#define HW 128
#define C 256
#define NTOK 16384
#define MALL 65536
#define HEADS 8
#define DH 32

typedef float f32x4 __attribute__((ext_vector_type(4)));
typedef short s16x8 __attribute__((ext_vector_type(8)));
typedef short s16x4 __attribute__((ext_vector_type(4)));
typedef __bf16 bf16x8 __attribute__((ext_vector_type(8)));

__device__ __forceinline__ float bf2f(unsigned short u) {
  union { unsigned int i; float f; } x;
  x.i = ((unsigned int)u) << 16;
  return x.f;
}
__device__ __forceinline__ unsigned short f2bf(float f) {
  union { float f; unsigned int i; } x;
  x.f = f;
  unsigned int lsb = (x.i >> 16) & 1u;
  unsigned int r = x.i + 0x7fffu + lsb;
  return (unsigned short)(r >> 16);
}

__device__ __forceinline__ void gload_lds16(const void* g, void* l) {
  auto gp = reinterpret_cast<const __attribute__((address_space(1))) unsigned int*>(
      reinterpret_cast<uintptr_t>(g));
  auto lp = reinterpret_cast<__attribute__((address_space(3))) unsigned int*>(
      reinterpret_cast<uintptr_t>(l));
  __builtin_amdgcn_global_load_lds(gp, lp, 16, 0, 0);
}

// ---------------- cast x to bf16 ----------------
__global__ __launch_bounds__(256) void cast_x_kernel(const float* __restrict__ x,
                                                     unsigned short* __restrict__ xb) {
  const size_t stride = (size_t)gridDim.x * blockDim.x * 4;
  for (size_t i = ((size_t)blockIdx.x * blockDim.x + threadIdx.x) * 4; i < (size_t)MALL * C;
       i += stride) {
    const float4 v = *(const float4*)&x[i];
    s16x4 o;
    o[0] = (short)f2bf(v.x);
    o[1] = (short)f2bf(v.y);
    o[2] = (short)f2bf(v.z);
    o[3] = (short)f2bf(v.w);
    *(s16x4*)&xb[i] = o;
  }
}

// ---------------- weight prep: transpose+cast ----------------
__global__ __launch_bounds__(256) void prep_w_kernel(
    const float* __restrict__ wq, const float* __restrict__ wk, const float* __restrict__ wv,
    const float* __restrict__ wproj, const float* __restrict__ w1, const float* __restrict__ w2,
    unsigned short* __restrict__ wqkvT, unsigned short* __restrict__ wprojT,
    unsigned short* __restrict__ w1b, unsigned short* __restrict__ w2b) {
  const int idx = blockIdx.x * 256 + threadIdx.x;  // 0..65535
  const int mat = blockIdx.y;
  const int n = idx >> 8, k = idx & 255;
  switch (mat) {
    case 0: wqkvT[idx] = f2bf(wq[k * 256 + n]); break;
    case 1: wqkvT[65536 + idx] = f2bf(wk[k * 256 + n]); break;
    case 2: wqkvT[131072 + idx] = f2bf(wv[k * 256 + n]); break;
    case 3: wprojT[idx] = f2bf(wproj[k * 256 + n]); break;
    case 4: w1b[idx] = f2bf(w1[idx]); break;   // [co][ci] already K-contig
    case 5: w2b[idx] = f2bf(w2[idx]); break;
  }
}

// ---------------- transpose mask [C][N] -> [N][C] bf16 ----------------
__global__ __launch_bounds__(1024) void tmask_kernel(const float* __restrict__ mask,
                                                     unsigned short* __restrict__ mT) {
  __shared__ float tile[32][33];
  const int p0 = blockIdx.x * 32, c0 = blockIdx.y * 32;
  const int tx = threadIdx.x & 31, ty = threadIdx.x >> 5;
  tile[ty][tx] = mask[(size_t)(c0 + ty) * NTOK + p0 + tx];
  __syncthreads();
  mT[(size_t)(p0 + ty) * C + c0 + tx] = f2bf(tile[tx][ty]);
}

// ---------------- main bf16 MFMA GEMM: C[M,N] = A[M,K] * Bt[N,K]^T ----------------
// 1D grid, XCD-swizzled, N-fast ordering. Double-buffered LDS with stage-ahead
// (T3 minimum 2-phase) + T2 XOR slot swizzle (pre-swizzled global source, rule #21).
// mode 0: split into 3 bf16 outputs by col/256 (qkv). mode 1: +bias, bf16 out.
// mode 2: +bias, accumulate into existing f32 out.
__global__ __launch_bounds__(256) void gemm_bt_kernel(
    const unsigned short* __restrict__ A, const unsigned short* __restrict__ Bt, const int K,
    const int nbn, const int mode, unsigned short* __restrict__ ob0,
    unsigned short* __restrict__ ob1, unsigned short* __restrict__ ob2,
    const float* __restrict__ bias, float* __restrict__ of32) {
  __shared__ unsigned short lA[2][128 * 64];
  __shared__ unsigned short lB[2][128 * 64];
  // bijective XCD swizzle (m204), then N-fast decomposition
  const int nwg = gridDim.x;
  const int bid = blockIdx.x;
  const int qd = nwg >> 3, rr = nwg & 7;
  const int xcd = bid & 7, sidx = bid >> 3;
  const int swz = (xcd < rr ? xcd * (qd + 1) : rr * (qd + 1) + (xcd - rr) * qd) + sidx;
  const int m0 = (swz / nbn) * 128;
  const int n0 = (swz % nbn) * 128;
  const int t = threadIdx.x;
  const int w = t >> 6, l = t & 63;
  const int wr = w >> 1, wc = w & 1;
  const int lr = l & 15, lg = l >> 4;

  // staging geometry: each thread writes 16B at LDS-linear (seg*1024 + l*16),
  // seg = w*4+s. LDS row = 64 bf16 = 128B. Lane's LDS row = seg*8 + (l>>3),
  // physical 16B-slot = l&7. Pre-swizzle: fetch logical slot (l&7)^((l>>3)&7).
  const int strow = (l >> 3);           // row-within-seg-group (0..7)
  const int scolb = (((l & 7) ^ strow) << 4);  // swizzled source byte offset in row

  f32x4 acc[4][4];
#pragma unroll
  for (int i = 0; i < 4; ++i)
#pragma unroll
    for (int j = 0; j < 4; ++j) acc[i][j] = f32x4{0.f, 0.f, 0.f, 0.f};

  auto stage = [&](int buf, int k0) {
#pragma unroll
    for (int s = 0; s < 4; ++s) {
      const int seg = w * 4 + s;
      const int row = seg * 8 + strow;
      gload_lds16((const char*)A + ((size_t)(m0 + row) * K + k0) * 2 + scolb,
                  (char*)&lA[buf][0] + seg * 1024 + (l & 7) * 16);
      gload_lds16((const char*)Bt + ((size_t)(n0 + row) * K + k0) * 2 + scolb,
                  (char*)&lB[buf][0] + seg * 1024 + (l & 7) * 16);
    }
  };
  auto compute = [&](int buf) {
#pragma unroll
    for (int kk = 0; kk < 64; kk += 32) {
      bf16x8 af[4], bfr[4];
      const int sbase = (kk >> 3) + lg;     // logical 16B slot (0..7)
      const int p = (sbase ^ (lr & 7)) << 3;  // physical slot -> ushort offset
#pragma unroll
      for (int i = 0; i < 4; ++i)
        af[i] = *(const bf16x8*)&lA[buf][(wr * 64 + i * 16 + lr) * 64 + p];
#pragma unroll
      for (int j = 0; j < 4; ++j)
        bfr[j] = *(const bf16x8*)&lB[buf][(wc * 64 + j * 16 + lr) * 64 + p];
#pragma unroll
      for (int i = 0; i < 4; ++i)
#pragma unroll
        for (int j = 0; j < 4; ++j)
          acc[i][j] = __builtin_amdgcn_mfma_f32_16x16x32_bf16(af[i], bfr[j], acc[i][j], 0, 0, 0);
    }
  };

  stage(0, 0);
  __syncthreads();
  int cur = 0;
  for (int k0 = 64; k0 < K; k0 += 64) {
    stage(cur ^ 1, k0);   // issue next-tile loads (async, in flight across compute)
    compute(cur);
    __syncthreads();      // compiler drains vmcnt(0)+lgkmcnt(0) here
    cur ^= 1;
  }
  compute(cur);

#pragma unroll
  for (int i = 0; i < 4; ++i) {
    const int grow = m0 + wr * 64 + i * 16 + lg * 4;
#pragma unroll
    for (int j = 0; j < 4; ++j) {
      const int gcol = n0 + wc * 64 + j * 16 + lr;
#pragma unroll
      for (int r = 0; r < 4; ++r) {
        const float v = acc[i][j][r];
        const size_t row = (size_t)(grow + r);
        if (mode == 0) {
          unsigned short* dst = (gcol < 256) ? ob0 : (gcol < 512 ? ob1 : ob2);
          dst[row * C + (gcol & 255)] = f2bf(v);
        } else if (mode == 1) {
          ob0[row * C + gcol] = f2bf(v + bias[gcol]);
        } else {
          const size_t idx = row * C + gcol;
          of32[idx] += v + bias[gcol];
        }
      }
    }
  }
}

// ---------------- depthwise 5x5 + sigmoid + mask_emb = m1*(1+a) ----------------
__global__ __launch_bounds__(256) void mask_dw5_kernel(
    const unsigned short* __restrict__ m2, const unsigned short* __restrict__ m1,
    const float* __restrict__ dw, const float* __restrict__ db,
    unsigned short* __restrict__ memb) {
  const int x0 = blockIdx.x * 32;
  const int y = blockIdx.y;
  const int c = threadIdx.x;
  float w[25];
#pragma unroll
  for (int e = 0; e < 25; ++e) w[e] = dw[c * 25 + e];
  const float bias = db[c];
  float col[5][5];  // col[k][dy]: column x-2+k
#pragma unroll
  for (int k = 0; k < 5; ++k) {
    const int xx = x0 - 2 + k;
#pragma unroll
    for (int dy = 0; dy < 5; ++dy) {
      const int yy = y + dy - 2;
      col[k][dy] = (xx >= 0 && xx < HW && yy >= 0 && yy < HW)
                       ? bf2f(m2[((size_t)yy * HW + xx) * C + c])
                       : 0.f;
    }
  }
  for (int xi = 0; xi < 32; ++xi) {
    const int x = x0 + xi;
    float s = bias;
#pragma unroll
    for (int kx = 0; kx < 5; ++kx)
#pragma unroll
      for (int ky = 0; ky < 5; ++ky) s += w[ky * 5 + kx] * col[kx][ky];
    const float a = 1.f / (1.f + expf(-s));
    const size_t oi = ((size_t)y * HW + x) * C + c;
    memb[oi] = f2bf(bf2f(m1[oi]) * (1.f + a));
#pragma unroll
    for (int k = 0; k < 4; ++k)
#pragma unroll
      for (int dy = 0; dy < 5; ++dy) col[k][dy] = col[k + 1][dy];
    const int xn = x + 3;
#pragma unroll
    for (int dy = 0; dy < 5; ++dy) {
      const int yy = y + dy - 2;
      col[4][dy] =
          (xn < HW && yy >= 0 && yy < HW) ? bf2f(m2[((size_t)yy * HW + xn) * C + c]) : 0.f;
    }
  }
}

// ---------------- Gram partials + fused sumsq ----------------
// G[i][j] = sum_n k[n,i]*q[n,j] per (b,h); sumsq of q,k per channel folded into staging.
__global__ __launch_bounds__(256) void gram_kernel(const unsigned short* __restrict__ qb,
                                                   const unsigned short* __restrict__ kb,
                                                   float* __restrict__ Gpart,
                                                   float* __restrict__ ssq,
                                                   float* __restrict__ ssk) {
  const int chunk = blockIdx.x;  // 16
  const int h = blockIdx.y;      // 8
  const int b = blockIdx.z;      // 4
  __shared__ unsigned short lk[128 * 32], lq[128 * 32];
  const int t = threadIdx.x;
  const int wv = t >> 6;
  const int i0 = (t & 7) * 4, j0 = ((t >> 3) & 7) * 4;
  const int lrow = t >> 2, lcb = (t & 3) * 8;
  float acc[4][4] = {};
  float sq[8] = {}, sk[8] = {};
  for (int sub = 0; sub < 8; ++sub) {
    const size_t nbase = (size_t)b * NTOK + chunk * 1024 + sub * 128;
    __syncthreads();
#pragma unroll
    for (int it = 0; it < 2; ++it) {
      const int row = it * 64 + lrow;
      const s16x8 kv8 = *(const s16x8*)&kb[(nbase + row) * C + h * 32 + lcb];
      const s16x8 qv8 = *(const s16x8*)&qb[(nbase + row) * C + h * 32 + lcb];
      *(s16x8*)&lk[row * 32 + lcb] = kv8;
      *(s16x8*)&lq[row * 32 + lcb] = qv8;
#pragma unroll
      for (int e = 0; e < 8; ++e) {
        const float kf = bf2f((unsigned short)kv8[e]);
        sk[e] += kf * kf;
        const float qf = bf2f((unsigned short)qv8[e]);
        sq[e] += qf * qf;
      }
    }
    __syncthreads();
    for (int n = wv; n < 128; n += 4) {
      s16x4 kv = *(const s16x4*)&lk[n * 32 + i0];
      s16x4 qv = *(const s16x4*)&lq[n * 32 + j0];
      float kf[4], qf[4];
#pragma unroll
      for (int e = 0; e < 4; ++e) {
        kf[e] = bf2f((unsigned short)kv[e]);
        qf[e] = bf2f((unsigned short)qv[e]);
      }
#pragma unroll
      for (int a = 0; a < 4; ++a)
#pragma unroll
        for (int bb = 0; bb < 4; ++bb) acc[a][bb] += kf[a] * qf[bb];
    }
  }
  const int pc = chunk * 4 + wv;
  float* dst = Gpart + (((size_t)pc * B + b) * HEADS + h) * 1024;
#pragma unroll
  for (int a = 0; a < 4; ++a)
#pragma unroll
    for (int bb = 0; bb < 4; ++bb) dst[(i0 + a) * 32 + (j0 + bb)] = acc[a][bb];
  // block-wide sumsq reduce (reuse LDS as float buffers)
  __syncthreads();
  float* fq = (float*)lq;
  float* fk = (float*)lk;
#pragma unroll
  for (int e = 0; e < 8; ++e) {
    fq[t * 8 + e] = sq[e];
    fk[t * 8 + e] = sk[e];
  }
  __syncthreads();
  if (t < 32) {
    const int tm = t >> 3, e = t & 7;
    float s1 = 0.f, s2 = 0.f;
    for (int k2 = 0; k2 < 64; ++k2) {
      const int tt = tm + k2 * 4;
      s1 += fq[tt * 8 + e];
      s2 += fk[tt * 8 + e];
    }
    ssq[((size_t)b * 16 + chunk) * C + h * 32 + t] = s1;
    ssk[((size_t)b * 16 + chunk) * C + h * 32 + t] = s2;
  }
}

// ---------------- reduce + normalize + softmax -> attn bf16 ----------------
__global__ __launch_bounds__(256) void softmax_kernel(
    const float* __restrict__ Gpart, const float* __restrict__ ssq,
    const float* __restrict__ ssk, const float* __restrict__ rescale,
    unsigned short* __restrict__ attnb) {
  const int h = blockIdx.x, b = blockIdx.y;
  const int t = threadIdx.x;
  __shared__ float G[1024];
  __shared__ float nq[32], nk[32];
#pragma unroll
  for (int e = 0; e < 4; ++e) {
    const int cell = e * 256 + t;
    float s = 0.f;
    for (int pc = 0; pc < 64; ++pc)
      s += Gpart[(((size_t)pc * B + b) * HEADS + h) * 1024 + cell];
    G[cell] = s;
  }
  if (t < 64) {
    const int d = t & 31;
    const float* ss = (t < 32) ? ssq : ssk;
    float s = 0.f;
    for (int ch = 0; ch < 16; ++ch) s += ss[((size_t)b * 16 + ch) * C + h * 32 + d];
    const float nn = fmaxf(sqrtf(s), 1e-12f);
    if (t < 32) nq[d] = nn;
    else nk[d] = nn;
  }
  __syncthreads();
  if (t < 32) {
    const int i = t;
    const float rs = rescale[h];
    float row[32];
    float mx = -1e30f;
#pragma unroll
    for (int j = 0; j < 32; ++j) {
      const float v = G[i * 32 + j] / (nk[i] * nq[j]) * rs;
      row[j] = v;
      mx = fmaxf(mx, v);
    }
    float sum = 0.f;
#pragma unroll
    for (int j = 0; j < 32; ++j) {
      const float e = expf(row[j] - mx);
      row[j] = e;
      sum += e;
    }
    const float inv = 1.f / sum;
#pragma unroll
    for (int j = 0; j < 32; ++j)
      attnb[(((size_t)b * HEADS + h) * 32 + i) * 32 + j] = f2bf(row[j] * inv);
  }
}

// ---------------- PV: out_pre[n, 32h+i] = sum_j attn[h,i,j] * (v*ma)[n, 32h+j] ----------------
#define PVP 264
#define ATP 40
__global__ __launch_bounds__(256) void pv_kernel(const unsigned short* __restrict__ vb,
                                                 const unsigned short* __restrict__ memb,
                                                 const unsigned short* __restrict__ attnb,
                                                 unsigned short* __restrict__ outp) {
  const int n0 = blockIdx.x * 64;
  const int b = blockIdx.y;
  __shared__ unsigned short vma[64 * PVP];
  __shared__ unsigned short at[HEADS * 32 * ATP];
  const int t = threadIdx.x, w = t >> 6, l = t & 63;
  const int lr = l & 15, lg = l >> 4;
  for (int e = t; e < 8192; e += 256) {
    const int h = e >> 10, ij = e & 1023;
    at[(h * 32 + (ij >> 5)) * ATP + (ij & 31)] = attnb[(size_t)b * 8192 + e];
  }
  {
    const int row = t >> 2, cs = (t & 3) * 64;
#pragma unroll
    for (int i2 = 0; i2 < 8; ++i2) {
      const int c = cs + i2 * 8;
      s16x8 vv = *(const s16x8*)&vb[((size_t)b * NTOK + n0 + row) * C + c];
      s16x8 mm = *(const s16x8*)&memb[(size_t)(n0 + row) * C + c];
      s16x8 o;
#pragma unroll
      for (int e = 0; e < 8; ++e)
        o[e] = (short)f2bf(bf2f((unsigned short)vv[e]) * bf2f((unsigned short)mm[e]));
      *(s16x8*)&vma[row * PVP + c] = o;
    }
  }
  __syncthreads();
  f32x4 acc[4][4];
#pragma unroll
  for (int i = 0; i < 4; ++i)
#pragma unroll
    for (int j = 0; j < 4; ++j) acc[i][j] = f32x4{0.f, 0.f, 0.f, 0.f};
#pragma unroll
  for (int j = 0; j < 4; ++j) {
    const int head = w * 2 + (j >> 1);
    const int colh = (j & 1) * 16 + lr;
    const bf16x8 bfr = *(const bf16x8*)&at[(head * 32 + colh) * ATP + lg * 8];
#pragma unroll
    for (int i = 0; i < 4; ++i) {
      const bf16x8 af = *(const bf16x8*)&vma[(i * 16 + lr) * PVP + head * 32 + lg * 8];
      acc[i][j] = __builtin_amdgcn_mfma_f32_16x16x32_bf16(af, bfr, acc[i][j], 0, 0, 0);
    }
  }
#pragma unroll
  for (int i = 0; i < 4; ++i) {
#pragma unroll
    for (int j = 0; j < 4; ++j) {
      const int head = w * 2 + (j >> 1);
      const int gcol = head * 32 + (j & 1) * 16 + lr;
      const int grow = n0 + i * 16 + lg * 4;
#pragma unroll
      for (int r = 0; r < 4; ++r)
        outp[((size_t)b * NTOK + grow + r) * C + gcol] = f2bf(acc[i][j][r]);
    }
  }
}

// ---------------- depthwise 3x3, 4 channels/thread (optional GELU; bf16 or f32 out) ------
__global__ __launch_bounds__(512) void dw3_kernel(const unsigned short* __restrict__ in,
                                                  const float* __restrict__ wgt,
                                                  unsigned short* __restrict__ out_bf,
                                                  float* __restrict__ out_f32,
                                                  const int do_gelu, const int write_f32) {
  const int y = blockIdx.x;
  const int b = blockIdx.y;
  const int t = threadIdx.x;
  const int cg = (t & 63) * 4;
  const int x0 = (t >> 6) * 16;
  float w[9][4];
#pragma unroll
  for (int e = 0; e < 9; ++e)
#pragma unroll
    for (int ch = 0; ch < 4; ++ch) w[e][ch] = wgt[(cg + ch) * 9 + e];
  const int ym = y - 1, yp = y + 1;
  const bool hm = (ym >= 0), hp = (yp < HW);
  const size_t base = (size_t)b * NTOK * C + cg;
  auto ld4 = [&](int yy, int xx) -> f32x4 {
    const s16x4 v = *(const s16x4*)&in[base + ((size_t)yy * HW + xx) * C];
    f32x4 f;
    f[0] = bf2f((unsigned short)v[0]);
    f[1] = bf2f((unsigned short)v[1]);
    f[2] = bf2f((unsigned short)v[2]);
    f[3] = bf2f((unsigned short)v[3]);
    return f;
  };
  const f32x4 zero = {0.f, 0.f, 0.f, 0.f};
  f32x4 a0, a1, a2, b0, b1, b2;
  if (x0 > 0) {
    a0 = hm ? ld4(ym, x0 - 1) : zero;
    a1 = ld4(y, x0 - 1);
    a2 = hp ? ld4(yp, x0 - 1) : zero;
  } else {
    a0 = a1 = a2 = zero;
  }
  b0 = hm ? ld4(ym, x0) : zero;
  b1 = ld4(y, x0);
  b2 = hp ? ld4(yp, x0) : zero;
  for (int xi = 0; xi < 16; ++xi) {
    const int x = x0 + xi;
    f32x4 c0, c1, c2;
    if (x + 1 < HW) {
      c0 = hm ? ld4(ym, x + 1) : zero;
      c1 = ld4(y, x + 1);
      c2 = hp ? ld4(yp, x + 1) : zero;
    } else {
      c0 = c1 = c2 = zero;
    }
    float res[4];
#pragma unroll
    for (int ch = 0; ch < 4; ++ch) {
      float r = w[0][ch] * a0[ch] + w[1][ch] * b0[ch] + w[2][ch] * c0[ch] +
                w[3][ch] * a1[ch] + w[4][ch] * b1[ch] + w[5][ch] * c1[ch] +
                w[6][ch] * a2[ch] + w[7][ch] * b2[ch] + w[8][ch] * c2[ch];
      if (do_gelu) r = 0.5f * r * (1.f + erff(r * 0.70710678118654752f));
      res[ch] = r;
    }
    const size_t oi = base + ((size_t)y * HW + x) * C;
    if (write_f32) {
      const f32x4 o = {res[0], res[1], res[2], res[3]};
      *(f32x4*)&out_f32[oi] = o;
    } else {
      s16x4 o;
      o[0] = (short)f2bf(res[0]);
      o[1] = (short)f2bf(res[1]);
      o[2] = (short)f2bf(res[2]);
      o[3] = (short)f2bf(res[3]);
      *(s16x4*)&out_bf[oi] = o;
    }
    a0 = b0; a1 = b1; a2 = b2;
    b0 = c0; b1 = c1; b2 = c2;
  }
}

extern "C" void kernel_launch(void* const* d_in, const int* in_sizes, int n_in, void* d_out,
                              int out_size, void* d_ws, size_t ws_size, hipStream_t stream) {
  (void)in_sizes; (void)n_in; (void)out_size; (void)ws_size;
  const float* x = (const float*)d_in[0];
  const float* maskp = (const float*)d_in[1];
  const float* wq = (const float*)d_in[2];
  const float* wk = (const float*)d_in[3];
  const float* wv = (const float*)d_in[4];
  const float* rescale = (const float*)d_in[5];
  const float* wproj = (const float*)d_in[6];
  const float* bproj = (const float*)d_in[7];
  const float* mg_w1 = (const float*)d_in[8];
  const float* mg_b1 = (const float*)d_in[9];
  const float* mg_w2 = (const float*)d_in[10];
  const float* mg_b2 = (const float*)d_in[11];
  const float* mg_dw = (const float*)d_in[12];
  const float* mg_db = (const float*)d_in[13];
  const float* be_w1 = (const float*)d_in[14];
  const float* be_w2 = (const float*)d_in[15];
  float* out = (float*)d_out;
  char* ws = (char*)d_ws;

  unsigned short* xb = (unsigned short*)(ws + 0ull);            // 32MB, later out_pre
  unsigned short* qb = (unsigned short*)(ws + 33554432ull);     // 32MB, later y1
  unsigned short* kb = (unsigned short*)(ws + 67108864ull);     // 32MB
  unsigned short* vb = (unsigned short*)(ws + 100663296ull);    // 32MB
  unsigned short* mT = (unsigned short*)(ws + 134217728ull);    // 8MB, later mask_emb
  unsigned short* m1b = (unsigned short*)(ws + 142606336ull);   // 8MB
  unsigned short* m2b = (unsigned short*)(ws + 150994944ull);   // 8MB, later Gpart
  unsigned short* wqkvT = (unsigned short*)(ws + 159383552ull); // 384KB
  unsigned short* wprojT = (unsigned short*)(ws + 159776768ull);// 128KB
  unsigned short* w1b = (unsigned short*)(ws + 159907840ull);   // 128KB
  unsigned short* w2b = (unsigned short*)(ws + 160038912ull);   // 128KB
  float* ssq = (float*)(ws + 160169984ull);                     // 64KB (16 partials)
  float* ssk = (float*)(ws + 160432128ull);                     // 64KB
  unsigned short* attnb = (unsigned short*)(ws + 160694272ull); // 64KB
  float* Gpart = (float*)m2b;
  unsigned short* memb = mT;
  unsigned short* outpre = xb;
  unsigned short* y1 = qb;

  cast_x_kernel<<<2048, 256, 0, stream>>>(x, xb);
  prep_w_kernel<<<dim3(256, 6), 256, 0, stream>>>(wq, wk, wv, wproj, mg_w1, mg_w2, wqkvT,
                                                  wprojT, w1b, w2b);
  tmask_kernel<<<dim3(512, 8), 1024, 0, stream>>>(maskp, mT);
  // mask branch: m1 = maskT*W1^T+b1 ; m2 = m1*W2^T+b2 ; memb = m1*(1+sigmoid(dw5(m2)+db))
  gemm_bt_kernel<<<256, 256, 0, stream>>>(mT, w1b, 256, 2, 1, m1b, nullptr, nullptr, mg_b1,
                                          nullptr);
  gemm_bt_kernel<<<256, 256, 0, stream>>>(m1b, w2b, 256, 2, 1, m2b, nullptr, nullptr, mg_b2,
                                          nullptr);
  mask_dw5_kernel<<<dim3(4, 128), 256, 0, stream>>>(m2b, m1b, mg_dw, mg_db, memb);
  // q,k,v
  gemm_bt_kernel<<<3072, 256, 0, stream>>>(xb, wqkvT, 256, 6, 0, qb, kb, vb, nullptr, nullptr);
  gram_kernel<<<dim3(16, 8, 4), 256, 0, stream>>>(qb, kb, Gpart, ssq, ssk);
  softmax_kernel<<<dim3(8, 4), 256, 0, stream>>>(Gpart, ssq, ssk, rescale, attnb);
  pv_kernel<<<dim3(256, 4), 256, 0, stream>>>(vb, memb, attnb, outpre);
  // band branch -> writes d_out; proj GEMM accumulates on top
  dw3_kernel<<<dim3(128, 4), 512, 0, stream>>>(vb, be_w1, y1, nullptr, 1, 0);
  dw3_kernel<<<dim3(128, 4), 512, 0, stream>>>(y1, be_w2, nullptr, out, 0, 1);
  gemm_bt_kernel<<<1024, 256, 0, stream>>>(outpre, wprojT, 256, 2, 2, nullptr, nullptr,
                                           nullptr, bproj, out);
}

// Round 4
// 347.956 us; speedup vs baseline: 1.2793x; 1.0722x over previous
//
#include <hip/hip_runtime.h>
#include <stdint.h>

#define B 4
#define HW 128
#define C 256
#define NTOK 16384
#define MALL 65536
#define HEADS 8
#define DH 32

typedef float f32x4 __attribute__((ext_vector_type(4)));
typedef short s16x8 __attribute__((ext_vector_type(8)));
typedef short s16x4 __attribute__((ext_vector_type(4)));
typedef __bf16 bf16x8 __attribute__((ext_vector_type(8)));

__device__ __forceinline__ float bf2f(unsigned short u) {
  union { unsigned int i; float f; } x;
  x.i = ((unsigned int)u) << 16;
  return x.f;
}
__device__ __forceinline__ unsigned short f2bf(float f) {
  union { float f; unsigned int i; } x;
  x.f = f;
  unsigned int lsb = (x.i >> 16) & 1u;
  unsigned int r = x.i + 0x7fffu + lsb;
  return (unsigned short)(r >> 16);
}

__device__ __forceinline__ void gload_lds16(const void* g, void* l) {
  auto gp = reinterpret_cast<const __attribute__((address_space(1))) unsigned int*>(
      reinterpret_cast<uintptr_t>(g));
  auto lp = reinterpret_cast<__attribute__((address_space(3))) unsigned int*>(
      reinterpret_cast<uintptr_t>(l));
  __builtin_amdgcn_global_load_lds(gp, lp, 16, 0, 0);
}

#define CFENCE asm volatile("" ::: "memory")
#define RAWBAR()                      \
  do {                                \
    CFENCE;                           \
    __builtin_amdgcn_s_barrier();     \
    CFENCE;                           \
  } while (0)

// ---------------- cast x to bf16 ----------------
__global__ __launch_bounds__(256) void cast_x_kernel(const float* __restrict__ x,
                                                     unsigned short* __restrict__ xb) {
  const size_t stride = (size_t)gridDim.x * blockDim.x * 4;
  for (size_t i = ((size_t)blockIdx.x * blockDim.x + threadIdx.x) * 4; i < (size_t)MALL * C;
       i += stride) {
    const float4 v = *(const float4*)&x[i];
    s16x4 o;
    o[0] = (short)f2bf(v.x);
    o[1] = (short)f2bf(v.y);
    o[2] = (short)f2bf(v.z);
    o[3] = (short)f2bf(v.w);
    *(s16x4*)&xb[i] = o;
  }
}

// ---------------- weight prep: transpose+cast ----------------
__global__ __launch_bounds__(256) void prep_w_kernel(
    const float* __restrict__ wq, const float* __restrict__ wk, const float* __restrict__ wv,
    const float* __restrict__ wproj, const float* __restrict__ w1, const float* __restrict__ w2,
    unsigned short* __restrict__ wqkvT, unsigned short* __restrict__ wprojT,
    unsigned short* __restrict__ w1b, unsigned short* __restrict__ w2b) {
  const int idx = blockIdx.x * 256 + threadIdx.x;  // 0..65535
  const int mat = blockIdx.y;
  const int n = idx >> 8, k = idx & 255;
  switch (mat) {
    case 0: wqkvT[idx] = f2bf(wq[k * 256 + n]); break;
    case 1: wqkvT[65536 + idx] = f2bf(wk[k * 256 + n]); break;
    case 2: wqkvT[131072 + idx] = f2bf(wv[k * 256 + n]); break;
    case 3: wprojT[idx] = f2bf(wproj[k * 256 + n]); break;
    case 4: w1b[idx] = f2bf(w1[idx]); break;   // [co][ci] already K-contig
    case 5: w2b[idx] = f2bf(w2[idx]); break;
  }
}

// ---------------- transpose mask [C][N] -> [N][C] bf16 ----------------
__global__ __launch_bounds__(1024) void tmask_kernel(const float* __restrict__ mask,
                                                     unsigned short* __restrict__ mT) {
  __shared__ float tile[32][33];
  const int p0 = blockIdx.x * 32, c0 = blockIdx.y * 32;
  const int tx = threadIdx.x & 31, ty = threadIdx.x >> 5;
  tile[ty][tx] = mask[(size_t)(c0 + ty) * NTOK + p0 + tx];
  __syncthreads();
  mT[(size_t)(p0 + ty) * C + c0 + tx] = f2bf(tile[tx][ty]);
}

// ================ 256x256 8-wave pipelined GEMM, K=256 fixed ================
// C[M,256panel] = A[M,256] * Bt[Npanel,256]^T. BK=32, 8 K-tiles, 3-buf LDS,
// prefetch distance 2, counted vmcnt(4), raw barriers, setprio MFMA clusters.
// mode 0: bf16 out selected by n0/256 (qkv). mode 2: of32 += v + bias.
__global__ __launch_bounds__(512) void gemm_bt256_kernel(
    const unsigned short* __restrict__ A, const unsigned short* __restrict__ Bt,
    const int nbn, const int mode, unsigned short* __restrict__ ob0,
    unsigned short* __restrict__ ob1, unsigned short* __restrict__ ob2,
    const float* __restrict__ bias, float* __restrict__ of32) {
  __shared__ unsigned short lA[3][8192];  // [buf][half*4096 + row*32 + k]
  __shared__ unsigned short lB[3][8192];
  const int nwg = gridDim.x;
  const int bid = blockIdx.x;
  const int qd = nwg >> 3, rr = nwg & 7;
  const int xcd = bid & 7, sidx = bid >> 3;
  const int swz = (xcd < rr ? xcd * (qd + 1) : rr * (qd + 1) + (xcd - rr) * qd) + sidx;
  const int m0 = (swz / nbn) * 256;
  const int n0 = (swz % nbn) * 256;
  const int t = threadIdx.x;
  const int w = t >> 6, l = t & 63;
  const int wr = w >> 2, wc = w & 3;   // wave grid 2(M) x 4(N)
  const int lr = l & 15, lg = l >> 4;

  // staging: thread t covers LDS bytes t*16 of an 8KB matrix-half.
  // LDS row = t>>2 (32 ushorts/row), physical slot = t&3.
  // source logical slot = (t&3) ^ ((row>>1)&3) = (t&3) ^ ((t>>3)&3).
  const int srow = t >> 2;
  const int ssl = (t & 3) ^ ((t >> 3) & 3);

  auto stageA = [&](int kt) {
    unsigned short* d = &lA[kt % 3][0];
    const size_t kb = ((size_t)kt * 32 + ssl * 8) * 2;  // byte k-offset
    gload_lds16((const char*)A + ((size_t)(m0 + srow) * 256) * 2 + kb, (char*)d + t * 16);
    gload_lds16((const char*)A + ((size_t)(m0 + 128 + srow) * 256) * 2 + kb,
                (char*)d + 8192 + t * 16);
  };
  auto stageB = [&](int kt) {
    unsigned short* d = &lB[kt % 3][0];
    const size_t kb = ((size_t)kt * 32 + ssl * 8) * 2;
    gload_lds16((const char*)Bt + ((size_t)(n0 + srow) * 256) * 2 + kb, (char*)d + t * 16);
    gload_lds16((const char*)Bt + ((size_t)(n0 + 128 + srow) * 256) * 2 + kb,
                (char*)d + 8192 + t * 16);
  };

  f32x4 acc[8][4];
#pragma unroll
  for (int m = 0; m < 8; ++m)
#pragma unroll
    for (int j = 0; j < 4; ++j) acc[m][j] = f32x4{0.f, 0.f, 0.f, 0.f};

  // read-side swizzled slot offset (ushorts): logical slot lg at row ..+lr
  const int asl = (lg ^ ((lr >> 1) & 3)) * 8;
  const int aoff = wr * 4096 + lr * 32 + asl;                    // A frag m: + m*512
  const int boff = (wc >> 1) * 4096 + ((wc & 1) * 64 + lr) * 32 + asl;  // B frag j: + j*512

  // prologue: stage K-tiles 0,1 ; wait tile 0 ; barrier
  stageA(0); stageB(0); stageA(1); stageB(1);
  asm volatile("s_waitcnt vmcnt(4)" ::: "memory");
  RAWBAR();

#pragma unroll
  for (int kt = 0; kt < 8; ++kt) {
    const int buf = kt % 3;
    // ---- phase 0: B frags + A frags 0..3, stage A of kt+2, MFMA quadrant 0 ----
    bf16x8 bfr[4], af[4];
#pragma unroll
    for (int j = 0; j < 4; ++j) bfr[j] = *(const bf16x8*)&lB[buf][boff + j * 512];
#pragma unroll
    for (int m = 0; m < 4; ++m) af[m] = *(const bf16x8*)&lA[buf][aoff + m * 512];
    if (kt < 6) stageA(kt + 2);
    RAWBAR();
    __builtin_amdgcn_s_setprio(1);
#pragma unroll
    for (int m = 0; m < 4; ++m)
#pragma unroll
      for (int j = 0; j < 4; ++j)
        acc[m][j] = __builtin_amdgcn_mfma_f32_16x16x32_bf16(af[m], bfr[j], acc[m][j], 0, 0, 0);
    __builtin_amdgcn_s_setprio(0);
    RAWBAR();
    // ---- phase 1: A frags 4..7, stage B of kt+2, MFMA quadrant 1 ----
#pragma unroll
    for (int m = 0; m < 4; ++m) af[m] = *(const bf16x8*)&lA[buf][aoff + (m + 4) * 512];
    if (kt < 6) stageB(kt + 2);
    RAWBAR();
    __builtin_amdgcn_s_setprio(1);
#pragma unroll
    for (int m = 0; m < 4; ++m)
#pragma unroll
      for (int j = 0; j < 4; ++j)
        acc[m + 4][j] =
            __builtin_amdgcn_mfma_f32_16x16x32_bf16(af[m], bfr[j], acc[m + 4][j], 0, 0, 0);
    __builtin_amdgcn_s_setprio(0);
    // counted drain: next tile's loads (issued last iter) must be done in ALL
    // waves before any wave passes the barrier below and starts ds_reads.
    if (kt < 6) asm volatile("s_waitcnt vmcnt(4)" ::: "memory");
    else asm volatile("s_waitcnt vmcnt(0)" ::: "memory");
    RAWBAR();
  }

#pragma unroll
  for (int m = 0; m < 8; ++m) {
    const int grow = m0 + wr * 128 + m * 16 + lg * 4;
#pragma unroll
    for (int j = 0; j < 4; ++j) {
      const int gcol = n0 + wc * 64 + j * 16 + lr;
#pragma unroll
      for (int r = 0; r < 4; ++r) {
        const float v = acc[m][j][r];
        const size_t row = (size_t)(grow + r);
        if (mode == 0) {
          unsigned short* dst = (n0 < 256) ? ob0 : (n0 < 512 ? ob1 : ob2);
          dst[row * C + (gcol & 255)] = f2bf(v);
        } else {
          const size_t idx = row * C + gcol;
          of32[idx] += v + bias[gcol];
        }
      }
    }
  }
}

// ---------------- 2-phase 128x128 GEMM (kept for small mask GEMMs) ----------------
__global__ __launch_bounds__(256) void gemm_bt_kernel(
    const unsigned short* __restrict__ A, const unsigned short* __restrict__ Bt, const int K,
    const int nbn, const int mode, unsigned short* __restrict__ ob0,
    unsigned short* __restrict__ ob1, unsigned short* __restrict__ ob2,
    const float* __restrict__ bias, float* __restrict__ of32) {
  __shared__ unsigned short lA[2][128 * 64];
  __shared__ unsigned short lB[2][128 * 64];
  const int nwg = gridDim.x;
  const int bid = blockIdx.x;
  const int qd = nwg >> 3, rr = nwg & 7;
  const int xcd = bid & 7, sidx = bid >> 3;
  const int swz = (xcd < rr ? xcd * (qd + 1) : rr * (qd + 1) + (xcd - rr) * qd) + sidx;
  const int m0 = (swz / nbn) * 128;
  const int n0 = (swz % nbn) * 128;
  const int t = threadIdx.x;
  const int w = t >> 6, l = t & 63;
  const int wr = w >> 1, wc = w & 1;
  const int lr = l & 15, lg = l >> 4;

  const int strow = (l >> 3);
  const int scolb = (((l & 7) ^ strow) << 4);

  f32x4 acc[4][4];
#pragma unroll
  for (int i = 0; i < 4; ++i)
#pragma unroll
    for (int j = 0; j < 4; ++j) acc[i][j] = f32x4{0.f, 0.f, 0.f, 0.f};

  auto stage = [&](int buf, int k0) {
#pragma unroll
    for (int s = 0; s < 4; ++s) {
      const int seg = w * 4 + s;
      const int row = seg * 8 + strow;
      gload_lds16((const char*)A + ((size_t)(m0 + row) * K + k0) * 2 + scolb,
                  (char*)&lA[buf][0] + seg * 1024 + (l & 7) * 16);
      gload_lds16((const char*)Bt + ((size_t)(n0 + row) * K + k0) * 2 + scolb,
                  (char*)&lB[buf][0] + seg * 1024 + (l & 7) * 16);
    }
  };
  auto compute = [&](int buf) {
#pragma unroll
    for (int kk = 0; kk < 64; kk += 32) {
      bf16x8 af[4], bfr[4];
      const int sbase = (kk >> 3) + lg;
      const int p = (sbase ^ (lr & 7)) << 3;
#pragma unroll
      for (int i = 0; i < 4; ++i)
        af[i] = *(const bf16x8*)&lA[buf][(wr * 64 + i * 16 + lr) * 64 + p];
#pragma unroll
      for (int j = 0; j < 4; ++j)
        bfr[j] = *(const bf16x8*)&lB[buf][(wc * 64 + j * 16 + lr) * 64 + p];
#pragma unroll
      for (int i = 0; i < 4; ++i)
#pragma unroll
        for (int j = 0; j < 4; ++j)
          acc[i][j] = __builtin_amdgcn_mfma_f32_16x16x32_bf16(af[i], bfr[j], acc[i][j], 0, 0, 0);
    }
  };

  stage(0, 0);
  __syncthreads();
  int cur = 0;
  for (int k0 = 64; k0 < K; k0 += 64) {
    stage(cur ^ 1, k0);
    compute(cur);
    __syncthreads();
    cur ^= 1;
  }
  compute(cur);

#pragma unroll
  for (int i = 0; i < 4; ++i) {
    const int grow = m0 + wr * 64 + i * 16 + lg * 4;
#pragma unroll
    for (int j = 0; j < 4; ++j) {
      const int gcol = n0 + wc * 64 + j * 16 + lr;
#pragma unroll
      for (int r = 0; r < 4; ++r) {
        const float v = acc[i][j][r];
        const size_t row = (size_t)(grow + r);
        if (mode == 0) {
          unsigned short* dst = (gcol < 256) ? ob0 : (gcol < 512 ? ob1 : ob2);
          dst[row * C + (gcol & 255)] = f2bf(v);
        } else if (mode == 1) {
          ob0[row * C + gcol] = f2bf(v + bias[gcol]);
        } else {
          const size_t idx = row * C + gcol;
          of32[idx] += v + bias[gcol];
        }
      }
    }
  }
}

// ---------------- depthwise 5x5 + sigmoid + mask_emb = m1*(1+a) ----------------
__global__ __launch_bounds__(256) void mask_dw5_kernel(
    const unsigned short* __restrict__ m2, const unsigned short* __restrict__ m1,
    const float* __restrict__ dw, const float* __restrict__ db,
    unsigned short* __restrict__ memb) {
  const int x0 = blockIdx.x * 32;
  const int y = blockIdx.y;
  const int c = threadIdx.x;
  float w[25];
#pragma unroll
  for (int e = 0; e < 25; ++e) w[e] = dw[c * 25 + e];
  const float bias = db[c];
  float col[5][5];  // col[k][dy]: column x-2+k
#pragma unroll
  for (int k = 0; k < 5; ++k) {
    const int xx = x0 - 2 + k;
#pragma unroll
    for (int dy = 0; dy < 5; ++dy) {
      const int yy = y + dy - 2;
      col[k][dy] = (xx >= 0 && xx < HW && yy >= 0 && yy < HW)
                       ? bf2f(m2[((size_t)yy * HW + xx) * C + c])
                       : 0.f;
    }
  }
  for (int xi = 0; xi < 32; ++xi) {
    const int x = x0 + xi;
    float s = bias;
#pragma unroll
    for (int kx = 0; kx < 5; ++kx)
#pragma unroll
      for (int ky = 0; ky < 5; ++ky) s += w[ky * 5 + kx] * col[kx][ky];
    const float a = 1.f / (1.f + expf(-s));
    const size_t oi = ((size_t)y * HW + x) * C + c;
    memb[oi] = f2bf(bf2f(m1[oi]) * (1.f + a));
#pragma unroll
    for (int k = 0; k < 4; ++k)
#pragma unroll
      for (int dy = 0; dy < 5; ++dy) col[k][dy] = col[k + 1][dy];
    const int xn = x + 3;
#pragma unroll
    for (int dy = 0; dy < 5; ++dy) {
      const int yy = y + dy - 2;
      col[4][dy] =
          (xn < HW && yy >= 0 && yy < HW) ? bf2f(m2[((size_t)yy * HW + xn) * C + c]) : 0.f;
    }
  }
}

// ---------------- Gram partials + fused sumsq ----------------
__global__ __launch_bounds__(256) void gram_kernel(const unsigned short* __restrict__ qb,
                                                   const unsigned short* __restrict__ kb,
                                                   float* __restrict__ Gpart,
                                                   float* __restrict__ ssq,
                                                   float* __restrict__ ssk) {
  const int chunk = blockIdx.x;  // 16
  const int h = blockIdx.y;      // 8
  const int b = blockIdx.z;      // 4
  __shared__ unsigned short lk[128 * 32], lq[128 * 32];
  const int t = threadIdx.x;
  const int wv = t >> 6;
  const int i0 = (t & 7) * 4, j0 = ((t >> 3) & 7) * 4;
  const int lrow = t >> 2, lcb = (t & 3) * 8;
  float acc[4][4] = {};
  float sq[8] = {}, sk[8] = {};
  for (int sub = 0; sub < 8; ++sub) {
    const size_t nbase = (size_t)b * NTOK + chunk * 1024 + sub * 128;
    __syncthreads();
#pragma unroll
    for (int it = 0; it < 2; ++it) {
      const int row = it * 64 + lrow;
      const s16x8 kv8 = *(const s16x8*)&kb[(nbase + row) * C + h * 32 + lcb];
      const s16x8 qv8 = *(const s16x8*)&qb[(nbase + row) * C + h * 32 + lcb];
      *(s16x8*)&lk[row * 32 + lcb] = kv8;
      *(s16x8*)&lq[row * 32 + lcb] = qv8;
#pragma unroll
      for (int e = 0; e < 8; ++e) {
        const float kf = bf2f((unsigned short)kv8[e]);
        sk[e] += kf * kf;
        const float qf = bf2f((unsigned short)qv8[e]);
        sq[e] += qf * qf;
      }
    }
    __syncthreads();
    for (int n = wv; n < 128; n += 4) {
      s16x4 kv = *(const s16x4*)&lk[n * 32 + i0];
      s16x4 qv = *(const s16x4*)&lq[n * 32 + j0];
      float kf[4], qf[4];
#pragma unroll
      for (int e = 0; e < 4; ++e) {
        kf[e] = bf2f((unsigned short)kv[e]);
        qf[e] = bf2f((unsigned short)qv[e]);
      }
#pragma unroll
      for (int a = 0; a < 4; ++a)
#pragma unroll
        for (int bb = 0; bb < 4; ++bb) acc[a][bb] += kf[a] * qf[bb];
    }
  }
  const int pc = chunk * 4 + wv;
  float* dst = Gpart + (((size_t)pc * B + b) * HEADS + h) * 1024;
#pragma unroll
  for (int a = 0; a < 4; ++a)
#pragma unroll
    for (int bb = 0; bb < 4; ++bb) dst[(i0 + a) * 32 + (j0 + bb)] = acc[a][bb];
  __syncthreads();
  float* fq = (float*)lq;
  float* fk = (float*)lk;
#pragma unroll
  for (int e = 0; e < 8; ++e) {
    fq[t * 8 + e] = sq[e];
    fk[t * 8 + e] = sk[e];
  }
  __syncthreads();
  if (t < 32) {
    const int tm = t >> 3, e = t & 7;
    float s1 = 0.f, s2 = 0.f;
    for (int k2 = 0; k2 < 64; ++k2) {
      const int tt = tm + k2 * 4;
      s1 += fq[tt * 8 + e];
      s2 += fk[tt * 8 + e];
    }
    ssq[((size_t)b * 16 + chunk) * C + h * 32 + t] = s1;
    ssk[((size_t)b * 16 + chunk) * C + h * 32 + t] = s2;
  }
}

// ---------------- reduce + normalize + softmax -> attn bf16 ----------------
__global__ __launch_bounds__(256) void softmax_kernel(
    const float* __restrict__ Gpart, const float* __restrict__ ssq,
    const float* __restrict__ ssk, const float* __restrict__ rescale,
    unsigned short* __restrict__ attnb) {
  const int h = blockIdx.x, b = blockIdx.y;
  const int t = threadIdx.x;
  __shared__ float G[1024];
  __shared__ float nq[32], nk[32];
#pragma unroll
  for (int e = 0; e < 4; ++e) {
    const int cell = e * 256 + t;
    float s = 0.f;
    for (int pc = 0; pc < 64; ++pc)
      s += Gpart[(((size_t)pc * B + b) * HEADS + h) * 1024 + cell];
    G[cell] = s;
  }
  if (t < 64) {
    const int d = t & 31;
    const float* ss = (t < 32) ? ssq : ssk;
    float s = 0.f;
    for (int ch = 0; ch < 16; ++ch) s += ss[((size_t)b * 16 + ch) * C + h * 32 + d];
    const float nn = fmaxf(sqrtf(s), 1e-12f);
    if (t < 32) nq[d] = nn;
    else nk[d] = nn;
  }
  __syncthreads();
  if (t < 32) {
    const int i = t;
    const float rs = rescale[h];
    float row[32];
    float mx = -1e30f;
#pragma unroll
    for (int j = 0; j < 32; ++j) {
      const float v = G[i * 32 + j] / (nk[i] * nq[j]) * rs;
      row[j] = v;
      mx = fmaxf(mx, v);
    }
    float sum = 0.f;
#pragma unroll
    for (int j = 0; j < 32; ++j) {
      const float e = expf(row[j] - mx);
      row[j] = e;
      sum += e;
    }
    const float inv = 1.f / sum;
#pragma unroll
    for (int j = 0; j < 32; ++j)
      attnb[(((size_t)b * HEADS + h) * 32 + i) * 32 + j] = f2bf(row[j] * inv);
  }
}

// ---------------- PV ----------------
#define PVP 264
#define ATP 40
__global__ __launch_bounds__(256) void pv_kernel(const unsigned short* __restrict__ vb,
                                                 const unsigned short* __restrict__ memb,
                                                 const unsigned short* __restrict__ attnb,
                                                 unsigned short* __restrict__ outp) {
  const int n0 = blockIdx.x * 64;
  const int b = blockIdx.y;
  __shared__ unsigned short vma[64 * PVP];
  __shared__ unsigned short at[HEADS * 32 * ATP];
  const int t = threadIdx.x, w = t >> 6, l = t & 63;
  const int lr = l & 15, lg = l >> 4;
  for (int e = t; e < 8192; e += 256) {
    const int h = e >> 10, ij = e & 1023;
    at[(h * 32 + (ij >> 5)) * ATP + (ij & 31)] = attnb[(size_t)b * 8192 + e];
  }
  {
    const int row = t >> 2, cs = (t & 3) * 64;
#pragma unroll
    for (int i2 = 0; i2 < 8; ++i2) {
      const int c = cs + i2 * 8;
      s16x8 vv = *(const s16x8*)&vb[((size_t)b * NTOK + n0 + row) * C + c];
      s16x8 mm = *(const s16x8*)&memb[(size_t)(n0 + row) * C + c];
      s16x8 o;
#pragma unroll
      for (int e = 0; e < 8; ++e)
        o[e] = (short)f2bf(bf2f((unsigned short)vv[e]) * bf2f((unsigned short)mm[e]));
      *(s16x8*)&vma[row * PVP + c] = o;
    }
  }
  __syncthreads();
  f32x4 acc[4][4];
#pragma unroll
  for (int i = 0; i < 4; ++i)
#pragma unroll
    for (int j = 0; j < 4; ++j) acc[i][j] = f32x4{0.f, 0.f, 0.f, 0.f};
#pragma unroll
  for (int j = 0; j < 4; ++j) {
    const int head = w * 2 + (j >> 1);
    const int colh = (j & 1) * 16 + lr;
    const bf16x8 bfr = *(const bf16x8*)&at[(head * 32 + colh) * ATP + lg * 8];
#pragma unroll
    for (int i = 0; i < 4; ++i) {
      const bf16x8 af = *(const bf16x8*)&vma[(i * 16 + lr) * PVP + head * 32 + lg * 8];
      acc[i][j] = __builtin_amdgcn_mfma_f32_16x16x32_bf16(af, bfr, acc[i][j], 0, 0, 0);
    }
  }
#pragma unroll
  for (int i = 0; i < 4; ++i) {
#pragma unroll
    for (int j = 0; j < 4; ++j) {
      const int head = w * 2 + (j >> 1);
      const int gcol = head * 32 + (j & 1) * 16 + lr;
      const int grow = n0 + i * 16 + lg * 4;
#pragma unroll
      for (int r = 0; r < 4; ++r)
        outp[((size_t)b * NTOK + grow + r) * C + gcol] = f2bf(acc[i][j][r]);
    }
  }
}

// ---------------- depthwise 3x3, 4 channels/thread ----------------
__global__ __launch_bounds__(512) void dw3_kernel(const unsigned short* __restrict__ in,
                                                  const float* __restrict__ wgt,
                                                  unsigned short* __restrict__ out_bf,
                                                  float* __restrict__ out_f32,
                                                  const int do_gelu, const int write_f32) {
  const int y = blockIdx.x;
  const int b = blockIdx.y;
  const int t = threadIdx.x;
  const int cg = (t & 63) * 4;
  const int x0 = (t >> 6) * 16;
  float w[9][4];
#pragma unroll
  for (int e = 0; e < 9; ++e)
#pragma unroll
    for (int ch = 0; ch < 4; ++ch) w[e][ch] = wgt[(cg + ch) * 9 + e];
  const int ym = y - 1, yp = y + 1;
  const bool hm = (ym >= 0), hp = (yp < HW);
  const size_t base = (size_t)b * NTOK * C + cg;
  auto ld4 = [&](int yy, int xx) -> f32x4 {
    const s16x4 v = *(const s16x4*)&in[base + ((size_t)yy * HW + xx) * C];
    f32x4 f;
    f[0] = bf2f((unsigned short)v[0]);
    f[1] = bf2f((unsigned short)v[1]);
    f[2] = bf2f((unsigned short)v[2]);
    f[3] = bf2f((unsigned short)v[3]);
    return f;
  };
  const f32x4 zero = {0.f, 0.f, 0.f, 0.f};
  f32x4 a0, a1, a2, b0, b1, b2;
  if (x0 > 0) {
    a0 = hm ? ld4(ym, x0 - 1) : zero;
    a1 = ld4(y, x0 - 1);
    a2 = hp ? ld4(yp, x0 - 1) : zero;
  } else {
    a0 = a1 = a2 = zero;
  }
  b0 = hm ? ld4(ym, x0) : zero;
  b1 = ld4(y, x0);
  b2 = hp ? ld4(yp, x0) : zero;
  for (int xi = 0; xi < 16; ++xi) {
    const int x = x0 + xi;
    f32x4 c0, c1, c2;
    if (x + 1 < HW) {
      c0 = hm ? ld4(ym, x + 1) : zero;
      c1 = ld4(y, x + 1);
      c2 = hp ? ld4(yp, x + 1) : zero;
    } else {
      c0 = c1 = c2 = zero;
    }
    float res[4];
#pragma unroll
    for (int ch = 0; ch < 4; ++ch) {
      float r = w[0][ch] * a0[ch] + w[1][ch] * b0[ch] + w[2][ch] * c0[ch] +
                w[3][ch] * a1[ch] + w[4][ch] * b1[ch] + w[5][ch] * c1[ch] +
                w[6][ch] * a2[ch] + w[7][ch] * b2[ch] + w[8][ch] * c2[ch];
      if (do_gelu) r = 0.5f * r * (1.f + erff(r * 0.70710678118654752f));
      res[ch] = r;
    }
    const size_t oi = base + ((size_t)y * HW + x) * C;
    if (write_f32) {
      const f32x4 o = {res[0], res[1], res[2], res[3]};
      *(f32x4*)&out_f32[oi] = o;
    } else {
      s16x4 o;
      o[0] = (short)f2bf(res[0]);
      o[1] = (short)f2bf(res[1]);
      o[2] = (short)f2bf(res[2]);
      o[3] = (short)f2bf(res[3]);
      *(s16x4*)&out_bf[oi] = o;
    }
    a0 = b0; a1 = b1; a2 = b2;
    b0 = c0; b1 = c1; b2 = c2;
  }
}

extern "C" void kernel_launch(void* const* d_in, const int* in_sizes, int n_in, void* d_out,
                              int out_size, void* d_ws, size_t ws_size, hipStream_t stream) {
  (void)in_sizes; (void)n_in; (void)out_size; (void)ws_size;
  const float* x = (const float*)d_in[0];
  const float* maskp = (const float*)d_in[1];
  const float* wq = (const float*)d_in[2];
  const float* wk = (const float*)d_in[3];
  const float* wv = (const float*)d_in[4];
  const float* rescale = (const float*)d_in[5];
  const float* wproj = (const float*)d_in[6];
  const float* bproj = (const float*)d_in[7];
  const float* mg_w1 = (const float*)d_in[8];
  const float* mg_b1 = (const float*)d_in[9];
  const float* mg_w2 = (const float*)d_in[10];
  const float* mg_b2 = (const float*)d_in[11];
  const float* mg_dw = (const float*)d_in[12];
  const float* mg_db = (const float*)d_in[13];
  const float* be_w1 = (const float*)d_in[14];
  const float* be_w2 = (const float*)d_in[15];
  float* out = (float*)d_out;
  char* ws = (char*)d_ws;

  unsigned short* xb = (unsigned short*)(ws + 0ull);            // 32MB, later out_pre
  unsigned short* qb = (unsigned short*)(ws + 33554432ull);     // 32MB, later y1
  unsigned short* kb = (unsigned short*)(ws + 67108864ull);     // 32MB
  unsigned short* vb = (unsigned short*)(ws + 100663296ull);    // 32MB
  unsigned short* mT = (unsigned short*)(ws + 134217728ull);    // 8MB, later mask_emb
  unsigned short* m1b = (unsigned short*)(ws + 142606336ull);   // 8MB
  unsigned short* m2b = (unsigned short*)(ws + 150994944ull);   // 8MB, later Gpart
  unsigned short* wqkvT = (unsigned short*)(ws + 159383552ull); // 384KB
  unsigned short* wprojT = (unsigned short*)(ws + 159776768ull);// 128KB
  unsigned short* w1b = (unsigned short*)(ws + 159907840ull);   // 128KB
  unsigned short* w2b = (unsigned short*)(ws + 160038912ull);   // 128KB
  float* ssq = (float*)(ws + 160169984ull);                     // 64KB (16 partials)
  float* ssk = (float*)(ws + 160432128ull);                     // 64KB
  unsigned short* attnb = (unsigned short*)(ws + 160694272ull); // 64KB
  float* Gpart = (float*)m2b;
  unsigned short* memb = mT;
  unsigned short* outpre = xb;
  unsigned short* y1 = qb;

  cast_x_kernel<<<2048, 256, 0, stream>>>(x, xb);
  prep_w_kernel<<<dim3(256, 6), 256, 0, stream>>>(wq, wk, wv, wproj, mg_w1, mg_w2, wqkvT,
                                                  wprojT, w1b, w2b);
  tmask_kernel<<<dim3(512, 8), 1024, 0, stream>>>(maskp, mT);
  // mask branch
  gemm_bt_kernel<<<256, 256, 0, stream>>>(mT, w1b, 256, 2, 1, m1b, nullptr, nullptr, mg_b1,
                                          nullptr);
  gemm_bt_kernel<<<256, 256, 0, stream>>>(m1b, w2b, 256, 2, 1, m2b, nullptr, nullptr, mg_b2,
                                          nullptr);
  mask_dw5_kernel<<<dim3(4, 128), 256, 0, stream>>>(m2b, m1b, mg_dw, mg_db, memb);
  // q,k,v : 256 M-tiles x 3 N-panels
  gemm_bt256_kernel<<<768, 512, 0, stream>>>(xb, wqkvT, 3, 0, qb, kb, vb, nullptr, nullptr);
  gram_kernel<<<dim3(16, 8, 4), 256, 0, stream>>>(qb, kb, Gpart, ssq, ssk);
  softmax_kernel<<<dim3(8, 4), 256, 0, stream>>>(Gpart, ssq, ssk, rescale, attnb);
  pv_kernel<<<dim3(256, 4), 256, 0, stream>>>(vb, memb, attnb, outpre);
  // band branch -> writes d_out; proj GEMM accumulates on top
  dw3_kernel<<<dim3(128, 4), 512, 0, stream>>>(vb, be_w1, y1, nullptr, 1, 0);
  dw3_kernel<<<dim3(128, 4), 512, 0, stream>>>(y1, be_w2, nullptr, out, 0, 1);
  gemm_bt256_kernel<<<256, 512, 0, stream>>>(outpre, wprojT, 1, 2, nullptr, nullptr, nullptr,
                                             bproj, out);
}

// Round 5
// 327.163 us; speedup vs baseline: 1.3606x; 1.0636x over previous
//
#include <hip/hip_runtime.h>
#include <stdint.h>

#define B 4
#define HW 128
#define C 256
#define NTOK 16384
#define MALL 65536
#define HEADS 8
#define DH 32

typedef float f32x4 __attribute__((ext_vector_type(4)));
typedef short s16x8 __attribute__((ext_vector_type(8)));
typedef short s16x4 __attribute__((ext_vector_type(4)));
typedef __bf16 bf16x8 __attribute__((ext_vector_type(8)));

__device__ __forceinline__ float bf2f(unsigned short u) {
  union { unsigned int i; float f; } x;
  x.i = ((unsigned int)u) << 16;
  return x.f;
}
__device__ __forceinline__ unsigned short f2bf(float f) {
  union { float f; unsigned int i; } x;
  x.f = f;
  unsigned int lsb = (x.i >> 16) & 1u;
  unsigned int r = x.i + 0x7fffu + lsb;
  return (unsigned short)(r >> 16);
}

__device__ __forceinline__ void gload_lds16(const void* g, void* l) {
  auto gp = reinterpret_cast<const __attribute__((address_space(1))) unsigned int*>(
      reinterpret_cast<uintptr_t>(g));
  auto lp = reinterpret_cast<__attribute__((address_space(3))) unsigned int*>(
      reinterpret_cast<uintptr_t>(l));
  __builtin_amdgcn_global_load_lds(gp, lp, 16, 0, 0);
}

#define CFENCE asm volatile("" ::: "memory")
#define RAWBAR()                      \
  do {                                \
    CFENCE;                           \
    __builtin_amdgcn_s_barrier();     \
    CFENCE;                           \
  } while (0)

// ---------------- cast x to bf16 ----------------
__global__ __launch_bounds__(256) void cast_x_kernel(const float* __restrict__ x,
                                                     unsigned short* __restrict__ xb) {
  const size_t stride = (size_t)gridDim.x * blockDim.x * 4;
  for (size_t i = ((size_t)blockIdx.x * blockDim.x + threadIdx.x) * 4; i < (size_t)MALL * C;
       i += stride) {
    const float4 v = *(const float4*)&x[i];
    s16x4 o;
    o[0] = (short)f2bf(v.x);
    o[1] = (short)f2bf(v.y);
    o[2] = (short)f2bf(v.z);
    o[3] = (short)f2bf(v.w);
    *(s16x4*)&xb[i] = o;
  }
}

// ---------------- weight prep: transpose+cast ----------------
__global__ __launch_bounds__(256) void prep_w_kernel(
    const float* __restrict__ wq, const float* __restrict__ wk, const float* __restrict__ wv,
    const float* __restrict__ wproj, const float* __restrict__ w1, const float* __restrict__ w2,
    unsigned short* __restrict__ wqkvT, unsigned short* __restrict__ wprojT,
    unsigned short* __restrict__ w1b, unsigned short* __restrict__ w2b) {
  const int idx = blockIdx.x * 256 + threadIdx.x;  // 0..65535
  const int mat = blockIdx.y;
  const int n = idx >> 8, k = idx & 255;
  switch (mat) {
    case 0: wqkvT[idx] = f2bf(wq[k * 256 + n]); break;
    case 1: wqkvT[65536 + idx] = f2bf(wk[k * 256 + n]); break;
    case 2: wqkvT[131072 + idx] = f2bf(wv[k * 256 + n]); break;
    case 3: wprojT[idx] = f2bf(wproj[k * 256 + n]); break;
    case 4: w1b[idx] = f2bf(w1[idx]); break;   // [co][ci] already K-contig
    case 5: w2b[idx] = f2bf(w2[idx]); break;
  }
}

// ---------------- transpose mask [C][N] -> [N][C] bf16 ----------------
__global__ __launch_bounds__(1024) void tmask_kernel(const float* __restrict__ mask,
                                                     unsigned short* __restrict__ mT) {
  __shared__ float tile[32][33];
  const int p0 = blockIdx.x * 32, c0 = blockIdx.y * 32;
  const int tx = threadIdx.x & 31, ty = threadIdx.x >> 5;
  tile[ty][tx] = mask[(size_t)(c0 + ty) * NTOK + p0 + tx];
  __syncthreads();
  mT[(size_t)(p0 + ty) * C + c0 + tx] = f2bf(tile[tx][ty]);
}

// ================ 256x256 8-wave pipelined GEMM, K=256 fixed ================
__global__ __launch_bounds__(512) void gemm_bt256_kernel(
    const unsigned short* __restrict__ A, const unsigned short* __restrict__ Bt,
    const int nbn, const int mode, unsigned short* __restrict__ ob0,
    unsigned short* __restrict__ ob1, unsigned short* __restrict__ ob2,
    const float* __restrict__ bias, float* __restrict__ of32) {
  __shared__ unsigned short lA[3][8192];  // [buf][half*4096 + row*32 + k]
  __shared__ unsigned short lB[3][8192];
  const int nwg = gridDim.x;
  const int bid = blockIdx.x;
  const int qd = nwg >> 3, rr = nwg & 7;
  const int xcd = bid & 7, sidx = bid >> 3;
  const int swz = (xcd < rr ? xcd * (qd + 1) : rr * (qd + 1) + (xcd - rr) * qd) + sidx;
  const int m0 = (swz / nbn) * 256;
  const int n0 = (swz % nbn) * 256;
  const int t = threadIdx.x;
  const int w = t >> 6, l = t & 63;
  const int wr = w >> 2, wc = w & 3;   // wave grid 2(M) x 4(N)
  const int lr = l & 15, lg = l >> 4;

  const int srow = t >> 2;
  const int ssl = (t & 3) ^ ((t >> 3) & 3);

  auto stageA = [&](int kt) {
    unsigned short* d = &lA[kt % 3][0];
    const size_t kb = ((size_t)kt * 32 + ssl * 8) * 2;  // byte k-offset
    gload_lds16((const char*)A + ((size_t)(m0 + srow) * 256) * 2 + kb, (char*)d + t * 16);
    gload_lds16((const char*)A + ((size_t)(m0 + 128 + srow) * 256) * 2 + kb,
                (char*)d + 8192 + t * 16);
  };
  auto stageB = [&](int kt) {
    unsigned short* d = &lB[kt % 3][0];
    const size_t kb = ((size_t)kt * 32 + ssl * 8) * 2;
    gload_lds16((const char*)Bt + ((size_t)(n0 + srow) * 256) * 2 + kb, (char*)d + t * 16);
    gload_lds16((const char*)Bt + ((size_t)(n0 + 128 + srow) * 256) * 2 + kb,
                (char*)d + 8192 + t * 16);
  };

  f32x4 acc[8][4];
#pragma unroll
  for (int m = 0; m < 8; ++m)
#pragma unroll
    for (int j = 0; j < 4; ++j) acc[m][j] = f32x4{0.f, 0.f, 0.f, 0.f};

  const int asl = (lg ^ ((lr >> 1) & 3)) * 8;
  const int aoff = wr * 4096 + lr * 32 + asl;                    // A frag m: + m*512
  const int boff = (wc >> 1) * 4096 + ((wc & 1) * 64 + lr) * 32 + asl;  // B frag j: + j*512

  stageA(0); stageB(0); stageA(1); stageB(1);
  asm volatile("s_waitcnt vmcnt(4)" ::: "memory");
  RAWBAR();

#pragma unroll
  for (int kt = 0; kt < 8; ++kt) {
    const int buf = kt % 3;
    bf16x8 bfr[4], af[4];
#pragma unroll
    for (int j = 0; j < 4; ++j) bfr[j] = *(const bf16x8*)&lB[buf][boff + j * 512];
#pragma unroll
    for (int m = 0; m < 4; ++m) af[m] = *(const bf16x8*)&lA[buf][aoff + m * 512];
    if (kt < 6) stageA(kt + 2);
    RAWBAR();
    __builtin_amdgcn_s_setprio(1);
#pragma unroll
    for (int m = 0; m < 4; ++m)
#pragma unroll
      for (int j = 0; j < 4; ++j)
        acc[m][j] = __builtin_amdgcn_mfma_f32_16x16x32_bf16(af[m], bfr[j], acc[m][j], 0, 0, 0);
    __builtin_amdgcn_s_setprio(0);
    RAWBAR();
#pragma unroll
    for (int m = 0; m < 4; ++m) af[m] = *(const bf16x8*)&lA[buf][aoff + (m + 4) * 512];
    if (kt < 6) stageB(kt + 2);
    RAWBAR();
    __builtin_amdgcn_s_setprio(1);
#pragma unroll
    for (int m = 0; m < 4; ++m)
#pragma unroll
      for (int j = 0; j < 4; ++j)
        acc[m + 4][j] =
            __builtin_amdgcn_mfma_f32_16x16x32_bf16(af[m], bfr[j], acc[m + 4][j], 0, 0, 0);
    __builtin_amdgcn_s_setprio(0);
    if (kt < 6) asm volatile("s_waitcnt vmcnt(4)" ::: "memory");
    else asm volatile("s_waitcnt vmcnt(0)" ::: "memory");
    RAWBAR();
  }

#pragma unroll
  for (int m = 0; m < 8; ++m) {
    const int grow = m0 + wr * 128 + m * 16 + lg * 4;
#pragma unroll
    for (int j = 0; j < 4; ++j) {
      const int gcol = n0 + wc * 64 + j * 16 + lr;
#pragma unroll
      for (int r = 0; r < 4; ++r) {
        const float v = acc[m][j][r];
        const size_t row = (size_t)(grow + r);
        if (mode == 0) {
          unsigned short* dst = (n0 < 256) ? ob0 : (n0 < 512 ? ob1 : ob2);
          dst[row * C + (gcol & 255)] = f2bf(v);
        } else {
          const size_t idx = row * C + gcol;
          of32[idx] += v + bias[gcol];
        }
      }
    }
  }
}

// ---------------- 2-phase 128x128 GEMM (kept for small mask GEMMs) ----------------
__global__ __launch_bounds__(256) void gemm_bt_kernel(
    const unsigned short* __restrict__ A, const unsigned short* __restrict__ Bt, const int K,
    const int nbn, const int mode, unsigned short* __restrict__ ob0,
    unsigned short* __restrict__ ob1, unsigned short* __restrict__ ob2,
    const float* __restrict__ bias, float* __restrict__ of32) {
  __shared__ unsigned short lA[2][128 * 64];
  __shared__ unsigned short lB[2][128 * 64];
  const int nwg = gridDim.x;
  const int bid = blockIdx.x;
  const int qd = nwg >> 3, rr = nwg & 7;
  const int xcd = bid & 7, sidx = bid >> 3;
  const int swz = (xcd < rr ? xcd * (qd + 1) : rr * (qd + 1) + (xcd - rr) * qd) + sidx;
  const int m0 = (swz / nbn) * 128;
  const int n0 = (swz % nbn) * 128;
  const int t = threadIdx.x;
  const int w = t >> 6, l = t & 63;
  const int wr = w >> 1, wc = w & 1;
  const int lr = l & 15, lg = l >> 4;

  const int strow = (l >> 3);
  const int scolb = (((l & 7) ^ strow) << 4);

  f32x4 acc[4][4];
#pragma unroll
  for (int i = 0; i < 4; ++i)
#pragma unroll
    for (int j = 0; j < 4; ++j) acc[i][j] = f32x4{0.f, 0.f, 0.f, 0.f};

  auto stage = [&](int buf, int k0) {
#pragma unroll
    for (int s = 0; s < 4; ++s) {
      const int seg = w * 4 + s;
      const int row = seg * 8 + strow;
      gload_lds16((const char*)A + ((size_t)(m0 + row) * K + k0) * 2 + scolb,
                  (char*)&lA[buf][0] + seg * 1024 + (l & 7) * 16);
      gload_lds16((const char*)Bt + ((size_t)(n0 + row) * K + k0) * 2 + scolb,
                  (char*)&lB[buf][0] + seg * 1024 + (l & 7) * 16);
    }
  };
  auto compute = [&](int buf) {
#pragma unroll
    for (int kk = 0; kk < 64; kk += 32) {
      bf16x8 af[4], bfr[4];
      const int sbase = (kk >> 3) + lg;
      const int p = (sbase ^ (lr & 7)) << 3;
#pragma unroll
      for (int i = 0; i < 4; ++i)
        af[i] = *(const bf16x8*)&lA[buf][(wr * 64 + i * 16 + lr) * 64 + p];
#pragma unroll
      for (int j = 0; j < 4; ++j)
        bfr[j] = *(const bf16x8*)&lB[buf][(wc * 64 + j * 16 + lr) * 64 + p];
#pragma unroll
      for (int i = 0; i < 4; ++i)
#pragma unroll
        for (int j = 0; j < 4; ++j)
          acc[i][j] = __builtin_amdgcn_mfma_f32_16x16x32_bf16(af[i], bfr[j], acc[i][j], 0, 0, 0);
    }
  };

  stage(0, 0);
  __syncthreads();
  int cur = 0;
  for (int k0 = 64; k0 < K; k0 += 64) {
    stage(cur ^ 1, k0);
    compute(cur);
    __syncthreads();
    cur ^= 1;
  }
  compute(cur);

#pragma unroll
  for (int i = 0; i < 4; ++i) {
    const int grow = m0 + wr * 64 + i * 16 + lg * 4;
#pragma unroll
    for (int j = 0; j < 4; ++j) {
      const int gcol = n0 + wc * 64 + j * 16 + lr;
#pragma unroll
      for (int r = 0; r < 4; ++r) {
        const float v = acc[i][j][r];
        const size_t row = (size_t)(grow + r);
        if (mode == 0) {
          unsigned short* dst = (gcol < 256) ? ob0 : (gcol < 512 ? ob1 : ob2);
          dst[row * C + (gcol & 255)] = f2bf(v);
        } else if (mode == 1) {
          ob0[row * C + gcol] = f2bf(v + bias[gcol]);
        } else {
          const size_t idx = row * C + gcol;
          of32[idx] += v + bias[gcol];
        }
      }
    }
  }
}

// ---------------- depthwise 5x5 + sigmoid + mask_emb, 4ch x 4x per thread ----------------
// Grid: (xtile 8, y 128), 256 threads: cg=(t&63)*4 channels, xsub=t>>6 (4 x per thread).
// All lanes of a wave share (y, xsub) -> boundary branches are wave-uniform.
__global__ __launch_bounds__(256) void mask_dw5_kernel(
    const unsigned short* __restrict__ m2, const unsigned short* __restrict__ m1,
    const float* __restrict__ dw, const float* __restrict__ db,
    unsigned short* __restrict__ memb) {
  __shared__ float wlds[25 * 256];
  __shared__ float blds[256];
  const int t = threadIdx.x;
  const int y = blockIdx.y;
  const int x0 = blockIdx.x * 16 + (t >> 6) * 4;
  const int cg = (t & 63) * 4;
  // stage weights (channel-major -> tap-major)
#pragma unroll
  for (int e = 0; e < 25; ++e) wlds[e * 256 + t] = dw[t * 25 + e];
  blds[t] = db[t];
  __syncthreads();

  const f32x4 bias = *(const f32x4*)&blds[cg];
  f32x4 acc[4];
#pragma unroll
  for (int xi = 0; xi < 4; ++xi) acc[xi] = bias;

#pragma unroll
  for (int dy = 0; dy < 5; ++dy) {
    const int yy = y + dy - 2;
    if (yy < 0 || yy >= HW) continue;
    // load 8 window columns x0-2 .. x0+5 for this row
    f32x4 col[8];
#pragma unroll
    for (int j = 0; j < 8; ++j) {
      const int xx = x0 - 2 + j;
      if (xx >= 0 && xx < HW) {
        const s16x4 v = *(const s16x4*)&m2[((size_t)yy * HW + xx) * C + cg];
        col[j][0] = bf2f((unsigned short)v[0]);
        col[j][1] = bf2f((unsigned short)v[1]);
        col[j][2] = bf2f((unsigned short)v[2]);
        col[j][3] = bf2f((unsigned short)v[3]);
      } else {
        col[j] = f32x4{0.f, 0.f, 0.f, 0.f};
      }
    }
#pragma unroll
    for (int dx = 0; dx < 5; ++dx) {
      const f32x4 wv = *(const f32x4*)&wlds[(dy * 5 + dx) * 256 + cg];
#pragma unroll
      for (int xi = 0; xi < 4; ++xi) acc[xi] += wv * col[dx + xi];
    }
  }

#pragma unroll
  for (int xi = 0; xi < 4; ++xi) {
    const size_t oi = ((size_t)y * HW + x0 + xi) * C + cg;
    const s16x4 mv = *(const s16x4*)&m1[oi];
    s16x4 o;
#pragma unroll
    for (int ch = 0; ch < 4; ++ch) {
      const float a = 1.f / (1.f + __expf(-acc[xi][ch]));
      o[ch] = (short)f2bf(bf2f((unsigned short)mv[ch]) * (1.f + a));
    }
    *(s16x4*)&memb[oi] = o;
  }
}

// ---------------- Gram partials + fused sumsq ----------------
__global__ __launch_bounds__(256) void gram_kernel(const unsigned short* __restrict__ qb,
                                                   const unsigned short* __restrict__ kb,
                                                   float* __restrict__ Gpart,
                                                   float* __restrict__ ssq,
                                                   float* __restrict__ ssk) {
  const int chunk = blockIdx.x;  // 16
  const int h = blockIdx.y;      // 8
  const int b = blockIdx.z;      // 4
  __shared__ unsigned short lk[128 * 32], lq[128 * 32];
  const int t = threadIdx.x;
  const int wv = t >> 6;
  const int i0 = (t & 7) * 4, j0 = ((t >> 3) & 7) * 4;
  const int lrow = t >> 2, lcb = (t & 3) * 8;
  float acc[4][4] = {};
  float sq[8] = {}, sk[8] = {};
  for (int sub = 0; sub < 8; ++sub) {
    const size_t nbase = (size_t)b * NTOK + chunk * 1024 + sub * 128;
    __syncthreads();
#pragma unroll
    for (int it = 0; it < 2; ++it) {
      const int row = it * 64 + lrow;
      const s16x8 kv8 = *(const s16x8*)&kb[(nbase + row) * C + h * 32 + lcb];
      const s16x8 qv8 = *(const s16x8*)&qb[(nbase + row) * C + h * 32 + lcb];
      *(s16x8*)&lk[row * 32 + lcb] = kv8;
      *(s16x8*)&lq[row * 32 + lcb] = qv8;
#pragma unroll
      for (int e = 0; e < 8; ++e) {
        const float kf = bf2f((unsigned short)kv8[e]);
        sk[e] += kf * kf;
        const float qf = bf2f((unsigned short)qv8[e]);
        sq[e] += qf * qf;
      }
    }
    __syncthreads();
    for (int n = wv; n < 128; n += 4) {
      s16x4 kv = *(const s16x4*)&lk[n * 32 + i0];
      s16x4 qv = *(const s16x4*)&lq[n * 32 + j0];
      float kf[4], qf[4];
#pragma unroll
      for (int e = 0; e < 4; ++e) {
        kf[e] = bf2f((unsigned short)kv[e]);
        qf[e] = bf2f((unsigned short)qv[e]);
      }
#pragma unroll
      for (int a = 0; a < 4; ++a)
#pragma unroll
        for (int bb = 0; bb < 4; ++bb) acc[a][bb] += kf[a] * qf[bb];
    }
  }
  const int pc = chunk * 4 + wv;
  float* dst = Gpart + (((size_t)pc * B + b) * HEADS + h) * 1024;
#pragma unroll
  for (int a = 0; a < 4; ++a)
#pragma unroll
    for (int bb = 0; bb < 4; ++bb) dst[(i0 + a) * 32 + (j0 + bb)] = acc[a][bb];
  __syncthreads();
  float* fq = (float*)lq;
  float* fk = (float*)lk;
#pragma unroll
  for (int e = 0; e < 8; ++e) {
    fq[t * 8 + e] = sq[e];
    fk[t * 8 + e] = sk[e];
  }
  __syncthreads();
  if (t < 32) {
    const int tm = t >> 3, e = t & 7;
    float s1 = 0.f, s2 = 0.f;
    for (int k2 = 0; k2 < 64; ++k2) {
      const int tt = tm + k2 * 4;
      s1 += fq[tt * 8 + e];
      s2 += fk[tt * 8 + e];
    }
    ssq[((size_t)b * 16 + chunk) * C + h * 32 + t] = s1;
    ssk[((size_t)b * 16 + chunk) * C + h * 32 + t] = s2;
  }
}

// ---------------- reduce + normalize + softmax -> attn bf16 ----------------
__global__ __launch_bounds__(256) void softmax_kernel(
    const float* __restrict__ Gpart, const float* __restrict__ ssq,
    const float* __restrict__ ssk, const float* __restrict__ rescale,
    unsigned short* __restrict__ attnb) {
  const int h = blockIdx.x, b = blockIdx.y;
  const int t = threadIdx.x;
  __shared__ float G[1024];
  __shared__ float nq[32], nk[32];
#pragma unroll
  for (int e = 0; e < 4; ++e) {
    const int cell = e * 256 + t;
    float s = 0.f;
    for (int pc = 0; pc < 64; ++pc)
      s += Gpart[(((size_t)pc * B + b) * HEADS + h) * 1024 + cell];
    G[cell] = s;
  }
  if (t < 64) {
    const int d = t & 31;
    const float* ss = (t < 32) ? ssq : ssk;
    float s = 0.f;
    for (int ch = 0; ch < 16; ++ch) s += ss[((size_t)b * 16 + ch) * C + h * 32 + d];
    const float nn = fmaxf(sqrtf(s), 1e-12f);
    if (t < 32) nq[d] = nn;
    else nk[d] = nn;
  }
  __syncthreads();
  if (t < 32) {
    const int i = t;
    const float rs = rescale[h];
    float row[32];
    float mx = -1e30f;
#pragma unroll
    for (int j = 0; j < 32; ++j) {
      const float v = G[i * 32 + j] / (nk[i] * nq[j]) * rs;
      row[j] = v;
      mx = fmaxf(mx, v);
    }
    float sum = 0.f;
#pragma unroll
    for (int j = 0; j < 32; ++j) {
      const float e = expf(row[j] - mx);
      row[j] = e;
      sum += e;
    }
    const float inv = 1.f / sum;
#pragma unroll
    for (int j = 0; j < 32; ++j)
      attnb[(((size_t)b * HEADS + h) * 32 + i) * 32 + j] = f2bf(row[j] * inv);
  }
}

// ---------------- PV ----------------
#define PVP 264
#define ATP 40
__global__ __launch_bounds__(256) void pv_kernel(const unsigned short* __restrict__ vb,
                                                 const unsigned short* __restrict__ memb,
                                                 const unsigned short* __restrict__ attnb,
                                                 unsigned short* __restrict__ outp) {
  const int n0 = blockIdx.x * 64;
  const int b = blockIdx.y;
  __shared__ unsigned short vma[64 * PVP];
  __shared__ unsigned short at[HEADS * 32 * ATP];
  const int t = threadIdx.x, w = t >> 6, l = t & 63;
  const int lr = l & 15, lg = l >> 4;
  for (int e = t; e < 8192; e += 256) {
    const int h = e >> 10, ij = e & 1023;
    at[(h * 32 + (ij >> 5)) * ATP + (ij & 31)] = attnb[(size_t)b * 8192 + e];
  }
  {
    const int row = t >> 2, cs = (t & 3) * 64;
#pragma unroll
    for (int i2 = 0; i2 < 8; ++i2) {
      const int c = cs + i2 * 8;
      s16x8 vv = *(const s16x8*)&vb[((size_t)b * NTOK + n0 + row) * C + c];
      s16x8 mm = *(const s16x8*)&memb[(size_t)(n0 + row) * C + c];
      s16x8 o;
#pragma unroll
      for (int e = 0; e < 8; ++e)
        o[e] = (short)f2bf(bf2f((unsigned short)vv[e]) * bf2f((unsigned short)mm[e]));
      *(s16x8*)&vma[row * PVP + c] = o;
    }
  }
  __syncthreads();
  f32x4 acc[4][4];
#pragma unroll
  for (int i = 0; i < 4; ++i)
#pragma unroll
    for (int j = 0; j < 4; ++j) acc[i][j] = f32x4{0.f, 0.f, 0.f, 0.f};
#pragma unroll
  for (int j = 0; j < 4; ++j) {
    const int head = w * 2 + (j >> 1);
    const int colh = (j & 1) * 16 + lr;
    const bf16x8 bfr = *(const bf16x8*)&at[(head * 32 + colh) * ATP + lg * 8];
#pragma unroll
    for (int i = 0; i < 4; ++i) {
      const bf16x8 af = *(const bf16x8*)&vma[(i * 16 + lr) * PVP + head * 32 + lg * 8];
      acc[i][j] = __builtin_amdgcn_mfma_f32_16x16x32_bf16(af, bfr, acc[i][j], 0, 0, 0);
    }
  }
#pragma unroll
  for (int i = 0; i < 4; ++i) {
#pragma unroll
    for (int j = 0; j < 4; ++j) {
      const int head = w * 2 + (j >> 1);
      const int gcol = head * 32 + (j & 1) * 16 + lr;
      const int grow = n0 + i * 16 + lg * 4;
#pragma unroll
      for (int r = 0; r < 4; ++r)
        outp[((size_t)b * NTOK + grow + r) * C + gcol] = f2bf(acc[i][j][r]);
    }
  }
}

// ---------------- depthwise 3x3, 4 channels/thread ----------------
__global__ __launch_bounds__(512) void dw3_kernel(const unsigned short* __restrict__ in,
                                                  const float* __restrict__ wgt,
                                                  unsigned short* __restrict__ out_bf,
                                                  float* __restrict__ out_f32,
                                                  const int do_gelu, const int write_f32) {
  const int y = blockIdx.x;
  const int b = blockIdx.y;
  const int t = threadIdx.x;
  const int cg = (t & 63) * 4;
  const int x0 = (t >> 6) * 16;
  float w[9][4];
#pragma unroll
  for (int e = 0; e < 9; ++e)
#pragma unroll
    for (int ch = 0; ch < 4; ++ch) w[e][ch] = wgt[(cg + ch) * 9 + e];
  const int ym = y - 1, yp = y + 1;
  const bool hm = (ym >= 0), hp = (yp < HW);
  const size_t base = (size_t)b * NTOK * C + cg;
  auto ld4 = [&](int yy, int xx) -> f32x4 {
    const s16x4 v = *(const s16x4*)&in[base + ((size_t)yy * HW + xx) * C];
    f32x4 f;
    f[0] = bf2f((unsigned short)v[0]);
    f[1] = bf2f((unsigned short)v[1]);
    f[2] = bf2f((unsigned short)v[2]);
    f[3] = bf2f((unsigned short)v[3]);
    return f;
  };
  const f32x4 zero = {0.f, 0.f, 0.f, 0.f};
  f32x4 a0, a1, a2, b0, b1, b2;
  if (x0 > 0) {
    a0 = hm ? ld4(ym, x0 - 1) : zero;
    a1 = ld4(y, x0 - 1);
    a2 = hp ? ld4(yp, x0 - 1) : zero;
  } else {
    a0 = a1 = a2 = zero;
  }
  b0 = hm ? ld4(ym, x0) : zero;
  b1 = ld4(y, x0);
  b2 = hp ? ld4(yp, x0) : zero;
  for (int xi = 0; xi < 16; ++xi) {
    const int x = x0 + xi;
    f32x4 c0, c1, c2;
    if (x + 1 < HW) {
      c0 = hm ? ld4(ym, x + 1) : zero;
      c1 = ld4(y, x + 1);
      c2 = hp ? ld4(yp, x + 1) : zero;
    } else {
      c0 = c1 = c2 = zero;
    }
    float res[4];
#pragma unroll
    for (int ch = 0; ch < 4; ++ch) {
      float r = w[0][ch] * a0[ch] + w[1][ch] * b0[ch] + w[2][ch] * c0[ch] +
                w[3][ch] * a1[ch] + w[4][ch] * b1[ch] + w[5][ch] * c1[ch] +
                w[6][ch] * a2[ch] + w[7][ch] * b2[ch] + w[8][ch] * c2[ch];
      if (do_gelu) r = 0.5f * r * (1.f + erff(r * 0.70710678118654752f));
      res[ch] = r;
    }
    const size_t oi = base + ((size_t)y * HW + x) * C;
    if (write_f32) {
      const f32x4 o = {res[0], res[1], res[2], res[3]};
      *(f32x4*)&out_f32[oi] = o;
    } else {
      s16x4 o;
      o[0] = (short)f2bf(res[0]);
      o[1] = (short)f2bf(res[1]);
      o[2] = (short)f2bf(res[2]);
      o[3] = (short)f2bf(res[3]);
      *(s16x4*)&out_bf[oi] = o;
    }
    a0 = b0; a1 = b1; a2 = b2;
    b0 = c0; b1 = c1; b2 = c2;
  }
}

extern "C" void kernel_launch(void* const* d_in, const int* in_sizes, int n_in, void* d_out,
                              int out_size, void* d_ws, size_t ws_size, hipStream_t stream) {
  (void)in_sizes; (void)n_in; (void)out_size; (void)ws_size;
  const float* x = (const float*)d_in[0];
  const float* maskp = (const float*)d_in[1];
  const float* wq = (const float*)d_in[2];
  const float* wk = (const float*)d_in[3];
  const float* wv = (const float*)d_in[4];
  const float* rescale = (const float*)d_in[5];
  const float* wproj = (const float*)d_in[6];
  const float* bproj = (const float*)d_in[7];
  const float* mg_w1 = (const float*)d_in[8];
  const float* mg_b1 = (const float*)d_in[9];
  const float* mg_w2 = (const float*)d_in[10];
  const float* mg_b2 = (const float*)d_in[11];
  const float* mg_dw = (const float*)d_in[12];
  const float* mg_db = (const float*)d_in[13];
  const float* be_w1 = (const float*)d_in[14];
  const float* be_w2 = (const float*)d_in[15];
  float* out = (float*)d_out;
  char* ws = (char*)d_ws;

  unsigned short* xb = (unsigned short*)(ws + 0ull);            // 32MB, later out_pre
  unsigned short* qb = (unsigned short*)(ws + 33554432ull);     // 32MB, later y1
  unsigned short* kb = (unsigned short*)(ws + 67108864ull);     // 32MB
  unsigned short* vb = (unsigned short*)(ws + 100663296ull);    // 32MB
  unsigned short* mT = (unsigned short*)(ws + 134217728ull);    // 8MB, later mask_emb
  unsigned short* m1b = (unsigned short*)(ws + 142606336ull);   // 8MB
  unsigned short* m2b = (unsigned short*)(ws + 150994944ull);   // 8MB, later Gpart
  unsigned short* wqkvT = (unsigned short*)(ws + 159383552ull); // 384KB
  unsigned short* wprojT = (unsigned short*)(ws + 159776768ull);// 128KB
  unsigned short* w1b = (unsigned short*)(ws + 159907840ull);   // 128KB
  unsigned short* w2b = (unsigned short*)(ws + 160038912ull);   // 128KB
  float* ssq = (float*)(ws + 160169984ull);                     // 64KB (16 partials)
  float* ssk = (float*)(ws + 160432128ull);                     // 64KB
  unsigned short* attnb = (unsigned short*)(ws + 160694272ull); // 64KB
  float* Gpart = (float*)m2b;
  unsigned short* memb = mT;
  unsigned short* outpre = xb;
  unsigned short* y1 = qb;

  cast_x_kernel<<<2048, 256, 0, stream>>>(x, xb);
  prep_w_kernel<<<dim3(256, 6), 256, 0, stream>>>(wq, wk, wv, wproj, mg_w1, mg_w2, wqkvT,
                                                  wprojT, w1b, w2b);
  tmask_kernel<<<dim3(512, 8), 1024, 0, stream>>>(maskp, mT);
  // mask branch
  gemm_bt_kernel<<<256, 256, 0, stream>>>(mT, w1b, 256, 2, 1, m1b, nullptr, nullptr, mg_b1,
                                          nullptr);
  gemm_bt_kernel<<<256, 256, 0, stream>>>(m1b, w2b, 256, 2, 1, m2b, nullptr, nullptr, mg_b2,
                                          nullptr);
  mask_dw5_kernel<<<dim3(8, 128), 256, 0, stream>>>(m2b, m1b, mg_dw, mg_db, memb);
  // q,k,v : 256 M-tiles x 3 N-panels
  gemm_bt256_kernel<<<768, 512, 0, stream>>>(xb, wqkvT, 3, 0, qb, kb, vb, nullptr, nullptr);
  gram_kernel<<<dim3(16, 8, 4), 256, 0, stream>>>(qb, kb, Gpart, ssq, ssk);
  softmax_kernel<<<dim3(8, 4), 256, 0, stream>>>(Gpart, ssq, ssk, rescale, attnb);
  pv_kernel<<<dim3(256, 4), 256, 0, stream>>>(vb, memb, attnb, outpre);
  // band branch -> writes d_out; proj GEMM accumulates on top
  dw3_kernel<<<dim3(128, 4), 512, 0, stream>>>(vb, be_w1, y1, nullptr, 1, 0);
  dw3_kernel<<<dim3(128, 4), 512, 0, stream>>>(y1, be_w2, nullptr, out, 0, 1);
  gemm_bt256_kernel<<<256, 512, 0, stream>>>(outpre, wprojT, 1, 2, nullptr, nullptr, nullptr,
                                             bproj, out);
}

// Round 6
// 299.561 us; speedup vs baseline: 1.4860x; 1.0921x over previous
//
#include <hip/hip_runtime.h>
#include <stdint.h>

#define B 4
#define HW 128
#define C 256
#define NTOK 16384
#define MALL 65536
#define HEADS 8
#define DH 32

typedef float f32x4 __attribute__((ext_vector_type(4)));
typedef short s16x8 __attribute__((ext_vector_type(8)));
typedef short s16x4 __attribute__((ext_vector_type(4)));
typedef __bf16 bf16x8 __attribute__((ext_vector_type(8)));

__device__ __forceinline__ float bf2f(unsigned short u) {
  union { unsigned int i; float f; } x;
  x.i = ((unsigned int)u) << 16;
  return x.f;
}
__device__ __forceinline__ unsigned short f2bf(float f) {
  union { float f; unsigned int i; } x;
  x.f = f;
  unsigned int lsb = (x.i >> 16) & 1u;
  unsigned int r = x.i + 0x7fffu + lsb;
  return (unsigned short)(r >> 16);
}

__device__ __forceinline__ void gload_lds16(const void* g, void* l) {
  auto gp = reinterpret_cast<const __attribute__((address_space(1))) unsigned int*>(
      reinterpret_cast<uintptr_t>(g));
  auto lp = reinterpret_cast<__attribute__((address_space(3))) unsigned int*>(
      reinterpret_cast<uintptr_t>(l));
  __builtin_amdgcn_global_load_lds(gp, lp, 16, 0, 0);
}

#define CFENCE asm volatile("" ::: "memory")
#define RAWBAR()                      \
  do {                                \
    CFENCE;                           \
    __builtin_amdgcn_s_barrier();     \
    CFENCE;                           \
  } while (0)
#define LDSBAR()                                        \
  do {                                                  \
    asm volatile("s_waitcnt lgkmcnt(0)" ::: "memory");  \
    __builtin_amdgcn_s_barrier();                       \
    CFENCE;                                             \
  } while (0)

// ---------------- cast x to bf16 ----------------
__global__ __launch_bounds__(256) void cast_x_kernel(const float* __restrict__ x,
                                                     unsigned short* __restrict__ xb) {
  const size_t stride = (size_t)gridDim.x * blockDim.x * 4;
  for (size_t i = ((size_t)blockIdx.x * blockDim.x + threadIdx.x) * 4; i < (size_t)MALL * C;
       i += stride) {
    const float4 v = *(const float4*)&x[i];
    s16x4 o;
    o[0] = (short)f2bf(v.x);
    o[1] = (short)f2bf(v.y);
    o[2] = (short)f2bf(v.z);
    o[3] = (short)f2bf(v.w);
    *(s16x4*)&xb[i] = o;
  }
}

// ---------------- weight prep: transpose+cast ----------------
__global__ __launch_bounds__(256) void prep_w_kernel(
    const float* __restrict__ wq, const float* __restrict__ wk, const float* __restrict__ wv,
    const float* __restrict__ wproj, const float* __restrict__ w1, const float* __restrict__ w2,
    unsigned short* __restrict__ wqkvT, unsigned short* __restrict__ wprojT,
    unsigned short* __restrict__ w1b, unsigned short* __restrict__ w2b) {
  const int idx = blockIdx.x * 256 + threadIdx.x;  // 0..65535
  const int mat = blockIdx.y;
  const int n = idx >> 8, k = idx & 255;
  switch (mat) {
    case 0: wqkvT[idx] = f2bf(wq[k * 256 + n]); break;
    case 1: wqkvT[65536 + idx] = f2bf(wk[k * 256 + n]); break;
    case 2: wqkvT[131072 + idx] = f2bf(wv[k * 256 + n]); break;
    case 3: wprojT[idx] = f2bf(wproj[k * 256 + n]); break;
    case 4: w1b[idx] = f2bf(w1[idx]); break;   // [co][ci] already K-contig
    case 5: w2b[idx] = f2bf(w2[idx]); break;
  }
}

// ---------------- transpose mask [C][N] -> [N][C] bf16 ----------------
__global__ __launch_bounds__(1024) void tmask_kernel(const float* __restrict__ mask,
                                                     unsigned short* __restrict__ mT) {
  __shared__ float tile[32][33];
  const int p0 = blockIdx.x * 32, c0 = blockIdx.y * 32;
  const int tx = threadIdx.x & 31, ty = threadIdx.x >> 5;
  tile[ty][tx] = mask[(size_t)(c0 + ty) * NTOK + p0 + tx];
  __syncthreads();
  mT[(size_t)(p0 + ty) * C + c0 + tx] = f2bf(tile[tx][ty]);
}

// ================ 256x256 8-wave pipelined GEMM, K=256 fixed ================
// mode 0: bf16 out (q/k/v selected by n0/256), LDS-staged coalesced epilogue.
// mode 2: out = acc + bias + bf2f(y2)  (single f32 write, no RMW).
__global__ __launch_bounds__(512) void gemm_bt256_kernel(
    const unsigned short* __restrict__ A, const unsigned short* __restrict__ Bt,
    const int nbn, const int mode, unsigned short* __restrict__ ob0,
    unsigned short* __restrict__ ob1, unsigned short* __restrict__ ob2,
    const float* __restrict__ bias, float* __restrict__ of32,
    const unsigned short* __restrict__ y2) {
  __shared__ unsigned short smem[49152];  // 96KB: lA 3x8192, lB 3x8192 (ushort)
  unsigned short* lAb = smem;
  unsigned short* lBb = smem + 24576;
  const int nwg = gridDim.x;
  const int bid = blockIdx.x;
  const int qd = nwg >> 3, rr = nwg & 7;
  const int xcd = bid & 7, sidx = bid >> 3;
  const int swz = (xcd < rr ? xcd * (qd + 1) : rr * (qd + 1) + (xcd - rr) * qd) + sidx;
  const int m0 = (swz / nbn) * 256;
  const int n0 = (swz % nbn) * 256;
  const int t = threadIdx.x;
  const int w = t >> 6, l = t & 63;
  const int wr = w >> 2, wc = w & 3;   // wave grid 2(M) x 4(N)
  const int lr = l & 15, lg = l >> 4;

  const int srow = t >> 2;
  const int ssl = (t & 3) ^ ((t >> 3) & 3);

  auto stageA = [&](int kt) {
    unsigned short* d = lAb + (kt % 3) * 8192;
    const size_t kb = ((size_t)kt * 32 + ssl * 8) * 2;  // byte k-offset
    gload_lds16((const char*)A + ((size_t)(m0 + srow) * 256) * 2 + kb, (char*)d + t * 16);
    gload_lds16((const char*)A + ((size_t)(m0 + 128 + srow) * 256) * 2 + kb,
                (char*)d + 8192 + t * 16);
  };
  auto stageB = [&](int kt) {
    unsigned short* d = lBb + (kt % 3) * 8192;
    const size_t kb = ((size_t)kt * 32 + ssl * 8) * 2;
    gload_lds16((const char*)Bt + ((size_t)(n0 + srow) * 256) * 2 + kb, (char*)d + t * 16);
    gload_lds16((const char*)Bt + ((size_t)(n0 + 128 + srow) * 256) * 2 + kb,
                (char*)d + 8192 + t * 16);
  };

  f32x4 acc[8][4];
#pragma unroll
  for (int m = 0; m < 8; ++m)
#pragma unroll
    for (int j = 0; j < 4; ++j) acc[m][j] = f32x4{0.f, 0.f, 0.f, 0.f};

  const int asl = (lg ^ ((lr >> 1) & 3)) * 8;
  const int aoff = lr * 32 + asl;                                      // + wrbase
  const int awb = wr * 4096;
  const int boff = (wc >> 1) * 4096 + ((wc & 1) * 64 + lr) * 32 + asl;

  stageA(0); stageB(0); stageA(1); stageB(1);
  asm volatile("s_waitcnt vmcnt(4)" ::: "memory");
  RAWBAR();

#pragma unroll
  for (int kt = 0; kt < 8; ++kt) {
    const unsigned short* bufA = lAb + (kt % 3) * 8192;
    const unsigned short* bufB = lBb + (kt % 3) * 8192;
    bf16x8 bfr[4], af[4];
#pragma unroll
    for (int j = 0; j < 4; ++j) bfr[j] = *(const bf16x8*)&bufB[boff + j * 512];
#pragma unroll
    for (int m = 0; m < 4; ++m) af[m] = *(const bf16x8*)&bufA[awb + aoff + m * 512];
    if (kt < 6) stageA(kt + 2);
    RAWBAR();
    __builtin_amdgcn_s_setprio(1);
#pragma unroll
    for (int m = 0; m < 4; ++m)
#pragma unroll
      for (int j = 0; j < 4; ++j)
        acc[m][j] = __builtin_amdgcn_mfma_f32_16x16x32_bf16(af[m], bfr[j], acc[m][j], 0, 0, 0);
    __builtin_amdgcn_s_setprio(0);
    RAWBAR();
#pragma unroll
    for (int m = 0; m < 4; ++m) af[m] = *(const bf16x8*)&bufA[awb + aoff + (m + 4) * 512];
    if (kt < 6) stageB(kt + 2);
    RAWBAR();
    __builtin_amdgcn_s_setprio(1);
#pragma unroll
    for (int m = 0; m < 4; ++m)
#pragma unroll
      for (int j = 0; j < 4; ++j)
        acc[m + 4][j] =
            __builtin_amdgcn_mfma_f32_16x16x32_bf16(af[m], bfr[j], acc[m + 4][j], 0, 0, 0);
    __builtin_amdgcn_s_setprio(0);
    if (kt < 6) asm volatile("s_waitcnt vmcnt(4)" ::: "memory");
    else asm volatile("s_waitcnt vmcnt(0)" ::: "memory");
    RAWBAR();
  }

  if (mode == 0) {
    // ---- bf16 epilogue: 2 halves x (ds-stage -> coalesced row flush) ----
    unsigned short* dst = (n0 < 256) ? ob0 : (n0 < 512 ? ob1 : ob2);
    unsigned short* eph = smem;  // [128][264] ushorts = 67.6KB
#pragma unroll
    for (int h = 0; h < 2; ++h) {
      LDSBAR();
#pragma unroll
      for (int mm = 0; mm < 4; ++mm) {
        const int m = h * 4 + mm;
        const int lrow = wr * 64 + mm * 16 + lg * 4;
#pragma unroll
        for (int j = 0; j < 4; ++j) {
          const int col = wc * 64 + j * 16 + lr;
#pragma unroll
          for (int r = 0; r < 4; ++r) eph[(lrow + r) * 264 + col] = f2bf(acc[m][j][r]);
        }
      }
      LDSBAR();
      const int col16 = t & 31;  // 16B chunk within row (32 per row)
#pragma unroll
      for (int c2 = 0; c2 < 8; ++c2) {
        const int lrow = c2 * 16 + (t >> 5);
        const int grow = m0 + (lrow >> 6) * 128 + h * 64 + (lrow & 63);
        const s16x8 v = *(const s16x8*)&eph[lrow * 264 + col16 * 8];
        *(s16x8*)&dst[(size_t)grow * C + col16 * 8] = v;
      }
    }
  } else {
    // ---- f32 epilogue: out = acc + bias + y2 ; 4 quarters ----
    float* ephf = (float*)smem;  // [64][260] floats = 66.6KB
    const int colc = t & 63;     // 16B chunk (4 floats) within row (64 per row)
    const f32x4 bv = *(const f32x4*)&bias[colc * 4];
#pragma unroll
    for (int qtr = 0; qtr < 4; ++qtr) {
      LDSBAR();
#pragma unroll
      for (int mm = 0; mm < 2; ++mm) {
        const int m = qtr * 2 + mm;
        const int lrow = wr * 32 + mm * 16 + lg * 4;
#pragma unroll
        for (int j = 0; j < 4; ++j) {
          const int col = wc * 64 + j * 16 + lr;
#pragma unroll
          for (int r = 0; r < 4; ++r) ephf[(lrow + r) * 260 + col] = acc[m][j][r];
        }
      }
      LDSBAR();
#pragma unroll
      for (int c2 = 0; c2 < 8; ++c2) {
        const int lrow = c2 * 8 + (t >> 6);
        const int grow = m0 + (lrow >> 5) * 128 + qtr * 32 + (lrow & 31);
        const f32x4 v = *(const f32x4*)&ephf[lrow * 260 + colc * 4];
        const s16x4 yv = *(const s16x4*)&y2[(size_t)grow * C + colc * 4];
        f32x4 o;
#pragma unroll
        for (int e = 0; e < 4; ++e) o[e] = v[e] + bv[e] + bf2f((unsigned short)yv[e]);
        *(f32x4*)&of32[(size_t)grow * C + colc * 4] = o;
      }
    }
  }
}

// ---------------- 2-phase 128x128 GEMM (kept for small mask GEMMs) ----------------
__global__ __launch_bounds__(256) void gemm_bt_kernel(
    const unsigned short* __restrict__ A, const unsigned short* __restrict__ Bt, const int K,
    const int nbn, const int mode, unsigned short* __restrict__ ob0,
    unsigned short* __restrict__ ob1, unsigned short* __restrict__ ob2,
    const float* __restrict__ bias, float* __restrict__ of32) {
  __shared__ unsigned short lA[2][128 * 64];
  __shared__ unsigned short lB[2][128 * 64];
  const int nwg = gridDim.x;
  const int bid = blockIdx.x;
  const int qd = nwg >> 3, rr = nwg & 7;
  const int xcd = bid & 7, sidx = bid >> 3;
  const int swz = (xcd < rr ? xcd * (qd + 1) : rr * (qd + 1) + (xcd - rr) * qd) + sidx;
  const int m0 = (swz / nbn) * 128;
  const int n0 = (swz % nbn) * 128;
  const int t = threadIdx.x;
  const int w = t >> 6, l = t & 63;
  const int wr = w >> 1, wc = w & 1;
  const int lr = l & 15, lg = l >> 4;

  const int strow = (l >> 3);
  const int scolb = (((l & 7) ^ strow) << 4);

  f32x4 acc[4][4];
#pragma unroll
  for (int i = 0; i < 4; ++i)
#pragma unroll
    for (int j = 0; j < 4; ++j) acc[i][j] = f32x4{0.f, 0.f, 0.f, 0.f};

  auto stage = [&](int buf, int k0) {
#pragma unroll
    for (int s = 0; s < 4; ++s) {
      const int seg = w * 4 + s;
      const int row = seg * 8 + strow;
      gload_lds16((const char*)A + ((size_t)(m0 + row) * K + k0) * 2 + scolb,
                  (char*)&lA[buf][0] + seg * 1024 + (l & 7) * 16);
      gload_lds16((const char*)Bt + ((size_t)(n0 + row) * K + k0) * 2 + scolb,
                  (char*)&lB[buf][0] + seg * 1024 + (l & 7) * 16);
    }
  };
  auto compute = [&](int buf) {
#pragma unroll
    for (int kk = 0; kk < 64; kk += 32) {
      bf16x8 af[4], bfr[4];
      const int sbase = (kk >> 3) + lg;
      const int p = (sbase ^ (lr & 7)) << 3;
#pragma unroll
      for (int i = 0; i < 4; ++i)
        af[i] = *(const bf16x8*)&lA[buf][(wr * 64 + i * 16 + lr) * 64 + p];
#pragma unroll
      for (int j = 0; j < 4; ++j)
        bfr[j] = *(const bf16x8*)&lB[buf][(wc * 64 + j * 16 + lr) * 64 + p];
#pragma unroll
      for (int i = 0; i < 4; ++i)
#pragma unroll
        for (int j = 0; j < 4; ++j)
          acc[i][j] = __builtin_amdgcn_mfma_f32_16x16x32_bf16(af[i], bfr[j], acc[i][j], 0, 0, 0);
    }
  };

  stage(0, 0);
  __syncthreads();
  int cur = 0;
  for (int k0 = 64; k0 < K; k0 += 64) {
    stage(cur ^ 1, k0);
    compute(cur);
    __syncthreads();
    cur ^= 1;
  }
  compute(cur);

#pragma unroll
  for (int i = 0; i < 4; ++i) {
    const int grow = m0 + wr * 64 + i * 16 + lg * 4;
#pragma unroll
    for (int j = 0; j < 4; ++j) {
      const int gcol = n0 + wc * 64 + j * 16 + lr;
#pragma unroll
      for (int r = 0; r < 4; ++r) {
        const float v = acc[i][j][r];
        const size_t row = (size_t)(grow + r);
        if (mode == 0) {
          unsigned short* dst = (gcol < 256) ? ob0 : (gcol < 512 ? ob1 : ob2);
          dst[row * C + (gcol & 255)] = f2bf(v);
        } else if (mode == 1) {
          ob0[row * C + gcol] = f2bf(v + bias[gcol]);
        } else {
          const size_t idx = row * C + gcol;
          of32[idx] += v + bias[gcol];
        }
      }
    }
  }
}

// ---------------- depthwise 5x5 + sigmoid + mask_emb, 4ch x 4x per thread ----------------
__global__ __launch_bounds__(256) void mask_dw5_kernel(
    const unsigned short* __restrict__ m2, const unsigned short* __restrict__ m1,
    const float* __restrict__ dw, const float* __restrict__ db,
    unsigned short* __restrict__ memb) {
  __shared__ float wlds[25 * 256];
  __shared__ float blds[256];
  const int t = threadIdx.x;
  const int y = blockIdx.y;
  const int x0 = blockIdx.x * 16 + (t >> 6) * 4;
  const int cg = (t & 63) * 4;
#pragma unroll
  for (int e = 0; e < 25; ++e) wlds[e * 256 + t] = dw[t * 25 + e];
  blds[t] = db[t];
  __syncthreads();

  const f32x4 bias = *(const f32x4*)&blds[cg];
  f32x4 acc[4];
#pragma unroll
  for (int xi = 0; xi < 4; ++xi) acc[xi] = bias;

#pragma unroll
  for (int dy = 0; dy < 5; ++dy) {
    const int yy = y + dy - 2;
    if (yy < 0 || yy >= HW) continue;
    f32x4 col[8];
#pragma unroll
    for (int j = 0; j < 8; ++j) {
      const int xx = x0 - 2 + j;
      if (xx >= 0 && xx < HW) {
        const s16x4 v = *(const s16x4*)&m2[((size_t)yy * HW + xx) * C + cg];
        col[j][0] = bf2f((unsigned short)v[0]);
        col[j][1] = bf2f((unsigned short)v[1]);
        col[j][2] = bf2f((unsigned short)v[2]);
        col[j][3] = bf2f((unsigned short)v[3]);
      } else {
        col[j] = f32x4{0.f, 0.f, 0.f, 0.f};
      }
    }
#pragma unroll
    for (int dx = 0; dx < 5; ++dx) {
      const f32x4 wv = *(const f32x4*)&wlds[(dy * 5 + dx) * 256 + cg];
#pragma unroll
      for (int xi = 0; xi < 4; ++xi) acc[xi] += wv * col[dx + xi];
    }
  }

#pragma unroll
  for (int xi = 0; xi < 4; ++xi) {
    const size_t oi = ((size_t)y * HW + x0 + xi) * C + cg;
    const s16x4 mv = *(const s16x4*)&m1[oi];
    s16x4 o;
#pragma unroll
    for (int ch = 0; ch < 4; ++ch) {
      const float a = 1.f / (1.f + __expf(-acc[xi][ch]));
      o[ch] = (short)f2bf(bf2f((unsigned short)mv[ch]) * (1.f + a));
    }
    *(s16x4*)&memb[oi] = o;
  }
}

// ---------------- Gram partials + fused sumsq ----------------
__global__ __launch_bounds__(256) void gram_kernel(const unsigned short* __restrict__ qb,
                                                   const unsigned short* __restrict__ kb,
                                                   float* __restrict__ Gpart,
                                                   float* __restrict__ ssq,
                                                   float* __restrict__ ssk) {
  const int chunk = blockIdx.x;  // 16
  const int h = blockIdx.y;      // 8
  const int b = blockIdx.z;      // 4
  __shared__ unsigned short lk[128 * 32], lq[128 * 32];
  const int t = threadIdx.x;
  const int wv = t >> 6;
  const int i0 = (t & 7) * 4, j0 = ((t >> 3) & 7) * 4;
  const int lrow = t >> 2, lcb = (t & 3) * 8;
  float acc[4][4] = {};
  float sq[8] = {}, sk[8] = {};
  for (int sub = 0; sub < 8; ++sub) {
    const size_t nbase = (size_t)b * NTOK + chunk * 1024 + sub * 128;
    __syncthreads();
#pragma unroll
    for (int it = 0; it < 2; ++it) {
      const int row = it * 64 + lrow;
      const s16x8 kv8 = *(const s16x8*)&kb[(nbase + row) * C + h * 32 + lcb];
      const s16x8 qv8 = *(const s16x8*)&qb[(nbase + row) * C + h * 32 + lcb];
      *(s16x8*)&lk[row * 32 + lcb] = kv8;
      *(s16x8*)&lq[row * 32 + lcb] = qv8;
#pragma unroll
      for (int e = 0; e < 8; ++e) {
        const float kf = bf2f((unsigned short)kv8[e]);
        sk[e] += kf * kf;
        const float qf = bf2f((unsigned short)qv8[e]);
        sq[e] += qf * qf;
      }
    }
    __syncthreads();
    for (int n = wv; n < 128; n += 4) {
      s16x4 kv = *(const s16x4*)&lk[n * 32 + i0];
      s16x4 qv = *(const s16x4*)&lq[n * 32 + j0];
      float kf[4], qf[4];
#pragma unroll
      for (int e = 0; e < 4; ++e) {
        kf[e] = bf2f((unsigned short)kv[e]);
        qf[e] = bf2f((unsigned short)qv[e]);
      }
#pragma unroll
      for (int a = 0; a < 4; ++a)
#pragma unroll
        for (int bb = 0; bb < 4; ++bb) acc[a][bb] += kf[a] * qf[bb];
    }
  }
  const int pc = chunk * 4 + wv;
  float* dst = Gpart + (((size_t)pc * B + b) * HEADS + h) * 1024;
#pragma unroll
  for (int a = 0; a < 4; ++a)
#pragma unroll
    for (int bb = 0; bb < 4; ++bb) dst[(i0 + a) * 32 + (j0 + bb)] = acc[a][bb];
  __syncthreads();
  float* fq = (float*)lq;
  float* fk = (float*)lk;
#pragma unroll
  for (int e = 0; e < 8; ++e) {
    fq[t * 8 + e] = sq[e];
    fk[t * 8 + e] = sk[e];
  }
  __syncthreads();
  if (t < 32) {
    const int tm = t >> 3, e = t & 7;
    float s1 = 0.f, s2 = 0.f;
    for (int k2 = 0; k2 < 64; ++k2) {
      const int tt = tm + k2 * 4;
      s1 += fq[tt * 8 + e];
      s2 += fk[tt * 8 + e];
    }
    ssq[((size_t)b * 16 + chunk) * C + h * 32 + t] = s1;
    ssk[((size_t)b * 16 + chunk) * C + h * 32 + t] = s2;
  }
}

// ---------------- reduce + normalize + softmax -> attn bf16 ----------------
__global__ __launch_bounds__(256) void softmax_kernel(
    const float* __restrict__ Gpart, const float* __restrict__ ssq,
    const float* __restrict__ ssk, const float* __restrict__ rescale,
    unsigned short* __restrict__ attnb) {
  const int h = blockIdx.x, b = blockIdx.y;
  const int t = threadIdx.x;
  __shared__ float G[1024];
  __shared__ float nq[32], nk[32];
#pragma unroll
  for (int e = 0; e < 4; ++e) {
    const int cell = e * 256 + t;
    float s = 0.f;
    for (int pc = 0; pc < 64; ++pc)
      s += Gpart[(((size_t)pc * B + b) * HEADS + h) * 1024 + cell];
    G[cell] = s;
  }
  if (t < 64) {
    const int d = t & 31;
    const float* ss = (t < 32) ? ssq : ssk;
    float s = 0.f;
    for (int ch = 0; ch < 16; ++ch) s += ss[((size_t)b * 16 + ch) * C + h * 32 + d];
    const float nn = fmaxf(sqrtf(s), 1e-12f);
    if (t < 32) nq[d] = nn;
    else nk[d] = nn;
  }
  __syncthreads();
  if (t < 32) {
    const int i = t;
    const float rs = rescale[h];
    float row[32];
    float mx = -1e30f;
#pragma unroll
    for (int j = 0; j < 32; ++j) {
      const float v = G[i * 32 + j] / (nk[i] * nq[j]) * rs;
      row[j] = v;
      mx = fmaxf(mx, v);
    }
    float sum = 0.f;
#pragma unroll
    for (int j = 0; j < 32; ++j) {
      const float e = expf(row[j] - mx);
      row[j] = e;
      sum += e;
    }
    const float inv = 1.f / sum;
#pragma unroll
    for (int j = 0; j < 32; ++j)
      attnb[(((size_t)b * HEADS + h) * 32 + i) * 32 + j] = f2bf(row[j] * inv);
  }
}

// ---------------- PV ----------------
#define PVP 264
#define ATP 40
__global__ __launch_bounds__(256) void pv_kernel(const unsigned short* __restrict__ vb,
                                                 const unsigned short* __restrict__ memb,
                                                 const unsigned short* __restrict__ attnb,
                                                 unsigned short* __restrict__ outp) {
  const int n0 = blockIdx.x * 64;
  const int b = blockIdx.y;
  __shared__ unsigned short vma[64 * PVP];
  __shared__ unsigned short at[HEADS * 32 * ATP];
  const int t = threadIdx.x, w = t >> 6, l = t & 63;
  const int lr = l & 15, lg = l >> 4;
  for (int e = t; e < 8192; e += 256) {
    const int h = e >> 10, ij = e & 1023;
    at[(h * 32 + (ij >> 5)) * ATP + (ij & 31)] = attnb[(size_t)b * 8192 + e];
  }
  {
    const int row = t >> 2, cs = (t & 3) * 64;
#pragma unroll
    for (int i2 = 0; i2 < 8; ++i2) {
      const int c = cs + i2 * 8;
      s16x8 vv = *(const s16x8*)&vb[((size_t)b * NTOK + n0 + row) * C + c];
      s16x8 mm = *(const s16x8*)&memb[(size_t)(n0 + row) * C + c];
      s16x8 o;
#pragma unroll
      for (int e = 0; e < 8; ++e)
        o[e] = (short)f2bf(bf2f((unsigned short)vv[e]) * bf2f((unsigned short)mm[e]));
      *(s16x8*)&vma[row * PVP + c] = o;
    }
  }
  __syncthreads();
  f32x4 acc[4][4];
#pragma unroll
  for (int i = 0; i < 4; ++i)
#pragma unroll
    for (int j = 0; j < 4; ++j) acc[i][j] = f32x4{0.f, 0.f, 0.f, 0.f};
#pragma unroll
  for (int j = 0; j < 4; ++j) {
    const int head = w * 2 + (j >> 1);
    const int colh = (j & 1) * 16 + lr;
    const bf16x8 bfr = *(const bf16x8*)&at[(head * 32 + colh) * ATP + lg * 8];
#pragma unroll
    for (int i = 0; i < 4; ++i) {
      const bf16x8 af = *(const bf16x8*)&vma[(i * 16 + lr) * PVP + head * 32 + lg * 8];
      acc[i][j] = __builtin_amdgcn_mfma_f32_16x16x32_bf16(af, bfr, acc[i][j], 0, 0, 0);
    }
  }
#pragma unroll
  for (int i = 0; i < 4; ++i) {
#pragma unroll
    for (int j = 0; j < 4; ++j) {
      const int head = w * 2 + (j >> 1);
      const int gcol = head * 32 + (j & 1) * 16 + lr;
      const int grow = n0 + i * 16 + lg * 4;
#pragma unroll
      for (int r = 0; r < 4; ++r)
        outp[((size_t)b * NTOK + grow + r) * C + gcol] = f2bf(acc[i][j][r]);
    }
  }
}

// ---------------- depthwise 3x3, 4 channels/thread ----------------
__global__ __launch_bounds__(512) void dw3_kernel(const unsigned short* __restrict__ in,
                                                  const float* __restrict__ wgt,
                                                  unsigned short* __restrict__ out_bf,
                                                  float* __restrict__ out_f32,
                                                  const int do_gelu, const int write_f32) {
  const int y = blockIdx.x;
  const int b = blockIdx.y;
  const int t = threadIdx.x;
  const int cg = (t & 63) * 4;
  const int x0 = (t >> 6) * 16;
  float w[9][4];
#pragma unroll
  for (int e = 0; e < 9; ++e)
#pragma unroll
    for (int ch = 0; ch < 4; ++ch) w[e][ch] = wgt[(cg + ch) * 9 + e];
  const int ym = y - 1, yp = y + 1;
  const bool hm = (ym >= 0), hp = (yp < HW);
  const size_t base = (size_t)b * NTOK * C + cg;
  auto ld4 = [&](int yy, int xx) -> f32x4 {
    const s16x4 v = *(const s16x4*)&in[base + ((size_t)yy * HW + xx) * C];
    f32x4 f;
    f[0] = bf2f((unsigned short)v[0]);
    f[1] = bf2f((unsigned short)v[1]);
    f[2] = bf2f((unsigned short)v[2]);
    f[3] = bf2f((unsigned short)v[3]);
    return f;
  };
  const f32x4 zero = {0.f, 0.f, 0.f, 0.f};
  f32x4 a0, a1, a2, b0, b1, b2;
  if (x0 > 0) {
    a0 = hm ? ld4(ym, x0 - 1) : zero;
    a1 = ld4(y, x0 - 1);
    a2 = hp ? ld4(yp, x0 - 1) : zero;
  } else {
    a0 = a1 = a2 = zero;
  }
  b0 = hm ? ld4(ym, x0) : zero;
  b1 = ld4(y, x0);
  b2 = hp ? ld4(yp, x0) : zero;
  for (int xi = 0; xi < 16; ++xi) {
    const int x = x0 + xi;
    f32x4 c0, c1, c2;
    if (x + 1 < HW) {
      c0 = hm ? ld4(ym, x + 1) : zero;
      c1 = ld4(y, x + 1);
      c2 = hp ? ld4(yp, x + 1) : zero;
    } else {
      c0 = c1 = c2 = zero;
    }
    float res[4];
#pragma unroll
    for (int ch = 0; ch < 4; ++ch) {
      float r = w[0][ch] * a0[ch] + w[1][ch] * b0[ch] + w[2][ch] * c0[ch] +
                w[3][ch] * a1[ch] + w[4][ch] * b1[ch] + w[5][ch] * c1[ch] +
                w[6][ch] * a2[ch] + w[7][ch] * b2[ch] + w[8][ch] * c2[ch];
      if (do_gelu) r = 0.5f * r * (1.f + erff(r * 0.70710678118654752f));
      res[ch] = r;
    }
    const size_t oi = base + ((size_t)y * HW + x) * C;
    if (write_f32) {
      const f32x4 o = {res[0], res[1], res[2], res[3]};
      *(f32x4*)&out_f32[oi] = o;
    } else {
      s16x4 o;
      o[0] = (short)f2bf(res[0]);
      o[1] = (short)f2bf(res[1]);
      o[2] = (short)f2bf(res[2]);
      o[3] = (short)f2bf(res[3]);
      *(s16x4*)&out_bf[oi] = o;
    }
    a0 = b0; a1 = b1; a2 = b2;
    b0 = c0; b1 = c1; b2 = c2;
  }
}

extern "C" void kernel_launch(void* const* d_in, const int* in_sizes, int n_in, void* d_out,
                              int out_size, void* d_ws, size_t ws_size, hipStream_t stream) {
  (void)in_sizes; (void)n_in; (void)out_size; (void)ws_size;
  const float* x = (const float*)d_in[0];
  const float* maskp = (const float*)d_in[1];
  const float* wq = (const float*)d_in[2];
  const float* wk = (const float*)d_in[3];
  const float* wv = (const float*)d_in[4];
  const float* rescale = (const float*)d_in[5];
  const float* wproj = (const float*)d_in[6];
  const float* bproj = (const float*)d_in[7];
  const float* mg_w1 = (const float*)d_in[8];
  const float* mg_b1 = (const float*)d_in[9];
  const float* mg_w2 = (const float*)d_in[10];
  const float* mg_b2 = (const float*)d_in[11];
  const float* mg_dw = (const float*)d_in[12];
  const float* mg_db = (const float*)d_in[13];
  const float* be_w1 = (const float*)d_in[14];
  const float* be_w2 = (const float*)d_in[15];
  float* out = (float*)d_out;
  char* ws = (char*)d_ws;

  unsigned short* xb = (unsigned short*)(ws + 0ull);            // 32MB, later out_pre
  unsigned short* qb = (unsigned short*)(ws + 33554432ull);     // 32MB, later y1
  unsigned short* kb = (unsigned short*)(ws + 67108864ull);     // 32MB, later y2
  unsigned short* vb = (unsigned short*)(ws + 100663296ull);    // 32MB
  unsigned short* mT = (unsigned short*)(ws + 134217728ull);    // 8MB, later mask_emb
  unsigned short* m1b = (unsigned short*)(ws + 142606336ull);   // 8MB
  unsigned short* m2b = (unsigned short*)(ws + 150994944ull);   // 8MB, later Gpart
  unsigned short* wqkvT = (unsigned short*)(ws + 159383552ull); // 384KB
  unsigned short* wprojT = (unsigned short*)(ws + 159776768ull);// 128KB
  unsigned short* w1b = (unsigned short*)(ws + 159907840ull);   // 128KB
  unsigned short* w2b = (unsigned short*)(ws + 160038912ull);   // 128KB
  float* ssq = (float*)(ws + 160169984ull);                     // 64KB (16 partials)
  float* ssk = (float*)(ws + 160432128ull);                     // 64KB
  unsigned short* attnb = (unsigned short*)(ws + 160694272ull); // 64KB
  float* Gpart = (float*)m2b;
  unsigned short* memb = mT;
  unsigned short* outpre = xb;
  unsigned short* y1 = qb;
  unsigned short* y2 = kb;

  cast_x_kernel<<<2048, 256, 0, stream>>>(x, xb);
  prep_w_kernel<<<dim3(256, 6), 256, 0, stream>>>(wq, wk, wv, wproj, mg_w1, mg_w2, wqkvT,
                                                  wprojT, w1b, w2b);
  tmask_kernel<<<dim3(512, 8), 1024, 0, stream>>>(maskp, mT);
  // mask branch
  gemm_bt_kernel<<<256, 256, 0, stream>>>(mT, w1b, 256, 2, 1, m1b, nullptr, nullptr, mg_b1,
                                          nullptr);
  gemm_bt_kernel<<<256, 256, 0, stream>>>(m1b, w2b, 256, 2, 1, m2b, nullptr, nullptr, mg_b2,
                                          nullptr);
  mask_dw5_kernel<<<dim3(8, 128), 256, 0, stream>>>(m2b, m1b, mg_dw, mg_db, memb);
  // q,k,v : 256 M-tiles x 3 N-panels
  gemm_bt256_kernel<<<768, 512, 0, stream>>>(xb, wqkvT, 3, 0, qb, kb, vb, nullptr, nullptr,
                                             nullptr);
  gram_kernel<<<dim3(16, 8, 4), 256, 0, stream>>>(qb, kb, Gpart, ssq, ssk);
  softmax_kernel<<<dim3(8, 4), 256, 0, stream>>>(Gpart, ssq, ssk, rescale, attnb);
  pv_kernel<<<dim3(256, 4), 256, 0, stream>>>(vb, memb, attnb, outpre);
  // band branch: y1 = gelu(dw3(v)); y2 = dw3(y1) as bf16
  dw3_kernel<<<dim3(128, 4), 512, 0, stream>>>(vb, be_w1, y1, nullptr, 1, 0);
  dw3_kernel<<<dim3(128, 4), 512, 0, stream>>>(y1, be_w2, y2, nullptr, 0, 0);
  // proj GEMM: out = outpre @ wproj^T + bproj + y2   (single f32 write)
  gemm_bt256_kernel<<<256, 512, 0, stream>>>(outpre, wprojT, 1, 2, nullptr, nullptr, nullptr,
                                             bproj, out, y2);
}

// Round 7
// 298.402 us; speedup vs baseline: 1.4918x; 1.0039x over previous
//
#include <hip/hip_runtime.h>
#include <stdint.h>

#define B 4
#define HW 128
#define C 256
#define NTOK 16384
#define MALL 65536
#define HEADS 8
#define DH 32

typedef float f32x4 __attribute__((ext_vector_type(4)));
typedef short s16x8 __attribute__((ext_vector_type(8)));
typedef short s16x4 __attribute__((ext_vector_type(4)));
typedef __bf16 bf16x8 __attribute__((ext_vector_type(8)));

__device__ __forceinline__ float bf2f(unsigned short u) {
  union { unsigned int i; float f; } x;
  x.i = ((unsigned int)u) << 16;
  return x.f;
}
__device__ __forceinline__ unsigned short f2bf(float f) {
  union { float f; unsigned int i; } x;
  x.f = f;
  unsigned int lsb = (x.i >> 16) & 1u;
  unsigned int r = x.i + 0x7fffu + lsb;
  return (unsigned short)(r >> 16);
}

__device__ __forceinline__ void gload_lds16(const void* g, void* l) {
  auto gp = reinterpret_cast<const __attribute__((address_space(1))) unsigned int*>(
      reinterpret_cast<uintptr_t>(g));
  auto lp = reinterpret_cast<__attribute__((address_space(3))) unsigned int*>(
      reinterpret_cast<uintptr_t>(l));
  __builtin_amdgcn_global_load_lds(gp, lp, 16, 0, 0);
}

#define CFENCE asm volatile("" ::: "memory")
#define RAWBAR()                      \
  do {                                \
    CFENCE;                           \
    __builtin_amdgcn_s_barrier();     \
    CFENCE;                           \
  } while (0)
#define LDSBAR()                                        \
  do {                                                  \
    asm volatile("s_waitcnt lgkmcnt(0)" ::: "memory");  \
    __builtin_amdgcn_s_barrier();                       \
    CFENCE;                                             \
  } while (0)

// ---------------- cast x to bf16 ----------------
__global__ __launch_bounds__(256) void cast_x_kernel(const float* __restrict__ x,
                                                     unsigned short* __restrict__ xb) {
  const size_t stride = (size_t)gridDim.x * blockDim.x * 4;
  for (size_t i = ((size_t)blockIdx.x * blockDim.x + threadIdx.x) * 4; i < (size_t)MALL * C;
       i += stride) {
    const float4 v = *(const float4*)&x[i];
    s16x4 o;
    o[0] = (short)f2bf(v.x);
    o[1] = (short)f2bf(v.y);
    o[2] = (short)f2bf(v.z);
    o[3] = (short)f2bf(v.w);
    *(s16x4*)&xb[i] = o;
  }
}

// ---------------- weight prep: transpose+cast ----------------
__global__ __launch_bounds__(256) void prep_w_kernel(
    const float* __restrict__ wq, const float* __restrict__ wk, const float* __restrict__ wv,
    const float* __restrict__ wproj, const float* __restrict__ w1, const float* __restrict__ w2,
    unsigned short* __restrict__ wqkvT, unsigned short* __restrict__ wprojT,
    unsigned short* __restrict__ w1b, unsigned short* __restrict__ w2b) {
  const int idx = blockIdx.x * 256 + threadIdx.x;  // 0..65535
  const int mat = blockIdx.y;
  const int n = idx >> 8, k = idx & 255;
  switch (mat) {
    case 0: wqkvT[idx] = f2bf(wq[k * 256 + n]); break;
    case 1: wqkvT[65536 + idx] = f2bf(wk[k * 256 + n]); break;
    case 2: wqkvT[131072 + idx] = f2bf(wv[k * 256 + n]); break;
    case 3: wprojT[idx] = f2bf(wproj[k * 256 + n]); break;
    case 4: w1b[idx] = f2bf(w1[idx]); break;   // [co][ci] already K-contig
    case 5: w2b[idx] = f2bf(w2[idx]); break;
  }
}

// ---------------- transpose mask [C][N] -> [N][C] bf16 ----------------
__global__ __launch_bounds__(1024) void tmask_kernel(const float* __restrict__ mask,
                                                     unsigned short* __restrict__ mT) {
  __shared__ float tile[32][33];
  const int p0 = blockIdx.x * 32, c0 = blockIdx.y * 32;
  const int tx = threadIdx.x & 31, ty = threadIdx.x >> 5;
  tile[ty][tx] = mask[(size_t)(c0 + ty) * NTOK + p0 + tx];
  __syncthreads();
  mT[(size_t)(p0 + ty) * C + c0 + tx] = f2bf(tile[tx][ty]);
}

// ================ 256x256 8-wave pipelined GEMM, K=256 fixed ================
// 2-buffer dist-1 pipeline, 64KB LDS -> 2 blocks/CU. 1 barrier + vmcnt(0)/kt.
// mode 0: bf16 out (q/k/v selected by n0/256), LDS-staged coalesced epilogue (4 chunks).
// mode 2: out = acc + bias + bf2f(y2), f32 epilogue (8 chunks, no RMW).
__global__ __launch_bounds__(512) void gemm_bt256_kernel(
    const unsigned short* __restrict__ A, const unsigned short* __restrict__ Bt,
    const int nbn, const int mode, unsigned short* __restrict__ ob0,
    unsigned short* __restrict__ ob1, unsigned short* __restrict__ ob2,
    const float* __restrict__ bias, float* __restrict__ of32,
    const unsigned short* __restrict__ y2) {
  __shared__ alignas(16) unsigned short smem[32768];  // 64KB: lA 2x8192, lB 2x8192
  unsigned short* lAb = smem;
  unsigned short* lBb = smem + 16384;
  const int nwg = gridDim.x;
  const int bid = blockIdx.x;
  const int qd = nwg >> 3, rr = nwg & 7;
  const int xcd = bid & 7, sidx = bid >> 3;
  const int swz = (xcd < rr ? xcd * (qd + 1) : rr * (qd + 1) + (xcd - rr) * qd) + sidx;
  const int m0 = (swz / nbn) * 256;
  const int n0 = (swz % nbn) * 256;
  const int t = threadIdx.x;
  const int w = t >> 6, l = t & 63;
  const int wr = w >> 2, wc = w & 3;   // wave grid 2(M) x 4(N)
  const int lr = l & 15, lg = l >> 4;

  const int srow = t >> 2;
  const int ssl = (t & 3) ^ ((t >> 3) & 3);

  auto stageA = [&](int kt) {
    unsigned short* d = lAb + (kt & 1) * 8192;
    const size_t kb = ((size_t)kt * 32 + ssl * 8) * 2;  // byte k-offset
    gload_lds16((const char*)A + ((size_t)(m0 + srow) * 256) * 2 + kb, (char*)d + t * 16);
    gload_lds16((const char*)A + ((size_t)(m0 + 128 + srow) * 256) * 2 + kb,
                (char*)d + 8192 + t * 16);
  };
  auto stageB = [&](int kt) {
    unsigned short* d = lBb + (kt & 1) * 8192;
    const size_t kb = ((size_t)kt * 32 + ssl * 8) * 2;
    gload_lds16((const char*)Bt + ((size_t)(n0 + srow) * 256) * 2 + kb, (char*)d + t * 16);
    gload_lds16((const char*)Bt + ((size_t)(n0 + 128 + srow) * 256) * 2 + kb,
                (char*)d + 8192 + t * 16);
  };

  f32x4 acc[8][4];
#pragma unroll
  for (int m = 0; m < 8; ++m)
#pragma unroll
    for (int j = 0; j < 4; ++j) acc[m][j] = f32x4{0.f, 0.f, 0.f, 0.f};

  const int asl = (lg ^ ((lr >> 1) & 3)) * 8;
  const int aoff = lr * 32 + asl;
  const int awb = wr * 4096;
  const int boff = (wc >> 1) * 4096 + ((wc & 1) * 64 + lr) * 32 + asl;

  stageA(0); stageB(0);
  asm volatile("s_waitcnt vmcnt(0)" ::: "memory");
  RAWBAR();

#pragma unroll
  for (int kt = 0; kt < 8; ++kt) {
    const unsigned short* bufA = lAb + (kt & 1) * 8192;
    const unsigned short* bufB = lBb + (kt & 1) * 8192;
    bf16x8 bfr[4], af[4], af2[4];
#pragma unroll
    for (int j = 0; j < 4; ++j) bfr[j] = *(const bf16x8*)&bufB[boff + j * 512];
#pragma unroll
    for (int m = 0; m < 4; ++m) af[m] = *(const bf16x8*)&bufA[awb + aoff + m * 512];
#pragma unroll
    for (int m = 0; m < 4; ++m) af2[m] = *(const bf16x8*)&bufA[awb + aoff + (m + 4) * 512];
    if (kt < 7) { stageA(kt + 1); stageB(kt + 1); }
    __builtin_amdgcn_s_setprio(1);
#pragma unroll
    for (int m = 0; m < 4; ++m)
#pragma unroll
      for (int j = 0; j < 4; ++j)
        acc[m][j] = __builtin_amdgcn_mfma_f32_16x16x32_bf16(af[m], bfr[j], acc[m][j], 0, 0, 0);
#pragma unroll
    for (int m = 0; m < 4; ++m)
#pragma unroll
      for (int j = 0; j < 4; ++j)
        acc[m + 4][j] =
            __builtin_amdgcn_mfma_f32_16x16x32_bf16(af2[m], bfr[j], acc[m + 4][j], 0, 0, 0);
    __builtin_amdgcn_s_setprio(0);
    if (kt < 7) asm volatile("s_waitcnt vmcnt(0)" ::: "memory");
    RAWBAR();
  }

  if (mode == 0) {
    // ---- bf16 epilogue: 4 chunks of 64 rows ----
    unsigned short* dst = (n0 < 256) ? ob0 : (n0 < 512 ? ob1 : ob2);
    unsigned short* eph = smem;  // [64][264] ushorts = 33.8KB
#pragma unroll
    for (int c = 0; c < 4; ++c) {
      LDSBAR();
      if (wr == (c >> 1)) {
#pragma unroll
        for (int mm = 0; mm < 4; ++mm) {
          const int m = (c & 1) * 4 + mm;
          const int lrow = mm * 16 + lg * 4;
#pragma unroll
          for (int j = 0; j < 4; ++j) {
            const int col = wc * 64 + j * 16 + lr;
#pragma unroll
            for (int r = 0; r < 4; ++r) eph[(lrow + r) * 264 + col] = f2bf(acc[m][j][r]);
          }
        }
      }
      LDSBAR();
      const int col16 = t & 31;  // 16B chunk within row
#pragma unroll
      for (int c2 = 0; c2 < 4; ++c2) {
        const int lrow = c2 * 16 + (t >> 5);
        const int grow = m0 + c * 64 + lrow;
        const s16x8 v = *(const s16x8*)&eph[lrow * 264 + col16 * 8];
        *(s16x8*)&dst[(size_t)grow * C + col16 * 8] = v;
      }
    }
  } else {
    // ---- f32 epilogue: out = acc + bias + y2 ; 8 chunks of 32 rows ----
    float* ephf = (float*)smem;  // [32][260] floats = 33.3KB
    const int colc = t & 63;
    const f32x4 bv = *(const f32x4*)&bias[colc * 4];
#pragma unroll
    for (int c = 0; c < 8; ++c) {
      LDSBAR();
      if (wr == (c >> 2)) {
#pragma unroll
        for (int mm = 0; mm < 2; ++mm) {
          const int m = (c & 3) * 2 + mm;
          const int lrow = mm * 16 + lg * 4;
#pragma unroll
          for (int j = 0; j < 4; ++j) {
            const int col = wc * 64 + j * 16 + lr;
#pragma unroll
            for (int r = 0; r < 4; ++r) ephf[(lrow + r) * 260 + col] = acc[m][j][r];
          }
        }
      }
      LDSBAR();
#pragma unroll
      for (int c2 = 0; c2 < 4; ++c2) {
        const int lrow = c2 * 8 + (t >> 6);
        const int grow = m0 + c * 32 + lrow;
        const f32x4 v = *(const f32x4*)&ephf[lrow * 260 + colc * 4];
        const s16x4 yv = *(const s16x4*)&y2[(size_t)grow * C + colc * 4];
        f32x4 o;
#pragma unroll
        for (int e = 0; e < 4; ++e) o[e] = v[e] + bv[e] + bf2f((unsigned short)yv[e]);
        *(f32x4*)&of32[(size_t)grow * C + colc * 4] = o;
      }
    }
  }
}

// ---------------- 2-phase 128x128 GEMM (kept for small mask GEMMs) ----------------
__global__ __launch_bounds__(256) void gemm_bt_kernel(
    const unsigned short* __restrict__ A, const unsigned short* __restrict__ Bt, const int K,
    const int nbn, const int mode, unsigned short* __restrict__ ob0,
    unsigned short* __restrict__ ob1, unsigned short* __restrict__ ob2,
    const float* __restrict__ bias, float* __restrict__ of32) {
  __shared__ unsigned short lA[2][128 * 64];
  __shared__ unsigned short lB[2][128 * 64];
  const int nwg = gridDim.x;
  const int bid = blockIdx.x;
  const int qd = nwg >> 3, rr = nwg & 7;
  const int xcd = bid & 7, sidx = bid >> 3;
  const int swz = (xcd < rr ? xcd * (qd + 1) : rr * (qd + 1) + (xcd - rr) * qd) + sidx;
  const int m0 = (swz / nbn) * 128;
  const int n0 = (swz % nbn) * 128;
  const int t = threadIdx.x;
  const int w = t >> 6, l = t & 63;
  const int wr = w >> 1, wc = w & 1;
  const int lr = l & 15, lg = l >> 4;

  const int strow = (l >> 3);
  const int scolb = (((l & 7) ^ strow) << 4);

  f32x4 acc[4][4];
#pragma unroll
  for (int i = 0; i < 4; ++i)
#pragma unroll
    for (int j = 0; j < 4; ++j) acc[i][j] = f32x4{0.f, 0.f, 0.f, 0.f};

  auto stage = [&](int buf, int k0) {
#pragma unroll
    for (int s = 0; s < 4; ++s) {
      const int seg = w * 4 + s;
      const int row = seg * 8 + strow;
      gload_lds16((const char*)A + ((size_t)(m0 + row) * K + k0) * 2 + scolb,
                  (char*)&lA[buf][0] + seg * 1024 + (l & 7) * 16);
      gload_lds16((const char*)Bt + ((size_t)(n0 + row) * K + k0) * 2 + scolb,
                  (char*)&lB[buf][0] + seg * 1024 + (l & 7) * 16);
    }
  };
  auto compute = [&](int buf) {
#pragma unroll
    for (int kk = 0; kk < 64; kk += 32) {
      bf16x8 af[4], bfr[4];
      const int sbase = (kk >> 3) + lg;
      const int p = (sbase ^ (lr & 7)) << 3;
#pragma unroll
      for (int i = 0; i < 4; ++i)
        af[i] = *(const bf16x8*)&lA[buf][(wr * 64 + i * 16 + lr) * 64 + p];
#pragma unroll
      for (int j = 0; j < 4; ++j)
        bfr[j] = *(const bf16x8*)&lB[buf][(wc * 64 + j * 16 + lr) * 64 + p];
#pragma unroll
      for (int i = 0; i < 4; ++i)
#pragma unroll
        for (int j = 0; j < 4; ++j)
          acc[i][j] = __builtin_amdgcn_mfma_f32_16x16x32_bf16(af[i], bfr[j], acc[i][j], 0, 0, 0);
    }
  };

  stage(0, 0);
  __syncthreads();
  int cur = 0;
  for (int k0 = 64; k0 < K; k0 += 64) {
    stage(cur ^ 1, k0);
    compute(cur);
    __syncthreads();
    cur ^= 1;
  }
  compute(cur);

#pragma unroll
  for (int i = 0; i < 4; ++i) {
    const int grow = m0 + wr * 64 + i * 16 + lg * 4;
#pragma unroll
    for (int j = 0; j < 4; ++j) {
      const int gcol = n0 + wc * 64 + j * 16 + lr;
#pragma unroll
      for (int r = 0; r < 4; ++r) {
        const float v = acc[i][j][r];
        const size_t row = (size_t)(grow + r);
        if (mode == 0) {
          unsigned short* dst = (gcol < 256) ? ob0 : (gcol < 512 ? ob1 : ob2);
          dst[row * C + (gcol & 255)] = f2bf(v);
        } else if (mode == 1) {
          ob0[row * C + gcol] = f2bf(v + bias[gcol]);
        } else {
          const size_t idx = row * C + gcol;
          of32[idx] += v + bias[gcol];
        }
      }
    }
  }
}

// ---------------- depthwise 5x5 + sigmoid + mask_emb, 4ch x 4x per thread ----------------
__global__ __launch_bounds__(256) void mask_dw5_kernel(
    const unsigned short* __restrict__ m2, const unsigned short* __restrict__ m1,
    const float* __restrict__ dw, const float* __restrict__ db,
    unsigned short* __restrict__ memb) {
  __shared__ float wlds[25 * 256];
  __shared__ float blds[256];
  const int t = threadIdx.x;
  const int y = blockIdx.y;
  const int x0 = blockIdx.x * 16 + (t >> 6) * 4;
  const int cg = (t & 63) * 4;
#pragma unroll
  for (int e = 0; e < 25; ++e) wlds[e * 256 + t] = dw[t * 25 + e];
  blds[t] = db[t];
  __syncthreads();

  const f32x4 bias = *(const f32x4*)&blds[cg];
  f32x4 acc[4];
#pragma unroll
  for (int xi = 0; xi < 4; ++xi) acc[xi] = bias;

#pragma unroll
  for (int dy = 0; dy < 5; ++dy) {
    const int yy = y + dy - 2;
    if (yy < 0 || yy >= HW) continue;
    f32x4 col[8];
#pragma unroll
    for (int j = 0; j < 8; ++j) {
      const int xx = x0 - 2 + j;
      if (xx >= 0 && xx < HW) {
        const s16x4 v = *(const s16x4*)&m2[((size_t)yy * HW + xx) * C + cg];
        col[j][0] = bf2f((unsigned short)v[0]);
        col[j][1] = bf2f((unsigned short)v[1]);
        col[j][2] = bf2f((unsigned short)v[2]);
        col[j][3] = bf2f((unsigned short)v[3]);
      } else {
        col[j] = f32x4{0.f, 0.f, 0.f, 0.f};
      }
    }
#pragma unroll
    for (int dx = 0; dx < 5; ++dx) {
      const f32x4 wv = *(const f32x4*)&wlds[(dy * 5 + dx) * 256 + cg];
#pragma unroll
      for (int xi = 0; xi < 4; ++xi) acc[xi] += wv * col[dx + xi];
    }
  }

#pragma unroll
  for (int xi = 0; xi < 4; ++xi) {
    const size_t oi = ((size_t)y * HW + x0 + xi) * C + cg;
    const s16x4 mv = *(const s16x4*)&m1[oi];
    s16x4 o;
#pragma unroll
    for (int ch = 0; ch < 4; ++ch) {
      const float a = 1.f / (1.f + __expf(-acc[xi][ch]));
      o[ch] = (short)f2bf(bf2f((unsigned short)mv[ch]) * (1.f + a));
    }
    *(s16x4*)&memb[oi] = o;
  }
}

// ---------------- Gram partials + fused sumsq ----------------
__global__ __launch_bounds__(256) void gram_kernel(const unsigned short* __restrict__ qb,
                                                   const unsigned short* __restrict__ kb,
                                                   float* __restrict__ Gpart,
                                                   float* __restrict__ ssq,
                                                   float* __restrict__ ssk) {
  const int chunk = blockIdx.x;  // 16
  const int h = blockIdx.y;      // 8
  const int b = blockIdx.z;      // 4
  __shared__ unsigned short lk[128 * 32], lq[128 * 32];
  const int t = threadIdx.x;
  const int wv = t >> 6;
  const int i0 = (t & 7) * 4, j0 = ((t >> 3) & 7) * 4;
  const int lrow = t >> 2, lcb = (t & 3) * 8;
  float acc[4][4] = {};
  float sq[8] = {}, sk[8] = {};
  for (int sub = 0; sub < 8; ++sub) {
    const size_t nbase = (size_t)b * NTOK + chunk * 1024 + sub * 128;
    __syncthreads();
#pragma unroll
    for (int it = 0; it < 2; ++it) {
      const int row = it * 64 + lrow;
      const s16x8 kv8 = *(const s16x8*)&kb[(nbase + row) * C + h * 32 + lcb];
      const s16x8 qv8 = *(const s16x8*)&qb[(nbase + row) * C + h * 32 + lcb];
      *(s16x8*)&lk[row * 32 + lcb] = kv8;
      *(s16x8*)&lq[row * 32 + lcb] = qv8;
#pragma unroll
      for (int e = 0; e < 8; ++e) {
        const float kf = bf2f((unsigned short)kv8[e]);
        sk[e] += kf * kf;
        const float qf = bf2f((unsigned short)qv8[e]);
        sq[e] += qf * qf;
      }
    }
    __syncthreads();
    for (int n = wv; n < 128; n += 4) {
      s16x4 kv = *(const s16x4*)&lk[n * 32 + i0];
      s16x4 qv = *(const s16x4*)&lq[n * 32 + j0];
      float kf[4], qf[4];
#pragma unroll
      for (int e = 0; e < 4; ++e) {
        kf[e] = bf2f((unsigned short)kv[e]);
        qf[e] = bf2f((unsigned short)qv[e]);
      }
#pragma unroll
      for (int a = 0; a < 4; ++a)
#pragma unroll
        for (int bb = 0; bb < 4; ++bb) acc[a][bb] += kf[a] * qf[bb];
    }
  }
  const int pc = chunk * 4 + wv;
  float* dst = Gpart + (((size_t)pc * B + b) * HEADS + h) * 1024;
#pragma unroll
  for (int a = 0; a < 4; ++a)
#pragma unroll
    for (int bb = 0; bb < 4; ++bb) dst[(i0 + a) * 32 + (j0 + bb)] = acc[a][bb];
  __syncthreads();
  float* fq = (float*)lq;
  float* fk = (float*)lk;
#pragma unroll
  for (int e = 0; e < 8; ++e) {
    fq[t * 8 + e] = sq[e];
    fk[t * 8 + e] = sk[e];
  }
  __syncthreads();
  if (t < 32) {
    const int tm = t >> 3, e = t & 7;
    float s1 = 0.f, s2 = 0.f;
    for (int k2 = 0; k2 < 64; ++k2) {
      const int tt = tm + k2 * 4;
      s1 += fq[tt * 8 + e];
      s2 += fk[tt * 8 + e];
    }
    ssq[((size_t)b * 16 + chunk) * C + h * 32 + t] = s1;
    ssk[((size_t)b * 16 + chunk) * C + h * 32 + t] = s2;
  }
}

// ---------------- reduce + normalize + softmax -> attn bf16 ----------------
__global__ __launch_bounds__(256) void softmax_kernel(
    const float* __restrict__ Gpart, const float* __restrict__ ssq,
    const float* __restrict__ ssk, const float* __restrict__ rescale,
    unsigned short* __restrict__ attnb) {
  const int h = blockIdx.x, b = blockIdx.y;
  const int t = threadIdx.x;
  __shared__ float G[1024];
  __shared__ float nq[32], nk[32];
#pragma unroll
  for (int e = 0; e < 4; ++e) {
    const int cell = e * 256 + t;
    float s = 0.f;
    for (int pc = 0; pc < 64; ++pc)
      s += Gpart[(((size_t)pc * B + b) * HEADS + h) * 1024 + cell];
    G[cell] = s;
  }
  if (t < 64) {
    const int d = t & 31;
    const float* ss = (t < 32) ? ssq : ssk;
    float s = 0.f;
    for (int ch = 0; ch < 16; ++ch) s += ss[((size_t)b * 16 + ch) * C + h * 32 + d];
    const float nn = fmaxf(sqrtf(s), 1e-12f);
    if (t < 32) nq[d] = nn;
    else nk[d] = nn;
  }
  __syncthreads();
  if (t < 32) {
    const int i = t;
    const float rs = rescale[h];
    float row[32];
    float mx = -1e30f;
#pragma unroll
    for (int j = 0; j < 32; ++j) {
      const float v = G[i * 32 + j] / (nk[i] * nq[j]) * rs;
      row[j] = v;
      mx = fmaxf(mx, v);
    }
    float sum = 0.f;
#pragma unroll
    for (int j = 0; j < 32; ++j) {
      const float e = expf(row[j] - mx);
      row[j] = e;
      sum += e;
    }
    const float inv = 1.f / sum;
#pragma unroll
    for (int j = 0; j < 32; ++j)
      attnb[(((size_t)b * HEADS + h) * 32 + i) * 32 + j] = f2bf(row[j] * inv);
  }
}

// ---------------- PV ----------------
#define PVP 264
#define ATP 40
__global__ __launch_bounds__(256) void pv_kernel(const unsigned short* __restrict__ vb,
                                                 const unsigned short* __restrict__ memb,
                                                 const unsigned short* __restrict__ attnb,
                                                 unsigned short* __restrict__ outp) {
  const int n0 = blockIdx.x * 64;
  const int b = blockIdx.y;
  __shared__ unsigned short vma[64 * PVP];
  __shared__ unsigned short at[HEADS * 32 * ATP];
  const int t = threadIdx.x, w = t >> 6, l = t & 63;
  const int lr = l & 15, lg = l >> 4;
  for (int e = t; e < 8192; e += 256) {
    const int h = e >> 10, ij = e & 1023;
    at[(h * 32 + (ij >> 5)) * ATP + (ij & 31)] = attnb[(size_t)b * 8192 + e];
  }
  {
    const int row = t >> 2, cs = (t & 3) * 64;
#pragma unroll
    for (int i2 = 0; i2 < 8; ++i2) {
      const int c = cs + i2 * 8;
      s16x8 vv = *(const s16x8*)&vb[((size_t)b * NTOK + n0 + row) * C + c];
      s16x8 mm = *(const s16x8*)&memb[(size_t)(n0 + row) * C + c];
      s16x8 o;
#pragma unroll
      for (int e = 0; e < 8; ++e)
        o[e] = (short)f2bf(bf2f((unsigned short)vv[e]) * bf2f((unsigned short)mm[e]));
      *(s16x8*)&vma[row * PVP + c] = o;
    }
  }
  __syncthreads();
  f32x4 acc[4][4];
#pragma unroll
  for (int i = 0; i < 4; ++i)
#pragma unroll
    for (int j = 0; j < 4; ++j) acc[i][j] = f32x4{0.f, 0.f, 0.f, 0.f};
#pragma unroll
  for (int j = 0; j < 4; ++j) {
    const int head = w * 2 + (j >> 1);
    const int colh = (j & 1) * 16 + lr;
    const bf16x8 bfr = *(const bf16x8*)&at[(head * 32 + colh) * ATP + lg * 8];
#pragma unroll
    for (int i = 0; i < 4; ++i) {
      const bf16x8 af = *(const bf16x8*)&vma[(i * 16 + lr) * PVP + head * 32 + lg * 8];
      acc[i][j] = __builtin_amdgcn_mfma_f32_16x16x32_bf16(af, bfr, acc[i][j], 0, 0, 0);
    }
  }
#pragma unroll
  for (int i = 0; i < 4; ++i) {
#pragma unroll
    for (int j = 0; j < 4; ++j) {
      const int head = w * 2 + (j >> 1);
      const int gcol = head * 32 + (j & 1) * 16 + lr;
      const int grow = n0 + i * 16 + lg * 4;
#pragma unroll
      for (int r = 0; r < 4; ++r)
        outp[((size_t)b * NTOK + grow + r) * C + gcol] = f2bf(acc[i][j][r]);
    }
  }
}

// ---------------- depthwise 3x3, 4 channels/thread ----------------
__global__ __launch_bounds__(512) void dw3_kernel(const unsigned short* __restrict__ in,
                                                  const float* __restrict__ wgt,
                                                  unsigned short* __restrict__ out_bf,
                                                  float* __restrict__ out_f32,
                                                  const int do_gelu, const int write_f32) {
  const int y = blockIdx.x;
  const int b = blockIdx.y;
  const int t = threadIdx.x;
  const int cg = (t & 63) * 4;
  const int x0 = (t >> 6) * 16;
  float w[9][4];
#pragma unroll
  for (int e = 0; e < 9; ++e)
#pragma unroll
    for (int ch = 0; ch < 4; ++ch) w[e][ch] = wgt[(cg + ch) * 9 + e];
  const int ym = y - 1, yp = y + 1;
  const bool hm = (ym >= 0), hp = (yp < HW);
  const size_t base = (size_t)b * NTOK * C + cg;
  auto ld4 = [&](int yy, int xx) -> f32x4 {
    const s16x4 v = *(const s16x4*)&in[base + ((size_t)yy * HW + xx) * C];
    f32x4 f;
    f[0] = bf2f((unsigned short)v[0]);
    f[1] = bf2f((unsigned short)v[1]);
    f[2] = bf2f((unsigned short)v[2]);
    f[3] = bf2f((unsigned short)v[3]);
    return f;
  };
  const f32x4 zero = {0.f, 0.f, 0.f, 0.f};
  f32x4 a0, a1, a2, b0, b1, b2;
  if (x0 > 0) {
    a0 = hm ? ld4(ym, x0 - 1) : zero;
    a1 = ld4(y, x0 - 1);
    a2 = hp ? ld4(yp, x0 - 1) : zero;
  } else {
    a0 = a1 = a2 = zero;
  }
  b0 = hm ? ld4(ym, x0) : zero;
  b1 = ld4(y, x0);
  b2 = hp ? ld4(yp, x0) : zero;
  for (int xi = 0; xi < 16; ++xi) {
    const int x = x0 + xi;
    f32x4 c0, c1, c2;
    if (x + 1 < HW) {
      c0 = hm ? ld4(ym, x + 1) : zero;
      c1 = ld4(y, x + 1);
      c2 = hp ? ld4(yp, x + 1) : zero;
    } else {
      c0 = c1 = c2 = zero;
    }
    float res[4];
#pragma unroll
    for (int ch = 0; ch < 4; ++ch) {
      float r = w[0][ch] * a0[ch] + w[1][ch] * b0[ch] + w[2][ch] * c0[ch] +
                w[3][ch] * a1[ch] + w[4][ch] * b1[ch] + w[5][ch] * c1[ch] +
                w[6][ch] * a2[ch] + w[7][ch] * b2[ch] + w[8][ch] * c2[ch];
      if (do_gelu) r = 0.5f * r * (1.f + erff(r * 0.70710678118654752f));
      res[ch] = r;
    }
    const size_t oi = base + ((size_t)y * HW + x) * C;
    if (write_f32) {
      const f32x4 o = {res[0], res[1], res[2], res[3]};
      *(f32x4*)&out_f32[oi] = o;
    } else {
      s16x4 o;
      o[0] = (short)f2bf(res[0]);
      o[1] = (short)f2bf(res[1]);
      o[2] = (short)f2bf(res[2]);
      o[3] = (short)f2bf(res[3]);
      *(s16x4*)&out_bf[oi] = o;
    }
    a0 = b0; a1 = b1; a2 = b2;
    b0 = c0; b1 = c1; b2 = c2;
  }
}

extern "C" void kernel_launch(void* const* d_in, const int* in_sizes, int n_in, void* d_out,
                              int out_size, void* d_ws, size_t ws_size, hipStream_t stream) {
  (void)in_sizes; (void)n_in; (void)out_size; (void)ws_size;
  const float* x = (const float*)d_in[0];
  const float* maskp = (const float*)d_in[1];
  const float* wq = (const float*)d_in[2];
  const float* wk = (const float*)d_in[3];
  const float* wv = (const float*)d_in[4];
  const float* rescale = (const float*)d_in[5];
  const float* wproj = (const float*)d_in[6];
  const float* bproj = (const float*)d_in[7];
  const float* mg_w1 = (const float*)d_in[8];
  const float* mg_b1 = (const float*)d_in[9];
  const float* mg_w2 = (const float*)d_in[10];
  const float* mg_b2 = (const float*)d_in[11];
  const float* mg_dw = (const float*)d_in[12];
  const float* mg_db = (const float*)d_in[13];
  const float* be_w1 = (const float*)d_in[14];
  const float* be_w2 = (const float*)d_in[15];
  float* out = (float*)d_out;
  char* ws = (char*)d_ws;

  unsigned short* xb = (unsigned short*)(ws + 0ull);            // 32MB, later out_pre
  unsigned short* qb = (unsigned short*)(ws + 33554432ull);     // 32MB, later y1
  unsigned short* kb = (unsigned short*)(ws + 67108864ull);     // 32MB, later y2
  unsigned short* vb = (unsigned short*)(ws + 100663296ull);    // 32MB
  unsigned short* mT = (unsigned short*)(ws + 134217728ull);    // 8MB, later mask_emb
  unsigned short* m1b = (unsigned short*)(ws + 142606336ull);   // 8MB
  unsigned short* m2b = (unsigned short*)(ws + 150994944ull);   // 8MB, later Gpart
  unsigned short* wqkvT = (unsigned short*)(ws + 159383552ull); // 384KB
  unsigned short* wprojT = (unsigned short*)(ws + 159776768ull);// 128KB
  unsigned short* w1b = (unsigned short*)(ws + 159907840ull);   // 128KB
  unsigned short* w2b = (unsigned short*)(ws + 160038912ull);   // 128KB
  float* ssq = (float*)(ws + 160169984ull);                     // 64KB (16 partials)
  float* ssk = (float*)(ws + 160432128ull);                     // 64KB
  unsigned short* attnb = (unsigned short*)(ws + 160694272ull); // 64KB
  float* Gpart = (float*)m2b;
  unsigned short* memb = mT;
  unsigned short* outpre = xb;
  unsigned short* y1 = qb;
  unsigned short* y2 = kb;

  cast_x_kernel<<<2048, 256, 0, stream>>>(x, xb);
  prep_w_kernel<<<dim3(256, 6), 256, 0, stream>>>(wq, wk, wv, wproj, mg_w1, mg_w2, wqkvT,
                                                  wprojT, w1b, w2b);
  tmask_kernel<<<dim3(512, 8), 1024, 0, stream>>>(maskp, mT);
  // mask branch
  gemm_bt_kernel<<<256, 256, 0, stream>>>(mT, w1b, 256, 2, 1, m1b, nullptr, nullptr, mg_b1,
                                          nullptr);
  gemm_bt_kernel<<<256, 256, 0, stream>>>(m1b, w2b, 256, 2, 1, m2b, nullptr, nullptr, mg_b2,
                                          nullptr);
  mask_dw5_kernel<<<dim3(8, 128), 256, 0, stream>>>(m2b, m1b, mg_dw, mg_db, memb);
  // q,k,v : 256 M-tiles x 3 N-panels
  gemm_bt256_kernel<<<768, 512, 0, stream>>>(xb, wqkvT, 3, 0, qb, kb, vb, nullptr, nullptr,
                                             nullptr);
  gram_kernel<<<dim3(16, 8, 4), 256, 0, stream>>>(qb, kb, Gpart, ssq, ssk);
  softmax_kernel<<<dim3(8, 4), 256, 0, stream>>>(Gpart, ssq, ssk, rescale, attnb);
  pv_kernel<<<dim3(256, 4), 256, 0, stream>>>(vb, memb, attnb, outpre);
  // band branch: y1 = gelu(dw3(v)); y2 = dw3(y1) as bf16
  dw3_kernel<<<dim3(128, 4), 512, 0, stream>>>(vb, be_w1, y1, nullptr, 1, 0);
  dw3_kernel<<<dim3(128, 4), 512, 0, stream>>>(y1, be_w2, y2, nullptr, 0, 0);
  // proj GEMM: out = outpre @ wproj^T + bproj + y2   (single f32 write)
  gemm_bt256_kernel<<<256, 512, 0, stream>>>(outpre, wprojT, 1, 2, nullptr, nullptr, nullptr,
                                             bproj, out, y2);
}